// Round 1
// baseline (927.701 us; speedup 1.0000x reference)
//
#include <hip/hip_runtime.h>
#include <hip/hip_bf16.h>
#include <math.h>

// Bidirectional Mamba block, fp32 baseline.
// Pipeline per direction (per-token ops in ORIGINAL order; flip handled by
// index reversal in conv + scan):
//   xn = x * rsqrt(mean(x^2)+eps)            (shared, norm weight folded into GEMM)
//   xz = (xn*w) @ in_proj.T -> xh, z
//   xc = silu(causal/anticausal depthwise conv4(xh))
//   xdbl = xc @ x_proj.T  (dt|B|C)
//   delta = softplus(dt @ dt_w.T + dt_b)
//   scan over L (fwd asc / bwd desc), y = (sum_n h*C) + xc*D, y *= silu(z)
//   out = 2*x + y_f @ out_proj_f.T + y_b @ out_proj_b.T

#define NTOK 8192      // B*L
#define LL   2048
#define DM   256
#define DI   512
#define DS2  16
#define DTR  16

// ---------------- rmsnorm (base only, weight folded later) ----------------
__global__ __launch_bounds__(256) void rmsnorm_kernel(const float* __restrict__ x,
                                                      float* __restrict__ xn) {
    int t = blockIdx.x;
    int tid = threadIdx.x;
    float v = x[(size_t)t * DM + tid];
    float ss = v * v;
    #pragma unroll
    for (int m = 1; m < 64; m <<= 1) ss += __shfl_xor(ss, m);
    __shared__ float ws[4];
    if ((tid & 63) == 0) ws[tid >> 6] = ss;
    __syncthreads();
    float tot = ws[0] + ws[1] + ws[2] + ws[3];
    float scale = rsqrtf(tot / (float)DM + 1e-5f);
    xn[(size_t)t * DM + tid] = v * scale;
}

// ---------------- generic tiled SGEMM: C = A[M,K] @ W[N,K]^T --------------
#define BM 64
#define BN 64
#define BKK 16
#define EPI_PLAIN 0
#define EPI_SPLIT 1   // cols<DI -> C0 (xh), cols>=DI -> C1 (z), ldc=DI
#define EPI_OUT_F 2   // C0 = acc + 2*X
#define EPI_OUT_B 3   // C0 += acc

template <int EPI>
__global__ __launch_bounds__(256) void sgemm_kernel(
    const float* __restrict__ A, const float* __restrict__ W,
    const float* __restrict__ colscale,
    float* __restrict__ C0, float* __restrict__ C1,
    const float* __restrict__ X,
    int M, int N, int K) {
    __shared__ float As[BKK][BM + 4];
    __shared__ float Bs[BKK][BN + 4];
    int tid = threadIdx.x;
    int m0 = blockIdx.y * BM;
    int n0 = blockIdx.x * BN;
    int tn = tid & 15, tm = tid >> 4;
    int lrow = tid >> 2;
    int lq = (tid & 3) * 4;
    float acc[4][4] = {};

    for (int k0 = 0; k0 < K; k0 += BKK) {
        // stage A (rows m0+lrow), transposed into As[k][m]
        {
            const float* src = &A[(size_t)(m0 + lrow) * K + k0 + lq];
            float4 v = *(const float4*)src;
            if (colscale) {
                v.x *= colscale[k0 + lq + 0];
                v.y *= colscale[k0 + lq + 1];
                v.z *= colscale[k0 + lq + 2];
                v.w *= colscale[k0 + lq + 3];
            }
            As[lq + 0][lrow] = v.x; As[lq + 1][lrow] = v.y;
            As[lq + 2][lrow] = v.z; As[lq + 3][lrow] = v.w;
        }
        // stage W (rows n0+lrow), transposed into Bs[k][n]
        {
            int n = n0 + lrow;
            float4 v = make_float4(0.f, 0.f, 0.f, 0.f);
            if (n < N) v = *(const float4*)&W[(size_t)n * K + k0 + lq];
            Bs[lq + 0][lrow] = v.x; Bs[lq + 1][lrow] = v.y;
            Bs[lq + 2][lrow] = v.z; Bs[lq + 3][lrow] = v.w;
        }
        __syncthreads();
        #pragma unroll
        for (int k = 0; k < BKK; ++k) {
            float4 a = *(const float4*)&As[k][tm * 4];
            float4 b = *(const float4*)&Bs[k][tn * 4];
            float av[4] = {a.x, a.y, a.z, a.w};
            float bv[4] = {b.x, b.y, b.z, b.w};
            #pragma unroll
            for (int i = 0; i < 4; ++i)
                #pragma unroll
                for (int j = 0; j < 4; ++j)
                    acc[i][j] = fmaf(av[i], bv[j], acc[i][j]);
        }
        __syncthreads();
    }

    #pragma unroll
    for (int i = 0; i < 4; ++i) {
        int m = m0 + tm * 4 + i;
        #pragma unroll
        for (int j = 0; j < 4; ++j) {
            int n = n0 + tn * 4 + j;
            if (n >= N) continue;
            float v = acc[i][j];
            if (EPI == EPI_PLAIN) {
                C0[(size_t)m * N + n] = v;
            } else if (EPI == EPI_SPLIT) {
                if (n < DI) C0[(size_t)m * DI + n] = v;
                else        C1[(size_t)m * DI + (n - DI)] = v;
            } else if (EPI == EPI_OUT_F) {
                C0[(size_t)m * DM + n] = v + 2.f * X[(size_t)m * DM + n];
            } else { // EPI_OUT_B
                C0[(size_t)m * DM + n] += v;
            }
        }
    }
}

// ---------------- depthwise causal/anticausal conv4 + silu ----------------
__global__ __launch_bounds__(256) void conv_silu_kernel(
    const float* __restrict__ xh, const float* __restrict__ cw,
    const float* __restrict__ cb, float* __restrict__ xc, int dir) {
    int idx = blockIdx.x * 256 + threadIdx.x;   // t*DI + c
    int c = idx & (DI - 1);
    int t = idx >> 9;
    int l = t & (LL - 1);
    float acc = cb[c];
    #pragma unroll
    for (int k = 0; k < 4; ++k) {
        int lo = (dir == 0) ? (l - 3 + k) : (l + 3 - k);
        if (lo >= 0 && lo < LL)
            acc = fmaf(xh[(size_t)(t + lo - l) * DI + c], cw[c * 4 + k], acc);
    }
    float s = acc / (1.f + __expf(-acc));
    xc[idx] = s;
}

// ---------------- delta = softplus(dt @ dt_w.T + dt_b) --------------------
__global__ __launch_bounds__(256) void delta_kernel(
    const float* __restrict__ xdbl, const float* __restrict__ dtw,
    const float* __restrict__ dtb, float* __restrict__ delta) {
    int t = blockIdx.x;
    int tid = threadIdx.x;
    __shared__ float sdt[DTR];
    if (tid < DTR) sdt[tid] = xdbl[(size_t)t * 48 + tid];
    __syncthreads();
    for (int d = tid; d < DI; d += 256) {
        float acc = dtb[d];
        #pragma unroll
        for (int r = 0; r < DTR; ++r) acc = fmaf(sdt[r], dtw[d * DTR + r], acc);
        float sp = (acc > 20.f) ? acc : log1pf(__expf(acc));
        delta[(size_t)t * DI + d] = sp;
    }
}

// ---------------- selective scan (both dirs in one launch) ----------------
// block: 256 thr = 16 d-groups x 16 n-lanes; grid (DI/16, B, 2)
__global__ __launch_bounds__(256) void scan_kernel(
    const float* __restrict__ delta_f, const float* __restrict__ delta_b,
    const float* __restrict__ xc_f, const float* __restrict__ xc_b,
    const float* __restrict__ xdbl_f, const float* __restrict__ xdbl_b,
    const float* __restrict__ z_f, const float* __restrict__ z_b,
    const float* __restrict__ Alog_f, const float* __restrict__ Alog_b,
    const float* __restrict__ Dp_f, const float* __restrict__ Dp_b,
    float* __restrict__ y_f, float* __restrict__ y_b) {
    int dir = blockIdx.z;
    const float* delta = dir ? delta_b : delta_f;
    const float* xc    = dir ? xc_b    : xc_f;
    const float* xdbl  = dir ? xdbl_b  : xdbl_f;
    const float* zbuf  = dir ? z_b     : z_f;
    const float* Alog  = dir ? Alog_b  : Alog_f;
    const float* Dp    = dir ? Dp_b    : Dp_f;
    float* y           = dir ? y_b     : y_f;

    int b = blockIdx.y;
    int d0 = blockIdx.x * 16;
    int tid = threadIdx.x;
    int n = tid & 15, dg = tid >> 4;
    int d = d0 + dg;

    float Av = -__expf(Alog[(size_t)d * DS2 + n]);
    float Dv = Dp[d];
    float h = 0.f;

    __shared__ float sd[64][16], sx[64][16], sz[64][16], sB[64][16], sC[64][16];
    int lrow = tid >> 2;
    int lq = (tid & 3) * 4;

    for (int c0 = 0; c0 < LL; c0 += 64) {
        int lr = c0 + lrow;
        int l = dir ? (LL - 1 - lr) : lr;
        size_t t = (size_t)b * LL + l;
        *(float4*)&sd[lrow][lq] = *(const float4*)&delta[t * DI + d0 + lq];
        *(float4*)&sx[lrow][lq] = *(const float4*)&xc[t * DI + d0 + lq];
        *(float4*)&sz[lrow][lq] = *(const float4*)&zbuf[t * DI + d0 + lq];
        *(float4*)&sB[lrow][lq] = *(const float4*)&xdbl[t * 48 + DTR + lq];
        *(float4*)&sC[lrow][lq] = *(const float4*)&xdbl[t * 48 + DTR + DS2 + lq];
        __syncthreads();
        for (int r = 0; r < 64; ++r) {
            float dl = sd[r][dg];
            float xcv = sx[r][dg];
            float a = __expf(dl * Av);
            float u = dl * sB[r][n] * xcv;
            h = fmaf(a, h, u);
            float ts = h * sC[r][n];
            ts += __shfl_xor(ts, 1);
            ts += __shfl_xor(ts, 2);
            ts += __shfl_xor(ts, 4);
            ts += __shfl_xor(ts, 8);
            if (n == 0) {
                int ll = dir ? (LL - 1 - (c0 + r)) : (c0 + r);
                float yv = ts + xcv * Dv;
                float zz = sz[r][dg];
                yv *= zz / (1.f + __expf(-zz));
                y[((size_t)b * LL + ll) * DI + d] = yv;
            }
        }
        __syncthreads();
    }
}

// -------------------------------------------------------------------------
extern "C" void kernel_launch(void* const* d_in, const int* in_sizes, int n_in,
                              void* d_out, int out_size, void* d_ws, size_t ws_size,
                              hipStream_t stream) {
    const float* x = (const float*)d_in[0];
    const float* p[2][10];
    for (int dir = 0; dir < 2; ++dir)
        for (int i = 0; i < 10; ++i)
            p[dir][i] = (const float*)d_in[1 + dir * 10 + i];
    // p[dir]: 0 norm, 1 in_proj, 2 conv_w, 3 conv_b, 4 x_proj,
    //         5 dt_w, 6 dt_b, 7 A_log, 8 D, 9 out_proj

    float* ws = (float*)d_ws;
    size_t off = 0;
    float* xn = ws + off; off += (size_t)NTOK * DM;
    float* xh[2]; float* zb[2]; float* xcb[2]; float* dlt[2]; float* xdbl[2];
    for (int dir = 0; dir < 2; ++dir) {
        xh[dir]   = ws + off; off += (size_t)NTOK * DI;   // later reused as y*silu(z)
        zb[dir]   = ws + off; off += (size_t)NTOK * DI;
        xcb[dir]  = ws + off; off += (size_t)NTOK * DI;
        dlt[dir]  = ws + off; off += (size_t)NTOK * DI;
        xdbl[dir] = ws + off; off += (size_t)NTOK * 48;
    }
    float* out = (float*)d_out;

    rmsnorm_kernel<<<NTOK, 256, 0, stream>>>(x, xn);

    for (int dir = 0; dir < 2; ++dir) {
        // in_proj: [8192,256] @ [1024,256]^T, split into xh|z, norm weight folded
        sgemm_kernel<EPI_SPLIT><<<dim3(1024 / BN, NTOK / BM), 256, 0, stream>>>(
            xn, p[dir][1], p[dir][0], xh[dir], zb[dir], nullptr, NTOK, 2 * DI, DM);
        // conv + silu
        conv_silu_kernel<<<(NTOK * DI) / 256, 256, 0, stream>>>(
            xh[dir], p[dir][2], p[dir][3], xcb[dir], dir);
        // x_proj: [8192,512] @ [48,512]^T
        sgemm_kernel<EPI_PLAIN><<<dim3(1, NTOK / BM), 256, 0, stream>>>(
            xcb[dir], p[dir][4], nullptr, xdbl[dir], nullptr, nullptr, NTOK, 48, DI);
        // delta
        delta_kernel<<<NTOK, 256, 0, stream>>>(xdbl[dir], p[dir][5], p[dir][6], dlt[dir]);
    }

    // fused bidirectional selective scan; writes y*silu(z) into xh buffers
    scan_kernel<<<dim3(DI / 16, 4, 2), 256, 0, stream>>>(
        dlt[0], dlt[1], xcb[0], xcb[1], xdbl[0], xdbl[1], zb[0], zb[1],
        p[0][7], p[1][7], p[0][8], p[1][8], xh[0], xh[1]);

    // out_proj fwd: out = acc + 2*x
    sgemm_kernel<EPI_OUT_F><<<dim3(DM / BN, NTOK / BM), 256, 0, stream>>>(
        xh[0], p[0][9], nullptr, out, nullptr, x, NTOK, DM, DI);
    // out_proj bwd: out += acc
    sgemm_kernel<EPI_OUT_B><<<dim3(DM / BN, NTOK / BM), 256, 0, stream>>>(
        xh[1], p[1][9], nullptr, out, nullptr, nullptr, NTOK, DM, DI);
}

// Round 2
// 497.174 us; speedup vs baseline: 1.8659x; 1.8659x over previous
//
#include <hip/hip_runtime.h>
#include <hip/hip_bf16.h>
#include <math.h>

// Bidirectional Mamba block. Round 2: chunked parallel selective scan.
//   phase1: per-chunk local scan -> (A_c, H_c)            [parallel over chunks]
//   phase2: tiny sequential chunk combine -> HIN          [65536 threads, 32 steps]
//   phase3: replay chunks with carry-in, emit y           [parallel over chunks]
// y*silu(z) gating folded into out_proj A-staging.

#define NTOK 8192      // B*L
#define LL   2048
#define DM   256
#define DI   512
#define DS2  16
#define DTR  16
#define CL   64        // chunk length
#define NCH  32        // chunks per sequence
#define PLANE 65536    // 2*4*512*16 = scan lanes per chunk-plane

// ---------------- rmsnorm (base only, weight folded later) ----------------
__global__ __launch_bounds__(256) void rmsnorm_kernel(const float* __restrict__ x,
                                                      float* __restrict__ xn) {
    int t = blockIdx.x;
    int tid = threadIdx.x;
    float v = x[(size_t)t * DM + tid];
    float ss = v * v;
    #pragma unroll
    for (int m = 1; m < 64; m <<= 1) ss += __shfl_xor(ss, m);
    __shared__ float ws[4];
    if ((tid & 63) == 0) ws[tid >> 6] = ss;
    __syncthreads();
    float tot = ws[0] + ws[1] + ws[2] + ws[3];
    float scale = rsqrtf(tot / (float)DM + 1e-5f);
    xn[(size_t)t * DM + tid] = v * scale;
}

// ---------------- generic tiled SGEMM: C = A[M,K] @ W[N,K]^T --------------
#define BM 64
#define BN 64
#define BKK 16
#define EPI_PLAIN 0
#define EPI_SPLIT 1   // cols<DI -> C0 (xh), cols>=DI -> C1 (z), ldc=DI
#define EPI_OUT_F 2   // C0 = acc + 2*X
#define EPI_OUT_B 3   // C0 += acc

template <int EPI>
__global__ __launch_bounds__(256) void sgemm_kernel(
    const float* __restrict__ A, const float* __restrict__ W,
    const float* __restrict__ colscale, const float* __restrict__ gateZ,
    float* __restrict__ C0, float* __restrict__ C1,
    const float* __restrict__ X,
    int M, int N, int K) {
    __shared__ float As[BKK][BM + 4];
    __shared__ float Bs[BKK][BN + 4];
    int tid = threadIdx.x;
    int m0 = blockIdx.y * BM;
    int n0 = blockIdx.x * BN;
    int tn = tid & 15, tm = tid >> 4;
    int lrow = tid >> 2;
    int lq = (tid & 3) * 4;
    float acc[4][4] = {};

    for (int k0 = 0; k0 < K; k0 += BKK) {
        // stage A (rows m0+lrow), transposed into As[k][m]
        {
            const float* src = &A[(size_t)(m0 + lrow) * K + k0 + lq];
            float4 v = *(const float4*)src;
            if (colscale) {
                v.x *= colscale[k0 + lq + 0];
                v.y *= colscale[k0 + lq + 1];
                v.z *= colscale[k0 + lq + 2];
                v.w *= colscale[k0 + lq + 3];
            }
            if (gateZ) {
                float4 zv = *(const float4*)&gateZ[(size_t)(m0 + lrow) * K + k0 + lq];
                v.x *= zv.x / (1.f + __expf(-zv.x));
                v.y *= zv.y / (1.f + __expf(-zv.y));
                v.z *= zv.z / (1.f + __expf(-zv.z));
                v.w *= zv.w / (1.f + __expf(-zv.w));
            }
            As[lq + 0][lrow] = v.x; As[lq + 1][lrow] = v.y;
            As[lq + 2][lrow] = v.z; As[lq + 3][lrow] = v.w;
        }
        // stage W (rows n0+lrow), transposed into Bs[k][n]
        {
            int n = n0 + lrow;
            float4 v = make_float4(0.f, 0.f, 0.f, 0.f);
            if (n < N) v = *(const float4*)&W[(size_t)n * K + k0 + lq];
            Bs[lq + 0][lrow] = v.x; Bs[lq + 1][lrow] = v.y;
            Bs[lq + 2][lrow] = v.z; Bs[lq + 3][lrow] = v.w;
        }
        __syncthreads();
        #pragma unroll
        for (int k = 0; k < BKK; ++k) {
            float4 a = *(const float4*)&As[k][tm * 4];
            float4 b = *(const float4*)&Bs[k][tn * 4];
            float av[4] = {a.x, a.y, a.z, a.w};
            float bv[4] = {b.x, b.y, b.z, b.w};
            #pragma unroll
            for (int i = 0; i < 4; ++i)
                #pragma unroll
                for (int j = 0; j < 4; ++j)
                    acc[i][j] = fmaf(av[i], bv[j], acc[i][j]);
        }
        __syncthreads();
    }

    #pragma unroll
    for (int i = 0; i < 4; ++i) {
        int m = m0 + tm * 4 + i;
        #pragma unroll
        for (int j = 0; j < 4; ++j) {
            int n = n0 + tn * 4 + j;
            if (n >= N) continue;
            float v = acc[i][j];
            if (EPI == EPI_PLAIN) {
                C0[(size_t)m * N + n] = v;
            } else if (EPI == EPI_SPLIT) {
                if (n < DI) C0[(size_t)m * DI + n] = v;
                else        C1[(size_t)m * DI + (n - DI)] = v;
            } else if (EPI == EPI_OUT_F) {
                C0[(size_t)m * DM + n] = v + 2.f * X[(size_t)m * DM + n];
            } else { // EPI_OUT_B
                C0[(size_t)m * DM + n] += v;
            }
        }
    }
}

// ---------------- depthwise causal/anticausal conv4 + silu ----------------
__global__ __launch_bounds__(256) void conv_silu_kernel(
    const float* __restrict__ xh, const float* __restrict__ cw,
    const float* __restrict__ cb, float* __restrict__ xc, int dir) {
    int idx = blockIdx.x * 256 + threadIdx.x;   // t*DI + c
    int c = idx & (DI - 1);
    int t = idx >> 9;
    int l = t & (LL - 1);
    float acc = cb[c];
    #pragma unroll
    for (int k = 0; k < 4; ++k) {
        int lo = (dir == 0) ? (l - 3 + k) : (l + 3 - k);
        if (lo >= 0 && lo < LL)
            acc = fmaf(xh[(size_t)(t + lo - l) * DI + c], cw[c * 4 + k], acc);
    }
    float s = acc / (1.f + __expf(-acc));
    xc[idx] = s;
}

// ---------------- delta = softplus(dt @ dt_w.T + dt_b) --------------------
__global__ __launch_bounds__(256) void delta_kernel(
    const float* __restrict__ xdbl, const float* __restrict__ dtw,
    const float* __restrict__ dtb, float* __restrict__ delta) {
    int t = blockIdx.x;
    int tid = threadIdx.x;
    __shared__ float sdt[DTR];
    if (tid < DTR) sdt[tid] = xdbl[(size_t)t * 48 + tid];
    __syncthreads();
    for (int d = tid; d < DI; d += 256) {
        float acc = dtb[d];
        #pragma unroll
        for (int r = 0; r < DTR; ++r) acc = fmaf(sdt[r], dtw[d * DTR + r], acc);
        float sp = (acc > 20.f) ? acc : log1pf(__expf(acc));
        delta[(size_t)t * DI + d] = sp;
    }
}

// ---------------- scan phase 1: per-chunk local scan -> AC, HC ------------
// block: 256 thr = 64 d x 4 nq (4 n-states each); grid (DI/64, B*NCH, 2)
__global__ __launch_bounds__(256) void scan_part1(
    const float* __restrict__ delta_f, const float* __restrict__ delta_b,
    const float* __restrict__ xc_f, const float* __restrict__ xc_b,
    const float* __restrict__ xdbl_f, const float* __restrict__ xdbl_b,
    const float* __restrict__ Alog_f, const float* __restrict__ Alog_b,
    float* __restrict__ AC, float* __restrict__ HC) {
    int dir = blockIdx.z;
    const float* delta = dir ? delta_b : delta_f;
    const float* xc    = dir ? xc_b    : xc_f;
    const float* xdbl  = dir ? xdbl_b  : xdbl_f;
    const float* Alog  = dir ? Alog_b  : Alog_f;
    int b  = blockIdx.y >> 5;
    int ch = blockIdx.y & 31;
    int d0 = blockIdx.x * 64;
    int tid = threadIdx.x;
    int dg = tid >> 2, nq = tid & 3;
    int d = d0 + dg;

    __shared__ float2 sdx[CL][65];      // (delta, xc) per (l, d)
    __shared__ float4 sB4[CL][4];       // B per (l, n-quad)

    {   // stage
        int row = tid >> 2, qq = (tid & 3) * 16;
        int lr = ch * CL + row;
        int l = dir ? (LL - 1 - lr) : lr;
        size_t t = (size_t)b * LL + l;
        const float* drow = &delta[t * DI + d0 + qq];
        const float* xrow = &xc[t * DI + d0 + qq];
        #pragma unroll
        for (int i = 0; i < 4; ++i) {
            float4 dv = *(const float4*)(drow + 4 * i);
            float4 xv = *(const float4*)(xrow + 4 * i);
            sdx[row][qq + 4 * i + 0] = make_float2(dv.x, xv.x);
            sdx[row][qq + 4 * i + 1] = make_float2(dv.y, xv.y);
            sdx[row][qq + 4 * i + 2] = make_float2(dv.z, xv.z);
            sdx[row][qq + 4 * i + 3] = make_float2(dv.w, xv.w);
        }
        sB4[row][tid & 3] = *(const float4*)&xdbl[t * 48 + DTR + (tid & 3) * 4];
    }
    __syncthreads();

    float4 Al = *(const float4*)&Alog[d * DS2 + nq * 4];
    float Av[4] = {-__expf(Al.x), -__expf(Al.y), -__expf(Al.z), -__expf(Al.w)};
    float h[4] = {0.f, 0.f, 0.f, 0.f};
    float sdl = 0.f;

    for (int r = 0; r < CL; ++r) {
        float2 dx = sdx[r][dg];
        float4 Bv = sB4[r][nq];
        float u0 = dx.x * dx.y;
        sdl += dx.x;
        h[0] = fmaf(__expf(dx.x * Av[0]), h[0], u0 * Bv.x);
        h[1] = fmaf(__expf(dx.x * Av[1]), h[1], u0 * Bv.y);
        h[2] = fmaf(__expf(dx.x * Av[2]), h[2], u0 * Bv.z);
        h[3] = fmaf(__expf(dx.x * Av[3]), h[3], u0 * Bv.w);
    }

    size_t base = (size_t)ch * PLANE + (size_t)(((dir * 4 + b) * DI + d) * DS2 + nq * 4);
    *(float4*)&AC[base] = make_float4(__expf(Av[0] * sdl), __expf(Av[1] * sdl),
                                      __expf(Av[2] * sdl), __expf(Av[3] * sdl));
    *(float4*)&HC[base] = make_float4(h[0], h[1], h[2], h[3]);
}

// ---------------- scan phase 2: sequential chunk combine -> HIN -----------
__global__ __launch_bounds__(256) void scan_part2(
    const float* __restrict__ AC, const float* __restrict__ HC,
    float* __restrict__ HIN) {
    int idx = blockIdx.x * 256 + threadIdx.x;
    float hin = 0.f;
    #pragma unroll
    for (int ch = 0; ch < NCH; ++ch) {
        size_t o = (size_t)ch * PLANE + idx;
        HIN[o] = hin;
        hin = fmaf(AC[o], hin, HC[o]);
    }
}

// ---------------- scan phase 3: replay with carry-in, emit raw y ----------
__global__ __launch_bounds__(256) void scan_part3(
    const float* __restrict__ delta_f, const float* __restrict__ delta_b,
    const float* __restrict__ xc_f, const float* __restrict__ xc_b,
    const float* __restrict__ xdbl_f, const float* __restrict__ xdbl_b,
    const float* __restrict__ Alog_f, const float* __restrict__ Alog_b,
    const float* __restrict__ Dp_f, const float* __restrict__ Dp_b,
    const float* __restrict__ HIN,
    float* __restrict__ y_f, float* __restrict__ y_b) {
    int dir = blockIdx.z;
    const float* delta = dir ? delta_b : delta_f;
    const float* xc    = dir ? xc_b    : xc_f;
    const float* xdbl  = dir ? xdbl_b  : xdbl_f;
    const float* Alog  = dir ? Alog_b  : Alog_f;
    const float* Dp    = dir ? Dp_b    : Dp_f;
    float* y           = dir ? y_b     : y_f;
    int b  = blockIdx.y >> 5;
    int ch = blockIdx.y & 31;
    int d0 = blockIdx.x * 64;
    int tid = threadIdx.x;
    int dg = tid >> 2, nq = tid & 3;
    int d = d0 + dg;

    __shared__ float2 sdx[CL][65];
    __shared__ float4 sB4[CL][4];
    __shared__ float4 sC4[CL][4];

    {   // stage
        int row = tid >> 2, qq = (tid & 3) * 16;
        int lr = ch * CL + row;
        int l = dir ? (LL - 1 - lr) : lr;
        size_t t = (size_t)b * LL + l;
        const float* drow = &delta[t * DI + d0 + qq];
        const float* xrow = &xc[t * DI + d0 + qq];
        #pragma unroll
        for (int i = 0; i < 4; ++i) {
            float4 dv = *(const float4*)(drow + 4 * i);
            float4 xv = *(const float4*)(xrow + 4 * i);
            sdx[row][qq + 4 * i + 0] = make_float2(dv.x, xv.x);
            sdx[row][qq + 4 * i + 1] = make_float2(dv.y, xv.y);
            sdx[row][qq + 4 * i + 2] = make_float2(dv.z, xv.z);
            sdx[row][qq + 4 * i + 3] = make_float2(dv.w, xv.w);
        }
        sB4[row][tid & 3] = *(const float4*)&xdbl[t * 48 + DTR + (tid & 3) * 4];
        sC4[row][tid & 3] = *(const float4*)&xdbl[t * 48 + DTR + DS2 + (tid & 3) * 4];
    }
    __syncthreads();

    float4 Al = *(const float4*)&Alog[d * DS2 + nq * 4];
    float Av[4] = {-__expf(Al.x), -__expf(Al.y), -__expf(Al.z), -__expf(Al.w)};
    float Dv = Dp[d];
    size_t base = (size_t)ch * PLANE + (size_t)(((dir * 4 + b) * DI + d) * DS2 + nq * 4);
    float4 h4 = *(const float4*)&HIN[base];
    float h[4] = {h4.x, h4.y, h4.z, h4.w};

    for (int r = 0; r < CL; ++r) {
        float2 dx = sdx[r][dg];
        float4 Bv = sB4[r][nq];
        float4 Cv = sC4[r][nq];
        float u0 = dx.x * dx.y;
        h[0] = fmaf(__expf(dx.x * Av[0]), h[0], u0 * Bv.x);
        h[1] = fmaf(__expf(dx.x * Av[1]), h[1], u0 * Bv.y);
        h[2] = fmaf(__expf(dx.x * Av[2]), h[2], u0 * Bv.z);
        h[3] = fmaf(__expf(dx.x * Av[3]), h[3], u0 * Bv.w);
        float ts = fmaf(h[0], Cv.x, fmaf(h[1], Cv.y, fmaf(h[2], Cv.z, h[3] * Cv.w)));
        ts += __shfl_xor(ts, 1);
        ts += __shfl_xor(ts, 2);
        if (nq == 0) {
            int lr = ch * CL + r;
            int ll = dir ? (LL - 1 - lr) : lr;
            y[((size_t)b * LL + ll) * DI + d] = fmaf(dx.y, Dv, ts);
        }
    }
}

// -------------------------------------------------------------------------
extern "C" void kernel_launch(void* const* d_in, const int* in_sizes, int n_in,
                              void* d_out, int out_size, void* d_ws, size_t ws_size,
                              hipStream_t stream) {
    const float* x = (const float*)d_in[0];
    const float* p[2][10];
    for (int dir = 0; dir < 2; ++dir)
        for (int i = 0; i < 10; ++i)
            p[dir][i] = (const float*)d_in[1 + dir * 10 + i];
    // p[dir]: 0 norm, 1 in_proj, 2 conv_w, 3 conv_b, 4 x_proj,
    //         5 dt_w, 6 dt_b, 7 A_log, 8 D, 9 out_proj

    float* ws = (float*)d_ws;
    size_t off = 0;
    float* xn = ws + off; off += (size_t)NTOK * DM;   // dead after in_proj -> reused as AC
    float* xh[2]; float* zb[2]; float* xcb[2]; float* dlt[2]; float* xdbl[2];
    for (int dir = 0; dir < 2; ++dir) {
        xh[dir]   = ws + off; off += (size_t)NTOK * DI;   // later reused as raw y
        zb[dir]   = ws + off; off += (size_t)NTOK * DI;
        xcb[dir]  = ws + off; off += (size_t)NTOK * DI;
        dlt[dir]  = ws + off; off += (size_t)NTOK * DI;
        xdbl[dir] = ws + off; off += (size_t)NTOK * 48;
    }
    float* AC  = xn;                                   // 2,097,152 floats = exact fit
    float* HC  = ws + off; off += (size_t)NCH * PLANE;
    float* HIN = ws + off; off += (size_t)NCH * PLANE;
    float* out = (float*)d_out;

    rmsnorm_kernel<<<NTOK, 256, 0, stream>>>(x, xn);

    for (int dir = 0; dir < 2; ++dir) {
        sgemm_kernel<EPI_SPLIT><<<dim3(1024 / BN, NTOK / BM), 256, 0, stream>>>(
            xn, p[dir][1], p[dir][0], nullptr, xh[dir], zb[dir], nullptr, NTOK, 2 * DI, DM);
        conv_silu_kernel<<<(NTOK * DI) / 256, 256, 0, stream>>>(
            xh[dir], p[dir][2], p[dir][3], xcb[dir], dir);
        sgemm_kernel<EPI_PLAIN><<<dim3(1, NTOK / BM), 256, 0, stream>>>(
            xcb[dir], p[dir][4], nullptr, nullptr, xdbl[dir], nullptr, nullptr, NTOK, 48, DI);
        delta_kernel<<<NTOK, 256, 0, stream>>>(xdbl[dir], p[dir][5], p[dir][6], dlt[dir]);
    }

    scan_part1<<<dim3(DI / 64, 4 * NCH, 2), 256, 0, stream>>>(
        dlt[0], dlt[1], xcb[0], xcb[1], xdbl[0], xdbl[1], p[0][7], p[1][7], AC, HC);
    scan_part2<<<PLANE / 256, 256, 0, stream>>>(AC, HC, HIN);
    scan_part3<<<dim3(DI / 64, 4 * NCH, 2), 256, 0, stream>>>(
        dlt[0], dlt[1], xcb[0], xcb[1], xdbl[0], xdbl[1], p[0][7], p[1][7],
        p[0][8], p[1][8], HIN, xh[0], xh[1]);

    // out_proj with y*silu(z) gating folded into A-staging
    sgemm_kernel<EPI_OUT_F><<<dim3(DM / BN, NTOK / BM), 256, 0, stream>>>(
        xh[0], p[0][9], nullptr, zb[0], out, nullptr, x, NTOK, DM, DI);
    sgemm_kernel<EPI_OUT_B><<<dim3(DM / BN, NTOK / BM), 256, 0, stream>>>(
        xh[1], p[1][9], nullptr, zb[1], out, nullptr, nullptr, NTOK, DM, DI);
}

// Round 3
// 298.953 us; speedup vs baseline: 3.1032x; 1.6631x over previous
//
#include <hip/hip_runtime.h>
#include <hip/hip_bf16.h>
#include <math.h>

// Bidirectional Mamba block. Round 3: bf16 MFMA GEMMs + bf16 activations.
// prep: weights->bf16, norm folded into in_proj, dt-path fused:
//       Wd = dt_w @ x_proj_dt  => delta_lin = xc @ [Wd; x_proj_BC]^T (+dt_b, softplus)
// gemm IN : xn[8192,256] @ w_in[2048,256]^T  -> xh,z (both dirs, bf16)
// conv+silu (bf16)
// gemm P2 : xc[8192,512] @ w_p2[576,512]^T   -> dlt (softplus), bc  (grid.z=2)
// scan p1/p2/p3 (chunked, fp32 math, bf16 IO); p3 fuses y*silu(z) -> ycat
// gemm OUT: ycat[8192,1024] @ w_out[256,1024]^T -> out = acc + 2x

#define NTOK 8192
#define LL   2048
#define DM   256
#define DI   512
#define DS2  16
#define CL   64
#define NCH  32
#define PLANE 65536
#define KSTEP 64

typedef __bf16 bf16x8 __attribute__((ext_vector_type(8)));
typedef float f32x4 __attribute__((ext_vector_type(4)));

__device__ inline unsigned short f2bf(float f) {
    unsigned u = __float_as_uint(f);
    unsigned r = (u + 0x7fffu + ((u >> 16) & 1u)) >> 16;
    return (unsigned short)r;
}
__device__ inline float bf2f(unsigned short s) {
    return __uint_as_float((unsigned)s << 16);
}

#define GLDS(gp, lp) __builtin_amdgcn_global_load_lds( \
    (const __attribute__((address_space(1))) void*)(gp), \
    (__attribute__((address_space(3))) void*)(lp), 16, 0, 0)

// ---------------- prep: weight conversion / folding -----------------------
__global__ __launch_bounds__(256) void prep_kernel(
    const float* __restrict__ ip0, const float* __restrict__ nw0,
    const float* __restrict__ ip1, const float* __restrict__ nw1,
    const float* __restrict__ xp0, const float* __restrict__ dtw0,
    const float* __restrict__ xp1, const float* __restrict__ dtw1,
    const float* __restrict__ op0, const float* __restrict__ op1,
    unsigned short* __restrict__ w_in, unsigned short* __restrict__ w_p2,
    unsigned short* __restrict__ w_out) {
    int bid = blockIdx.x, tid = threadIdx.x;
    if (bid < 2048) {                       // in_proj rows, norm folded
        int dir = bid >> 10, n = bid & 1023;
        const float* ip = dir ? ip1 : ip0;
        const float* nw = dir ? nw1 : nw0;
        w_in[(size_t)bid * 256 + tid] = f2bf(ip[n * 256 + tid] * nw[tid]);
    } else if (bid < 3200) {                // w_p2 rows (576 per dir)
        int idx = bid - 2048;
        int dir = idx / 576, row = idx % 576;
        const float* xp = dir ? xp1 : xp0;
        const float* dtw = dir ? dtw1 : dtw0;
        unsigned short* dst = w_p2 + (size_t)idx * 512;
        for (int k = tid; k < 512; k += 256) {
            float v = 0.f;
            if (row < 512) {
                #pragma unroll
                for (int r = 0; r < 16; ++r) v = fmaf(dtw[row * 16 + r], xp[r * 512 + k], v);
            } else if (row < 544) {
                v = xp[(16 + row - 512) * 512 + k];
            }
            dst[k] = f2bf(v);
        }
    } else {                                // w_out rows (256), K=1024 concat
        int n = bid - 3200;
        for (int k = tid; k < 1024; k += 256) {
            float v = (k < 512) ? op0[n * 512 + k] : op1[n * 512 + (k - 512)];
            w_out[(size_t)n * 1024 + k] = f2bf(v);
        }
    }
}

// ---------------- rmsnorm -> bf16 -----------------------------------------
__global__ __launch_bounds__(256) void rmsnorm_kernel(const float* __restrict__ x,
                                                      unsigned short* __restrict__ xn) {
    int t = blockIdx.x;
    int tid = threadIdx.x;
    float v = x[(size_t)t * DM + tid];
    float ss = v * v;
    #pragma unroll
    for (int m = 1; m < 64; m <<= 1) ss += __shfl_xor(ss, m);
    __shared__ float ws[4];
    if ((tid & 63) == 0) ws[tid >> 6] = ss;
    __syncthreads();
    float tot = ws[0] + ws[1] + ws[2] + ws[3];
    float scale = rsqrtf(tot / (float)DM + 1e-5f);
    xn[(size_t)t * DM + tid] = f2bf(v * scale);
}

// ---------------- bf16 MFMA GEMM: C = A[M,K] @ W[N,K]^T -------------------
// 64x64 tile, 4 waves (2x2), KSTEP=64, double-buffered LDS, XOR chunk swizzle.
#define EPI_IN  0
#define EPI_P2  1
#define EPI_OUT 2

template <int EPI>
__global__ __launch_bounds__(256) void mfma_gemm(
    const unsigned short* __restrict__ A0, const unsigned short* __restrict__ A1,
    const unsigned short* __restrict__ Wb, int K,
    unsigned short* __restrict__ d0, unsigned short* __restrict__ d1,
    unsigned short* __restrict__ e0, unsigned short* __restrict__ e1,
    const float* __restrict__ aux0, const float* __restrict__ aux1,
    const float* __restrict__ Xres, float* __restrict__ outF) {
    __shared__ char lds[2][2][8192];     // [buf][A/B][64 rows * 128B]
    int tid = threadIdx.x;
    int lane = tid & 63, wid = tid >> 6;
    int wm = wid >> 1, wn = wid & 1;
    int m0 = blockIdx.y * 64;
    int n0 = blockIdx.x * 64;
    int dir = blockIdx.z;
    const unsigned short* A = dir ? A1 : A0;
    const unsigned short* W = Wb + ((EPI == EPI_P2) ? (size_t)dir * 576 * 512 : 0);

    // staging chunk mapping: linear slot s -> row=s>>3, stored chunk c=(s&7)^(row&7)
    const int s1 = tid, s2 = tid + 256;
    const int r1 = s1 >> 3, c1 = (s1 & 7) ^ (r1 & 7);
    const int r2 = s2 >> 3, c2 = (s2 & 7) ^ (r2 & 7);

    f32x4 acc[2][2] = {};
    int nt = K / KSTEP;

    auto stage = [&](int t, int buf) {
        int k0 = t * KSTEP;
        GLDS(A + (size_t)(m0 + r1) * K + k0 + c1 * 8, &lds[buf][0][0] + wid * 1024);
        GLDS(A + (size_t)(m0 + r2) * K + k0 + c2 * 8, &lds[buf][0][0] + 4096 + wid * 1024);
        GLDS(W + (size_t)(n0 + r1) * K + k0 + c1 * 8, &lds[buf][1][0] + wid * 1024);
        GLDS(W + (size_t)(n0 + r2) * K + k0 + c2 * 8, &lds[buf][1][0] + 4096 + wid * 1024);
    };

    stage(0, 0);
    for (int t = 0; t < nt; ++t) {
        int buf = t & 1;
        __syncthreads();                 // drains vmcnt: buf ready, prev reads done
        if (t + 1 < nt) stage(t + 1, buf ^ 1);
        const char* Ab = &lds[buf][0][0];
        const char* Bb = &lds[buf][1][0];
        bf16x8 af[2][2], bfv[2][2];
        #pragma unroll
        for (int mf = 0; mf < 2; ++mf)
            #pragma unroll
            for (int kf = 0; kf < 2; ++kf) {
                int r = wm * 32 + mf * 16 + (lane & 15);
                int c = (lane >> 4) + kf * 4;
                af[mf][kf] = *(const bf16x8*)(Ab + r * 128 + ((c ^ (r & 7)) << 4));
            }
        #pragma unroll
        for (int nf = 0; nf < 2; ++nf)
            #pragma unroll
            for (int kf = 0; kf < 2; ++kf) {
                int r = wn * 32 + nf * 16 + (lane & 15);
                int c = (lane >> 4) + kf * 4;
                bfv[nf][kf] = *(const bf16x8*)(Bb + r * 128 + ((c ^ (r & 7)) << 4));
            }
        #pragma unroll
        for (int kf = 0; kf < 2; ++kf)
            #pragma unroll
            for (int mf = 0; mf < 2; ++mf)
                #pragma unroll
                for (int nf = 0; nf < 2; ++nf)
                    acc[mf][nf] = __builtin_amdgcn_mfma_f32_16x16x32_bf16(
                        af[mf][kf], bfv[nf][kf], acc[mf][nf], 0, 0, 0);
    }

    // epilogue: C/D layout col=lane&15, row=(lane>>4)*4+reg
    int cb0 = n0 + wn * 32 + (lane & 15);
    int rb0 = m0 + wm * 32 + ((lane >> 4) << 2);
    #pragma unroll
    for (int mf = 0; mf < 2; ++mf)
        #pragma unroll
        for (int nf = 0; nf < 2; ++nf) {
            int n = cb0 + nf * 16;
            #pragma unroll
            for (int r = 0; r < 4; ++r) {
                int m = rb0 + mf * 16 + r;
                float v = acc[mf][nf][r];
                if (EPI == EPI_IN) {
                    int dd = n >> 10, c = n & 1023;
                    unsigned short* dst = (c < 512)
                        ? (dd ? d1 : d0) + (size_t)m * 512 + c
                        : (dd ? e1 : e0) + (size_t)m * 512 + (c - 512);
                    *dst = f2bf(v);
                } else if (EPI == EPI_P2) {
                    if (n < 512) {
                        float sv = v + (dir ? aux1 : aux0)[n];
                        float sp = (sv > 20.f) ? sv : log1pf(__expf(sv));
                        (dir ? d1 : d0)[(size_t)m * 512 + n] = f2bf(sp);
                    } else if (n < 544) {
                        (dir ? e1 : e0)[(size_t)m * 32 + (n - 512)] = f2bf(v);
                    }
                } else {
                    outF[(size_t)m * 256 + n] = v + 2.f * Xres[(size_t)m * 256 + n];
                }
            }
        }
}

// ---------------- depthwise conv4 + silu (bf16, 8 ch/thread) --------------
__global__ __launch_bounds__(256) void conv_silu_kernel(
    const unsigned short* __restrict__ xh0, const unsigned short* __restrict__ xh1,
    const float* __restrict__ cw0, const float* __restrict__ cw1,
    const float* __restrict__ cb0, const float* __restrict__ cb1,
    unsigned short* __restrict__ o0, unsigned short* __restrict__ o1) {
    int dir = blockIdx.y;
    const unsigned short* xh = dir ? xh1 : xh0;
    const float* cw = dir ? cw1 : cw0;
    const float* cb = dir ? cb1 : cb0;
    unsigned short* xc = dir ? o1 : o0;
    int idx8 = blockIdx.x * 256 + threadIdx.x;
    int t = idx8 >> 6;
    int c8 = (idx8 & 63) << 3;
    int l = t & (LL - 1);
    float acc[8];
    #pragma unroll
    for (int j = 0; j < 8; ++j) acc[j] = cb[c8 + j];
    #pragma unroll
    for (int k = 0; k < 4; ++k) {
        int lo = dir ? (l + 3 - k) : (l - 3 + k);
        if (lo < 0 || lo >= LL) continue;
        uint4 u = *(const uint4*)(xh + (size_t)(t + lo - l) * DI + c8);
        unsigned wv[4] = {u.x, u.y, u.z, u.w};
        #pragma unroll
        for (int j = 0; j < 4; ++j) {
            float flo = __uint_as_float(wv[j] << 16);
            float fhi = __uint_as_float(wv[j] & 0xffff0000u);
            acc[2 * j]     = fmaf(flo, cw[(c8 + 2 * j) * 4 + k], acc[2 * j]);
            acc[2 * j + 1] = fmaf(fhi, cw[(c8 + 2 * j + 1) * 4 + k], acc[2 * j + 1]);
        }
    }
    unsigned out[4];
    #pragma unroll
    for (int j = 0; j < 4; ++j) {
        float a0 = acc[2 * j], a1 = acc[2 * j + 1];
        float s0 = a0 / (1.f + __expf(-a0));
        float s1 = a1 / (1.f + __expf(-a1));
        out[j] = (unsigned)f2bf(s0) | ((unsigned)f2bf(s1) << 16);
    }
    *(uint4*)(xc + (size_t)idx8 * 8) = make_uint4(out[0], out[1], out[2], out[3]);
}

// ---------------- scan phase 1: per-chunk local scan -> AC, HC ------------
__global__ __launch_bounds__(256) void scan_part1(
    const unsigned short* __restrict__ dlt0, const unsigned short* __restrict__ dlt1,
    const unsigned short* __restrict__ xc0, const unsigned short* __restrict__ xc1,
    const unsigned short* __restrict__ bc0, const unsigned short* __restrict__ bc1,
    const float* __restrict__ Al0, const float* __restrict__ Al1,
    float* __restrict__ AC, float* __restrict__ HC) {
    int dir = blockIdx.z;
    const unsigned short* delta = dir ? dlt1 : dlt0;
    const unsigned short* xc    = dir ? xc1 : xc0;
    const unsigned short* bc    = dir ? bc1 : bc0;
    const float* Alog           = dir ? Al1 : Al0;
    int b = blockIdx.y >> 5, ch = blockIdx.y & 31;
    int d0 = blockIdx.x * 64;
    int tid = threadIdx.x;
    int dg = tid >> 2, nq = tid & 3;
    int d = d0 + dg;

    __shared__ float2 sdx[CL][65];
    __shared__ float4 sB4[CL][4];
    {
        int row = tid >> 2, q = tid & 3;
        int lr = ch * CL + row;
        int l = dir ? (LL - 1 - lr) : lr;
        size_t t = (size_t)b * LL + l;
        const uint4* dp = (const uint4*)(delta + t * DI + d0 + q * 16);
        const uint4* xp = (const uint4*)(xc + t * DI + d0 + q * 16);
        #pragma unroll
        for (int h = 0; h < 2; ++h) {
            uint4 du = dp[h], xu = xp[h];
            unsigned dw[4] = {du.x, du.y, du.z, du.w};
            unsigned xw[4] = {xu.x, xu.y, xu.z, xu.w};
            #pragma unroll
            for (int j = 0; j < 4; ++j) {
                sdx[row][q * 16 + h * 8 + j * 2 + 0] =
                    make_float2(__uint_as_float(dw[j] << 16), __uint_as_float(xw[j] << 16));
                sdx[row][q * 16 + h * 8 + j * 2 + 1] =
                    make_float2(__uint_as_float(dw[j] & 0xffff0000u), __uint_as_float(xw[j] & 0xffff0000u));
            }
        }
        if (q < 2) {
            uint4 bu = *(const uint4*)(bc + t * 32 + q * 8);
            unsigned bw[4] = {bu.x, bu.y, bu.z, bu.w};
            float f[8];
            #pragma unroll
            for (int j = 0; j < 4; ++j) {
                f[2 * j] = __uint_as_float(bw[j] << 16);
                f[2 * j + 1] = __uint_as_float(bw[j] & 0xffff0000u);
            }
            sB4[row][q * 2 + 0] = make_float4(f[0], f[1], f[2], f[3]);
            sB4[row][q * 2 + 1] = make_float4(f[4], f[5], f[6], f[7]);
        }
    }
    __syncthreads();

    float4 Al = *(const float4*)&Alog[d * DS2 + nq * 4];
    float Av[4] = {-__expf(Al.x), -__expf(Al.y), -__expf(Al.z), -__expf(Al.w)};
    float h[4] = {0.f, 0.f, 0.f, 0.f};
    float sdl = 0.f;
    for (int r = 0; r < CL; ++r) {
        float2 dx = sdx[r][dg];
        float4 Bv = sB4[r][nq];
        float u0 = dx.x * dx.y;
        sdl += dx.x;
        h[0] = fmaf(__expf(dx.x * Av[0]), h[0], u0 * Bv.x);
        h[1] = fmaf(__expf(dx.x * Av[1]), h[1], u0 * Bv.y);
        h[2] = fmaf(__expf(dx.x * Av[2]), h[2], u0 * Bv.z);
        h[3] = fmaf(__expf(dx.x * Av[3]), h[3], u0 * Bv.w);
    }
    size_t base = (size_t)ch * PLANE + (size_t)(((dir * 4 + b) * DI + d) * DS2 + nq * 4);
    *(float4*)&AC[base] = make_float4(__expf(Av[0] * sdl), __expf(Av[1] * sdl),
                                      __expf(Av[2] * sdl), __expf(Av[3] * sdl));
    *(float4*)&HC[base] = make_float4(h[0], h[1], h[2], h[3]);
}

// ---------------- scan phase 2: sequential chunk combine ------------------
__global__ __launch_bounds__(256) void scan_part2(
    const float* __restrict__ AC, const float* __restrict__ HC,
    float* __restrict__ HIN) {
    int idx = blockIdx.x * 256 + threadIdx.x;
    float hin = 0.f;
    #pragma unroll
    for (int ch = 0; ch < NCH; ++ch) {
        size_t o = (size_t)ch * PLANE + idx;
        HIN[o] = hin;
        hin = fmaf(AC[o], hin, HC[o]);
    }
}

// ---------------- scan phase 3: replay, gate with silu(z), -> ycat --------
__global__ __launch_bounds__(256) void scan_part3(
    const unsigned short* __restrict__ dlt0, const unsigned short* __restrict__ dlt1,
    const unsigned short* __restrict__ xc0, const unsigned short* __restrict__ xc1,
    const unsigned short* __restrict__ bc0, const unsigned short* __restrict__ bc1,
    const unsigned short* __restrict__ z0, const unsigned short* __restrict__ z1,
    const float* __restrict__ Al0, const float* __restrict__ Al1,
    const float* __restrict__ Dp0, const float* __restrict__ Dp1,
    const float* __restrict__ HIN, unsigned short* __restrict__ ycat) {
    int dir = blockIdx.z;
    const unsigned short* delta = dir ? dlt1 : dlt0;
    const unsigned short* xc    = dir ? xc1 : xc0;
    const unsigned short* bc    = dir ? bc1 : bc0;
    const unsigned short* zb    = dir ? z1 : z0;
    const float* Alog           = dir ? Al1 : Al0;
    const float* Dp             = dir ? Dp1 : Dp0;
    int b = blockIdx.y >> 5, ch = blockIdx.y & 31;
    int d0 = blockIdx.x * 64;
    int tid = threadIdx.x;
    int dg = tid >> 2, nq = tid & 3;
    int d = d0 + dg;

    __shared__ float2 sdx[CL][65];
    __shared__ float4 sB4[CL][4];
    __shared__ float4 sC4[CL][4];
    {
        int row = tid >> 2, q = tid & 3;
        int lr = ch * CL + row;
        int l = dir ? (LL - 1 - lr) : lr;
        size_t t = (size_t)b * LL + l;
        const uint4* dp = (const uint4*)(delta + t * DI + d0 + q * 16);
        const uint4* xp = (const uint4*)(xc + t * DI + d0 + q * 16);
        #pragma unroll
        for (int h = 0; h < 2; ++h) {
            uint4 du = dp[h], xu = xp[h];
            unsigned dw[4] = {du.x, du.y, du.z, du.w};
            unsigned xw[4] = {xu.x, xu.y, xu.z, xu.w};
            #pragma unroll
            for (int j = 0; j < 4; ++j) {
                sdx[row][q * 16 + h * 8 + j * 2 + 0] =
                    make_float2(__uint_as_float(dw[j] << 16), __uint_as_float(xw[j] << 16));
                sdx[row][q * 16 + h * 8 + j * 2 + 1] =
                    make_float2(__uint_as_float(dw[j] & 0xffff0000u), __uint_as_float(xw[j] & 0xffff0000u));
            }
        }
        uint4 bu = *(const uint4*)(bc + t * 32 + (q & 1) * 8 + (q >> 1) * 16);
        unsigned bw[4] = {bu.x, bu.y, bu.z, bu.w};
        float f[8];
        #pragma unroll
        for (int j = 0; j < 4; ++j) {
            f[2 * j] = __uint_as_float(bw[j] << 16);
            f[2 * j + 1] = __uint_as_float(bw[j] & 0xffff0000u);
        }
        float4 v0 = make_float4(f[0], f[1], f[2], f[3]);
        float4 v1 = make_float4(f[4], f[5], f[6], f[7]);
        if (q < 2) { sB4[row][q * 2] = v0; sB4[row][q * 2 + 1] = v1; }
        else       { sC4[row][(q - 2) * 2] = v0; sC4[row][(q - 2) * 2 + 1] = v1; }
    }
    __syncthreads();

    float4 Al = *(const float4*)&Alog[d * DS2 + nq * 4];
    float Av[4] = {-__expf(Al.x), -__expf(Al.y), -__expf(Al.z), -__expf(Al.w)};
    float Dv = Dp[d];
    size_t base = (size_t)ch * PLANE + (size_t)(((dir * 4 + b) * DI + d) * DS2 + nq * 4);
    float4 h4 = *(const float4*)&HIN[base];
    float h[4] = {h4.x, h4.y, h4.z, h4.w};

    for (int r = 0; r < CL; ++r) {
        float2 dx = sdx[r][dg];
        float4 Bv = sB4[r][nq];
        float4 Cv = sC4[r][nq];
        float u0 = dx.x * dx.y;
        h[0] = fmaf(__expf(dx.x * Av[0]), h[0], u0 * Bv.x);
        h[1] = fmaf(__expf(dx.x * Av[1]), h[1], u0 * Bv.y);
        h[2] = fmaf(__expf(dx.x * Av[2]), h[2], u0 * Bv.z);
        h[3] = fmaf(__expf(dx.x * Av[3]), h[3], u0 * Bv.w);
        float ts = fmaf(h[0], Cv.x, fmaf(h[1], Cv.y, fmaf(h[2], Cv.z, h[3] * Cv.w)));
        ts += __shfl_xor(ts, 1);
        ts += __shfl_xor(ts, 2);
        if (nq == 0) {
            int lr = ch * CL + r;
            int ll = dir ? (LL - 1 - lr) : lr;
            size_t tt = (size_t)b * LL + ll;
            float yv = fmaf(dx.y, Dv, ts);
            float zz = bf2f(zb[tt * DI + d]);
            yv *= zz / (1.f + __expf(-zz));
            ycat[tt * 1024 + (size_t)dir * 512 + d] = f2bf(yv);
        }
    }
}

// -------------------------------------------------------------------------
extern "C" void kernel_launch(void* const* d_in, const int* in_sizes, int n_in,
                              void* d_out, int out_size, void* d_ws, size_t ws_size,
                              hipStream_t stream) {
    const float* x = (const float*)d_in[0];
    const float* p[2][10];
    for (int dir = 0; dir < 2; ++dir)
        for (int i = 0; i < 10; ++i)
            p[dir][i] = (const float*)d_in[1 + dir * 10 + i];
    // p[dir]: 0 norm, 1 in_proj, 2 conv_w, 3 conv_b, 4 x_proj,
    //         5 dt_w, 6 dt_b, 7 A_log, 8 D, 9 out_proj

    char* w = (char*)d_ws;
    auto alloc = [&](size_t bytes) { char* q = w; w += (bytes + 255) & ~(size_t)255; return q; };
    unsigned short* xn    = (unsigned short*)alloc((size_t)NTOK * DM * 2);
    unsigned short* w_in  = (unsigned short*)alloc((size_t)2048 * 256 * 2);
    unsigned short* w_p2  = (unsigned short*)alloc((size_t)1152 * 512 * 2);
    unsigned short* w_out = (unsigned short*)alloc((size_t)256 * 1024 * 2);
    unsigned short *xh[2], *zb[2], *xcb[2], *dlt[2], *bc[2];
    for (int dir = 0; dir < 2; ++dir) {
        xh[dir]  = (unsigned short*)alloc((size_t)NTOK * DI * 2);
        zb[dir]  = (unsigned short*)alloc((size_t)NTOK * DI * 2);
        xcb[dir] = (unsigned short*)alloc((size_t)NTOK * DI * 2);
        dlt[dir] = (unsigned short*)alloc((size_t)NTOK * DI * 2);
        bc[dir]  = (unsigned short*)alloc((size_t)NTOK * 32 * 2);
    }
    unsigned short* ycat = (unsigned short*)alloc((size_t)NTOK * 1024 * 2);
    float* AC  = (float*)alloc((size_t)NCH * PLANE * 4);
    float* HC  = (float*)alloc((size_t)NCH * PLANE * 4);
    float* HIN = (float*)alloc((size_t)NCH * PLANE * 4);
    float* out = (float*)d_out;

    prep_kernel<<<3456, 256, 0, stream>>>(
        p[0][1], p[0][0], p[1][1], p[1][0],
        p[0][4], p[0][5], p[1][4], p[1][5],
        p[0][9], p[1][9], w_in, w_p2, w_out);

    rmsnorm_kernel<<<NTOK, 256, 0, stream>>>(x, xn);

    // in_proj both dirs: N=2048
    mfma_gemm<EPI_IN><<<dim3(32, 128, 1), 256, 0, stream>>>(
        xn, xn, w_in, 256, xh[0], xh[1], zb[0], zb[1],
        nullptr, nullptr, nullptr, nullptr);

    conv_silu_kernel<<<dim3(2048, 2), 256, 0, stream>>>(
        xh[0], xh[1], p[0][2], p[1][2], p[0][3], p[1][3], xcb[0], xcb[1]);

    // proj2: delta_lin (softplus) + BC, both dirs via grid.z
    mfma_gemm<EPI_P2><<<dim3(9, 128, 2), 256, 0, stream>>>(
        xcb[0], xcb[1], w_p2, 512, dlt[0], dlt[1], bc[0], bc[1],
        p[0][6], p[1][6], nullptr, nullptr);

    scan_part1<<<dim3(DI / 64, 4 * NCH, 2), 256, 0, stream>>>(
        dlt[0], dlt[1], xcb[0], xcb[1], bc[0], bc[1], p[0][7], p[1][7], AC, HC);
    scan_part2<<<PLANE / 256, 256, 0, stream>>>(AC, HC, HIN);
    scan_part3<<<dim3(DI / 64, 4 * NCH, 2), 256, 0, stream>>>(
        dlt[0], dlt[1], xcb[0], xcb[1], bc[0], bc[1], zb[0], zb[1],
        p[0][7], p[1][7], p[0][8], p[1][8], HIN, ycat);

    // out_proj both dirs fused: K=1024, out = acc + 2x
    mfma_gemm<EPI_OUT><<<dim3(4, 128, 1), 256, 0, stream>>>(
        ycat, ycat, w_out, 1024, nullptr, nullptr, nullptr, nullptr,
        nullptr, nullptr, x, out);
}

// Round 4
// 268.695 us; speedup vs baseline: 3.4526x; 1.1126x over previous
//
#include <hip/hip_runtime.h>
#include <hip/hip_bf16.h>
#include <math.h>

// Bidirectional Mamba block. Round 4: scan occupancy + bank-conflict fixes.
// - (delta,xc) packed as bf16-pair uint in LDS (halves scan LDS, 6-7 blk/CU)
// - conflict-free staging layout (row + 16q + col banks)
// - exp2-based dA computation (Av pre-scaled by log2 e)

#define NTOK 8192
#define LL   2048
#define DM   256
#define DI   512
#define DS2  16
#define CL   64
#define NCH  32
#define PLANE 65536
#define KSTEP 64

typedef __bf16 bf16x8 __attribute__((ext_vector_type(8)));
typedef float f32x4 __attribute__((ext_vector_type(4)));

__device__ inline unsigned short f2bf(float f) {
    unsigned u = __float_as_uint(f);
    unsigned r = (u + 0x7fffu + ((u >> 16) & 1u)) >> 16;
    return (unsigned short)r;
}
__device__ inline float bf2f(unsigned short s) {
    return __uint_as_float((unsigned)s << 16);
}

#define GLDS(gp, lp) __builtin_amdgcn_global_load_lds( \
    (const __attribute__((address_space(1))) void*)(gp), \
    (__attribute__((address_space(3))) void*)(lp), 16, 0, 0)

#define L2E 1.4426950408889634f

// ---------------- prep: weight conversion / folding -----------------------
__global__ __launch_bounds__(256) void prep_kernel(
    const float* __restrict__ ip0, const float* __restrict__ nw0,
    const float* __restrict__ ip1, const float* __restrict__ nw1,
    const float* __restrict__ xp0, const float* __restrict__ dtw0,
    const float* __restrict__ xp1, const float* __restrict__ dtw1,
    const float* __restrict__ op0, const float* __restrict__ op1,
    unsigned short* __restrict__ w_in, unsigned short* __restrict__ w_p2,
    unsigned short* __restrict__ w_out) {
    int bid = blockIdx.x, tid = threadIdx.x;
    if (bid < 2048) {                       // in_proj rows, norm folded
        int dir = bid >> 10, n = bid & 1023;
        const float* ip = dir ? ip1 : ip0;
        const float* nw = dir ? nw1 : nw0;
        w_in[(size_t)bid * 256 + tid] = f2bf(ip[n * 256 + tid] * nw[tid]);
    } else if (bid < 3200) {                // w_p2 rows (576 per dir)
        int idx = bid - 2048;
        int dir = idx / 576, row = idx % 576;
        const float* xp = dir ? xp1 : xp0;
        const float* dtw = dir ? dtw1 : dtw0;
        unsigned short* dst = w_p2 + (size_t)idx * 512;
        for (int k = tid; k < 512; k += 256) {
            float v = 0.f;
            if (row < 512) {
                #pragma unroll
                for (int r = 0; r < 16; ++r) v = fmaf(dtw[row * 16 + r], xp[r * 512 + k], v);
            } else if (row < 544) {
                v = xp[(16 + row - 512) * 512 + k];
            }
            dst[k] = f2bf(v);
        }
    } else {                                // w_out rows (256), K=1024 concat
        int n = bid - 3200;
        for (int k = tid; k < 1024; k += 256) {
            float v = (k < 512) ? op0[n * 512 + k] : op1[n * 512 + (k - 512)];
            w_out[(size_t)n * 1024 + k] = f2bf(v);
        }
    }
}

// ---------------- rmsnorm -> bf16 -----------------------------------------
__global__ __launch_bounds__(256) void rmsnorm_kernel(const float* __restrict__ x,
                                                      unsigned short* __restrict__ xn) {
    int t = blockIdx.x;
    int tid = threadIdx.x;
    float v = x[(size_t)t * DM + tid];
    float ss = v * v;
    #pragma unroll
    for (int m = 1; m < 64; m <<= 1) ss += __shfl_xor(ss, m);
    __shared__ float ws[4];
    if ((tid & 63) == 0) ws[tid >> 6] = ss;
    __syncthreads();
    float tot = ws[0] + ws[1] + ws[2] + ws[3];
    float scale = rsqrtf(tot / (float)DM + 1e-5f);
    xn[(size_t)t * DM + tid] = f2bf(v * scale);
}

// ---------------- bf16 MFMA GEMM: C = A[M,K] @ W[N,K]^T -------------------
#define EPI_IN  0
#define EPI_P2  1
#define EPI_OUT 2

template <int EPI>
__global__ __launch_bounds__(256) void mfma_gemm(
    const unsigned short* __restrict__ A0, const unsigned short* __restrict__ A1,
    const unsigned short* __restrict__ Wb, int K,
    unsigned short* __restrict__ d0, unsigned short* __restrict__ d1,
    unsigned short* __restrict__ e0, unsigned short* __restrict__ e1,
    const float* __restrict__ aux0, const float* __restrict__ aux1,
    const float* __restrict__ Xres, float* __restrict__ outF) {
    __shared__ char lds[2][2][8192];     // [buf][A/B][64 rows * 128B]
    int tid = threadIdx.x;
    int lane = tid & 63, wid = tid >> 6;
    int wm = wid >> 1, wn = wid & 1;
    int m0 = blockIdx.y * 64;
    int n0 = blockIdx.x * 64;
    int dir = blockIdx.z;
    const unsigned short* A = dir ? A1 : A0;
    const unsigned short* W = Wb + ((EPI == EPI_P2) ? (size_t)dir * 576 * 512 : 0);

    const int s1 = tid, s2 = tid + 256;
    const int r1 = s1 >> 3, c1 = (s1 & 7) ^ (r1 & 7);
    const int r2 = s2 >> 3, c2 = (s2 & 7) ^ (r2 & 7);

    f32x4 acc[2][2] = {};
    int nt = K / KSTEP;

    auto stage = [&](int t, int buf) {
        int k0 = t * KSTEP;
        GLDS(A + (size_t)(m0 + r1) * K + k0 + c1 * 8, &lds[buf][0][0] + wid * 1024);
        GLDS(A + (size_t)(m0 + r2) * K + k0 + c2 * 8, &lds[buf][0][0] + 4096 + wid * 1024);
        GLDS(W + (size_t)(n0 + r1) * K + k0 + c1 * 8, &lds[buf][1][0] + wid * 1024);
        GLDS(W + (size_t)(n0 + r2) * K + k0 + c2 * 8, &lds[buf][1][0] + 4096 + wid * 1024);
    };

    stage(0, 0);
    for (int t = 0; t < nt; ++t) {
        int buf = t & 1;
        __syncthreads();
        if (t + 1 < nt) stage(t + 1, buf ^ 1);
        const char* Ab = &lds[buf][0][0];
        const char* Bb = &lds[buf][1][0];
        bf16x8 af[2][2], bfv[2][2];
        #pragma unroll
        for (int mf = 0; mf < 2; ++mf)
            #pragma unroll
            for (int kf = 0; kf < 2; ++kf) {
                int r = wm * 32 + mf * 16 + (lane & 15);
                int c = (lane >> 4) + kf * 4;
                af[mf][kf] = *(const bf16x8*)(Ab + r * 128 + ((c ^ (r & 7)) << 4));
            }
        #pragma unroll
        for (int nf = 0; nf < 2; ++nf)
            #pragma unroll
            for (int kf = 0; kf < 2; ++kf) {
                int r = wn * 32 + nf * 16 + (lane & 15);
                int c = (lane >> 4) + kf * 4;
                bfv[nf][kf] = *(const bf16x8*)(Bb + r * 128 + ((c ^ (r & 7)) << 4));
            }
        #pragma unroll
        for (int kf = 0; kf < 2; ++kf)
            #pragma unroll
            for (int mf = 0; mf < 2; ++mf)
                #pragma unroll
                for (int nf = 0; nf < 2; ++nf)
                    acc[mf][nf] = __builtin_amdgcn_mfma_f32_16x16x32_bf16(
                        af[mf][kf], bfv[nf][kf], acc[mf][nf], 0, 0, 0);
    }

    int cb0 = n0 + wn * 32 + (lane & 15);
    int rb0 = m0 + wm * 32 + ((lane >> 4) << 2);
    #pragma unroll
    for (int mf = 0; mf < 2; ++mf)
        #pragma unroll
        for (int nf = 0; nf < 2; ++nf) {
            int n = cb0 + nf * 16;
            #pragma unroll
            for (int r = 0; r < 4; ++r) {
                int m = rb0 + mf * 16 + r;
                float v = acc[mf][nf][r];
                if (EPI == EPI_IN) {
                    int dd = n >> 10, c = n & 1023;
                    unsigned short* dst = (c < 512)
                        ? (dd ? d1 : d0) + (size_t)m * 512 + c
                        : (dd ? e1 : e0) + (size_t)m * 512 + (c - 512);
                    *dst = f2bf(v);
                } else if (EPI == EPI_P2) {
                    if (n < 512) {
                        float sv = v + (dir ? aux1 : aux0)[n];
                        float sp = (sv > 20.f) ? sv : log1pf(__expf(sv));
                        (dir ? d1 : d0)[(size_t)m * 512 + n] = f2bf(sp);
                    } else if (n < 544) {
                        (dir ? e1 : e0)[(size_t)m * 32 + (n - 512)] = f2bf(v);
                    }
                } else {
                    outF[(size_t)m * 256 + n] = v + 2.f * Xres[(size_t)m * 256 + n];
                }
            }
        }
}

// ---------------- depthwise conv4 + silu (bf16, 8 ch/thread) --------------
__global__ __launch_bounds__(256) void conv_silu_kernel(
    const unsigned short* __restrict__ xh0, const unsigned short* __restrict__ xh1,
    const float* __restrict__ cw0, const float* __restrict__ cw1,
    const float* __restrict__ cb0, const float* __restrict__ cb1,
    unsigned short* __restrict__ o0, unsigned short* __restrict__ o1) {
    int dir = blockIdx.y;
    const unsigned short* xh = dir ? xh1 : xh0;
    const float* cw = dir ? cw1 : cw0;
    const float* cb = dir ? cb1 : cb0;
    unsigned short* xc = dir ? o1 : o0;
    int idx8 = blockIdx.x * 256 + threadIdx.x;
    int t = idx8 >> 6;
    int c8 = (idx8 & 63) << 3;
    int l = t & (LL - 1);
    float acc[8];
    #pragma unroll
    for (int j = 0; j < 8; ++j) acc[j] = cb[c8 + j];
    #pragma unroll
    for (int k = 0; k < 4; ++k) {
        int lo = dir ? (l + 3 - k) : (l - 3 + k);
        if (lo < 0 || lo >= LL) continue;
        uint4 u = *(const uint4*)(xh + (size_t)(t + lo - l) * DI + c8);
        unsigned wv[4] = {u.x, u.y, u.z, u.w};
        #pragma unroll
        for (int j = 0; j < 4; ++j) {
            float flo = __uint_as_float(wv[j] << 16);
            float fhi = __uint_as_float(wv[j] & 0xffff0000u);
            acc[2 * j]     = fmaf(flo, cw[(c8 + 2 * j) * 4 + k], acc[2 * j]);
            acc[2 * j + 1] = fmaf(fhi, cw[(c8 + 2 * j + 1) * 4 + k], acc[2 * j + 1]);
        }
    }
    unsigned out[4];
    #pragma unroll
    for (int j = 0; j < 4; ++j) {
        float a0 = acc[2 * j], a1 = acc[2 * j + 1];
        float s0 = a0 / (1.f + __expf(-a0));
        float s1 = a1 / (1.f + __expf(-a1));
        out[j] = (unsigned)f2bf(s0) | ((unsigned)f2bf(s1) << 16);
    }
    *(uint4*)(xc + (size_t)idx8 * 8) = make_uint4(out[0], out[1], out[2], out[3]);
}

// ---------------- scan phase 1: per-chunk local scan -> AC, HC ------------
// LDS: (delta,xc) packed bf16-pair per uint; conflict-free [CL][65] layout.
__global__ __launch_bounds__(256) void scan_part1(
    const unsigned short* __restrict__ dlt0, const unsigned short* __restrict__ dlt1,
    const unsigned short* __restrict__ xc0, const unsigned short* __restrict__ xc1,
    const unsigned short* __restrict__ bc0, const unsigned short* __restrict__ bc1,
    const float* __restrict__ Al0, const float* __restrict__ Al1,
    float* __restrict__ AC, float* __restrict__ HC) {
    int dir = blockIdx.z;
    const unsigned short* delta = dir ? dlt1 : dlt0;
    const unsigned short* xc    = dir ? xc1 : xc0;
    const unsigned short* bc    = dir ? bc1 : bc0;
    const float* Alog           = dir ? Al1 : Al0;
    int b = blockIdx.y >> 5, ch = blockIdx.y & 31;
    int d0 = blockIdx.x * 64;
    int tid = threadIdx.x;
    int dg = tid >> 2, nq = tid & 3;
    int d = d0 + dg;

    __shared__ unsigned sdxu[CL][65];
    __shared__ float4 sB4[CL][4];
    {
        int row = tid >> 2, q = tid & 3;
        int lr = ch * CL + row;
        int l = dir ? (LL - 1 - lr) : lr;
        size_t t = (size_t)b * LL + l;
        const uint4* dp = (const uint4*)(delta + t * DI + d0 + q * 16);
        const uint4* xp = (const uint4*)(xc + t * DI + d0 + q * 16);
        #pragma unroll
        for (int hh = 0; hh < 2; ++hh) {
            uint4 du = dp[hh], xu = xp[hh];
            unsigned dw[4] = {du.x, du.y, du.z, du.w};
            unsigned xw[4] = {xu.x, xu.y, xu.z, xu.w};
            #pragma unroll
            for (int j = 0; j < 4; ++j) {
                sdxu[row][q * 16 + hh * 8 + 2 * j]     = (dw[j] & 0xffffu) | (xw[j] << 16);
                sdxu[row][q * 16 + hh * 8 + 2 * j + 1] = (dw[j] >> 16) | (xw[j] & 0xffff0000u);
            }
        }
        if (q < 2) {
            uint4 bu = *(const uint4*)(bc + t * 32 + q * 8);
            unsigned bw[4] = {bu.x, bu.y, bu.z, bu.w};
            float f[8];
            #pragma unroll
            for (int j = 0; j < 4; ++j) {
                f[2 * j] = __uint_as_float(bw[j] << 16);
                f[2 * j + 1] = __uint_as_float(bw[j] & 0xffff0000u);
            }
            sB4[row][q * 2 + 0] = make_float4(f[0], f[1], f[2], f[3]);
            sB4[row][q * 2 + 1] = make_float4(f[4], f[5], f[6], f[7]);
        }
    }
    __syncthreads();

    float4 Al = *(const float4*)&Alog[d * DS2 + nq * 4];
    float Avl[4] = {-__expf(Al.x) * L2E, -__expf(Al.y) * L2E,
                    -__expf(Al.z) * L2E, -__expf(Al.w) * L2E};
    float h[4] = {0.f, 0.f, 0.f, 0.f};
    float sdl = 0.f;
    for (int r = 0; r < CL; ++r) {
        unsigned u = sdxu[r][dg];
        float dl = __uint_as_float(u << 16);
        float xcv = __uint_as_float(u & 0xffff0000u);
        float4 Bv = sB4[r][nq];
        float u0 = dl * xcv;
        sdl += dl;
        h[0] = fmaf(__builtin_amdgcn_exp2f(dl * Avl[0]), h[0], u0 * Bv.x);
        h[1] = fmaf(__builtin_amdgcn_exp2f(dl * Avl[1]), h[1], u0 * Bv.y);
        h[2] = fmaf(__builtin_amdgcn_exp2f(dl * Avl[2]), h[2], u0 * Bv.z);
        h[3] = fmaf(__builtin_amdgcn_exp2f(dl * Avl[3]), h[3], u0 * Bv.w);
    }
    size_t base = (size_t)ch * PLANE + (size_t)(((dir * 4 + b) * DI + d) * DS2 + nq * 4);
    *(float4*)&AC[base] = make_float4(
        __builtin_amdgcn_exp2f(Avl[0] * sdl), __builtin_amdgcn_exp2f(Avl[1] * sdl),
        __builtin_amdgcn_exp2f(Avl[2] * sdl), __builtin_amdgcn_exp2f(Avl[3] * sdl));
    *(float4*)&HC[base] = make_float4(h[0], h[1], h[2], h[3]);
}

// ---------------- scan phase 2: sequential chunk combine ------------------
__global__ __launch_bounds__(256) void scan_part2(
    const float* __restrict__ AC, const float* __restrict__ HC,
    float* __restrict__ HIN) {
    int idx = blockIdx.x * 256 + threadIdx.x;
    float hin = 0.f;
    #pragma unroll
    for (int ch = 0; ch < NCH; ++ch) {
        size_t o = (size_t)ch * PLANE + idx;
        HIN[o] = hin;
        hin = fmaf(AC[o], hin, HC[o]);
    }
}

// ---------------- scan phase 3: replay, gate with silu(z), -> ycat --------
__global__ __launch_bounds__(256) void scan_part3(
    const unsigned short* __restrict__ dlt0, const unsigned short* __restrict__ dlt1,
    const unsigned short* __restrict__ xc0, const unsigned short* __restrict__ xc1,
    const unsigned short* __restrict__ bc0, const unsigned short* __restrict__ bc1,
    const unsigned short* __restrict__ z0, const unsigned short* __restrict__ z1,
    const float* __restrict__ Al0, const float* __restrict__ Al1,
    const float* __restrict__ Dp0, const float* __restrict__ Dp1,
    const float* __restrict__ HIN, unsigned short* __restrict__ ycat) {
    int dir = blockIdx.z;
    const unsigned short* delta = dir ? dlt1 : dlt0;
    const unsigned short* xc    = dir ? xc1 : xc0;
    const unsigned short* bc    = dir ? bc1 : bc0;
    const unsigned short* zb    = dir ? z1 : z0;
    const float* Alog           = dir ? Al1 : Al0;
    const float* Dp             = dir ? Dp1 : Dp0;
    int b = blockIdx.y >> 5, ch = blockIdx.y & 31;
    int d0 = blockIdx.x * 64;
    int tid = threadIdx.x;
    int dg = tid >> 2, nq = tid & 3;
    int d = d0 + dg;

    __shared__ unsigned sdxu[CL][65];
    __shared__ float4 sB4[CL][4];
    __shared__ float4 sC4[CL][4];
    {
        int row = tid >> 2, q = tid & 3;
        int lr = ch * CL + row;
        int l = dir ? (LL - 1 - lr) : lr;
        size_t t = (size_t)b * LL + l;
        const uint4* dp = (const uint4*)(delta + t * DI + d0 + q * 16);
        const uint4* xp = (const uint4*)(xc + t * DI + d0 + q * 16);
        #pragma unroll
        for (int hh = 0; hh < 2; ++hh) {
            uint4 du = dp[hh], xu = xp[hh];
            unsigned dw[4] = {du.x, du.y, du.z, du.w};
            unsigned xw[4] = {xu.x, xu.y, xu.z, xu.w};
            #pragma unroll
            for (int j = 0; j < 4; ++j) {
                sdxu[row][q * 16 + hh * 8 + 2 * j]     = (dw[j] & 0xffffu) | (xw[j] << 16);
                sdxu[row][q * 16 + hh * 8 + 2 * j + 1] = (dw[j] >> 16) | (xw[j] & 0xffff0000u);
            }
        }
        uint4 bu = *(const uint4*)(bc + t * 32 + (q & 1) * 8 + (q >> 1) * 16);
        unsigned bw[4] = {bu.x, bu.y, bu.z, bu.w};
        float f[8];
        #pragma unroll
        for (int j = 0; j < 4; ++j) {
            f[2 * j] = __uint_as_float(bw[j] << 16);
            f[2 * j + 1] = __uint_as_float(bw[j] & 0xffff0000u);
        }
        float4 v0 = make_float4(f[0], f[1], f[2], f[3]);
        float4 v1 = make_float4(f[4], f[5], f[6], f[7]);
        if (q < 2) { sB4[row][q * 2] = v0; sB4[row][q * 2 + 1] = v1; }
        else       { sC4[row][(q - 2) * 2] = v0; sC4[row][(q - 2) * 2 + 1] = v1; }
    }
    __syncthreads();

    float4 Al = *(const float4*)&Alog[d * DS2 + nq * 4];
    float Avl[4] = {-__expf(Al.x) * L2E, -__expf(Al.y) * L2E,
                    -__expf(Al.z) * L2E, -__expf(Al.w) * L2E};
    float Dv = Dp[d];
    size_t base = (size_t)ch * PLANE + (size_t)(((dir * 4 + b) * DI + d) * DS2 + nq * 4);
    float4 h4 = *(const float4*)&HIN[base];
    float h[4] = {h4.x, h4.y, h4.z, h4.w};

    for (int r = 0; r < CL; ++r) {
        unsigned u = sdxu[r][dg];
        float dl = __uint_as_float(u << 16);
        float xcv = __uint_as_float(u & 0xffff0000u);
        float4 Bv = sB4[r][nq];
        float4 Cv = sC4[r][nq];
        float u0 = dl * xcv;
        h[0] = fmaf(__builtin_amdgcn_exp2f(dl * Avl[0]), h[0], u0 * Bv.x);
        h[1] = fmaf(__builtin_amdgcn_exp2f(dl * Avl[1]), h[1], u0 * Bv.y);
        h[2] = fmaf(__builtin_amdgcn_exp2f(dl * Avl[2]), h[2], u0 * Bv.z);
        h[3] = fmaf(__builtin_amdgcn_exp2f(dl * Avl[3]), h[3], u0 * Bv.w);
        float ts = fmaf(h[0], Cv.x, fmaf(h[1], Cv.y, fmaf(h[2], Cv.z, h[3] * Cv.w)));
        ts += __shfl_xor(ts, 1);
        ts += __shfl_xor(ts, 2);
        if (nq == 0) {
            int lr = ch * CL + r;
            int ll = dir ? (LL - 1 - lr) : lr;
            size_t tt = (size_t)b * LL + ll;
            float yv = fmaf(xcv, Dv, ts);
            float zz = bf2f(zb[tt * DI + d]);
            yv *= zz / (1.f + __expf(-zz));
            ycat[tt * 1024 + (size_t)dir * 512 + d] = f2bf(yv);
        }
    }
}

// -------------------------------------------------------------------------
extern "C" void kernel_launch(void* const* d_in, const int* in_sizes, int n_in,
                              void* d_out, int out_size, void* d_ws, size_t ws_size,
                              hipStream_t stream) {
    const float* x = (const float*)d_in[0];
    const float* p[2][10];
    for (int dir = 0; dir < 2; ++dir)
        for (int i = 0; i < 10; ++i)
            p[dir][i] = (const float*)d_in[1 + dir * 10 + i];
    // p[dir]: 0 norm, 1 in_proj, 2 conv_w, 3 conv_b, 4 x_proj,
    //         5 dt_w, 6 dt_b, 7 A_log, 8 D, 9 out_proj

    char* w = (char*)d_ws;
    auto alloc = [&](size_t bytes) { char* q = w; w += (bytes + 255) & ~(size_t)255; return q; };
    unsigned short* xn    = (unsigned short*)alloc((size_t)NTOK * DM * 2);
    unsigned short* w_in  = (unsigned short*)alloc((size_t)2048 * 256 * 2);
    unsigned short* w_p2  = (unsigned short*)alloc((size_t)1152 * 512 * 2);
    unsigned short* w_out = (unsigned short*)alloc((size_t)256 * 1024 * 2);
    unsigned short *xh[2], *zb[2], *xcb[2], *dlt[2], *bc[2];
    for (int dir = 0; dir < 2; ++dir) {
        xh[dir]  = (unsigned short*)alloc((size_t)NTOK * DI * 2);
        zb[dir]  = (unsigned short*)alloc((size_t)NTOK * DI * 2);
        xcb[dir] = (unsigned short*)alloc((size_t)NTOK * DI * 2);
        dlt[dir] = (unsigned short*)alloc((size_t)NTOK * DI * 2);
        bc[dir]  = (unsigned short*)alloc((size_t)NTOK * 32 * 2);
    }
    unsigned short* ycat = (unsigned short*)alloc((size_t)NTOK * 1024 * 2);
    float* AC  = (float*)alloc((size_t)NCH * PLANE * 4);
    float* HC  = (float*)alloc((size_t)NCH * PLANE * 4);
    float* HIN = (float*)alloc((size_t)NCH * PLANE * 4);
    float* out = (float*)d_out;

    prep_kernel<<<3456, 256, 0, stream>>>(
        p[0][1], p[0][0], p[1][1], p[1][0],
        p[0][4], p[0][5], p[1][4], p[1][5],
        p[0][9], p[1][9], w_in, w_p2, w_out);

    rmsnorm_kernel<<<NTOK, 256, 0, stream>>>(x, xn);

    mfma_gemm<EPI_IN><<<dim3(32, 128, 1), 256, 0, stream>>>(
        xn, xn, w_in, 256, xh[0], xh[1], zb[0], zb[1],
        nullptr, nullptr, nullptr, nullptr);

    conv_silu_kernel<<<dim3(2048, 2), 256, 0, stream>>>(
        xh[0], xh[1], p[0][2], p[1][2], p[0][3], p[1][3], xcb[0], xcb[1]);

    mfma_gemm<EPI_P2><<<dim3(9, 128, 2), 256, 0, stream>>>(
        xcb[0], xcb[1], w_p2, 512, dlt[0], dlt[1], bc[0], bc[1],
        p[0][6], p[1][6], nullptr, nullptr);

    scan_part1<<<dim3(DI / 64, 4 * NCH, 2), 256, 0, stream>>>(
        dlt[0], dlt[1], xcb[0], xcb[1], bc[0], bc[1], p[0][7], p[1][7], AC, HC);
    scan_part2<<<PLANE / 256, 256, 0, stream>>>(AC, HC, HIN);
    scan_part3<<<dim3(DI / 64, 4 * NCH, 2), 256, 0, stream>>>(
        dlt[0], dlt[1], xcb[0], xcb[1], bc[0], bc[1], zb[0], zb[1],
        p[0][7], p[1][7], p[0][8], p[1][8], HIN, ycat);

    mfma_gemm<EPI_OUT><<<dim3(4, 128, 1), 256, 0, stream>>>(
        ycat, ycat, w_out, 1024, nullptr, nullptr, nullptr, nullptr,
        nullptr, nullptr, x, out);
}

// Round 5
// 250.726 us; speedup vs baseline: 3.7001x; 1.0717x over previous
//
#include <hip/hip_runtime.h>
#include <hip/hip_bf16.h>
#include <math.h>

// Bidirectional Mamba block. Round 5: non-replay scan.
//   part1: local chunk scan -> AC, HC, packed (y_local, cumDelta) per (l,d)
//   part2: sequential chunk combine -> HIN
//   lite : fully parallel correction y = y_loc + sum_n C*exp2(Avl*s)*hin,
//          gated by silu(z), -> ycat   (no serial chain, no replay)

#define NTOK 8192
#define LL   2048
#define DM   256
#define DI   512
#define DS2  16
#define CL   64
#define NCH  32
#define PLANE 65536
#define KSTEP 64

typedef __bf16 bf16x8 __attribute__((ext_vector_type(8)));
typedef float f32x4 __attribute__((ext_vector_type(4)));

__device__ inline unsigned short f2bf(float f) {
    unsigned u = __float_as_uint(f);
    unsigned r = (u + 0x7fffu + ((u >> 16) & 1u)) >> 16;
    return (unsigned short)r;
}
__device__ inline float bf2f(unsigned short s) {
    return __uint_as_float((unsigned)s << 16);
}

#define GLDS(gp, lp) __builtin_amdgcn_global_load_lds( \
    (const __attribute__((address_space(1))) void*)(gp), \
    (__attribute__((address_space(3))) void*)(lp), 16, 0, 0)

#define L2E 1.4426950408889634f

// ---------------- prep: weight conversion / folding -----------------------
__global__ __launch_bounds__(256) void prep_kernel(
    const float* __restrict__ ip0, const float* __restrict__ nw0,
    const float* __restrict__ ip1, const float* __restrict__ nw1,
    const float* __restrict__ xp0, const float* __restrict__ dtw0,
    const float* __restrict__ xp1, const float* __restrict__ dtw1,
    const float* __restrict__ op0, const float* __restrict__ op1,
    unsigned short* __restrict__ w_in, unsigned short* __restrict__ w_p2,
    unsigned short* __restrict__ w_out) {
    int bid = blockIdx.x, tid = threadIdx.x;
    if (bid < 2048) {                       // in_proj rows, norm folded
        int dir = bid >> 10, n = bid & 1023;
        const float* ip = dir ? ip1 : ip0;
        const float* nw = dir ? nw1 : nw0;
        w_in[(size_t)bid * 256 + tid] = f2bf(ip[n * 256 + tid] * nw[tid]);
    } else if (bid < 3200) {                // w_p2 rows (576 per dir)
        int idx = bid - 2048;
        int dir = idx / 576, row = idx % 576;
        const float* xp = dir ? xp1 : xp0;
        const float* dtw = dir ? dtw1 : dtw0;
        unsigned short* dst = w_p2 + (size_t)idx * 512;
        for (int k = tid; k < 512; k += 256) {
            float v = 0.f;
            if (row < 512) {
                #pragma unroll
                for (int r = 0; r < 16; ++r) v = fmaf(dtw[row * 16 + r], xp[r * 512 + k], v);
            } else if (row < 544) {
                v = xp[(16 + row - 512) * 512 + k];
            }
            dst[k] = f2bf(v);
        }
    } else {                                // w_out rows (256), K=1024 concat
        int n = bid - 3200;
        for (int k = tid; k < 1024; k += 256) {
            float v = (k < 512) ? op0[n * 512 + k] : op1[n * 512 + (k - 512)];
            w_out[(size_t)n * 1024 + k] = f2bf(v);
        }
    }
}

// ---------------- rmsnorm -> bf16 -----------------------------------------
__global__ __launch_bounds__(256) void rmsnorm_kernel(const float* __restrict__ x,
                                                      unsigned short* __restrict__ xn) {
    int t = blockIdx.x;
    int tid = threadIdx.x;
    float v = x[(size_t)t * DM + tid];
    float ss = v * v;
    #pragma unroll
    for (int m = 1; m < 64; m <<= 1) ss += __shfl_xor(ss, m);
    __shared__ float ws[4];
    if ((tid & 63) == 0) ws[tid >> 6] = ss;
    __syncthreads();
    float tot = ws[0] + ws[1] + ws[2] + ws[3];
    float scale = rsqrtf(tot / (float)DM + 1e-5f);
    xn[(size_t)t * DM + tid] = f2bf(v * scale);
}

// ---------------- bf16 MFMA GEMM: C = A[M,K] @ W[N,K]^T -------------------
#define EPI_IN  0
#define EPI_P2  1
#define EPI_OUT 2

template <int EPI>
__global__ __launch_bounds__(256) void mfma_gemm(
    const unsigned short* __restrict__ A0, const unsigned short* __restrict__ A1,
    const unsigned short* __restrict__ Wb, int K,
    unsigned short* __restrict__ d0, unsigned short* __restrict__ d1,
    unsigned short* __restrict__ e0, unsigned short* __restrict__ e1,
    const float* __restrict__ aux0, const float* __restrict__ aux1,
    const float* __restrict__ Xres, float* __restrict__ outF) {
    __shared__ char lds[2][2][8192];     // [buf][A/B][64 rows * 128B]
    int tid = threadIdx.x;
    int lane = tid & 63, wid = tid >> 6;
    int wm = wid >> 1, wn = wid & 1;
    int m0 = blockIdx.y * 64;
    int n0 = blockIdx.x * 64;
    int dir = blockIdx.z;
    const unsigned short* A = dir ? A1 : A0;
    const unsigned short* W = Wb + ((EPI == EPI_P2) ? (size_t)dir * 576 * 512 : 0);

    const int s1 = tid, s2 = tid + 256;
    const int r1 = s1 >> 3, c1 = (s1 & 7) ^ (r1 & 7);
    const int r2 = s2 >> 3, c2 = (s2 & 7) ^ (r2 & 7);

    f32x4 acc[2][2] = {};
    int nt = K / KSTEP;

    auto stage = [&](int t, int buf) {
        int k0 = t * KSTEP;
        GLDS(A + (size_t)(m0 + r1) * K + k0 + c1 * 8, &lds[buf][0][0] + wid * 1024);
        GLDS(A + (size_t)(m0 + r2) * K + k0 + c2 * 8, &lds[buf][0][0] + 4096 + wid * 1024);
        GLDS(W + (size_t)(n0 + r1) * K + k0 + c1 * 8, &lds[buf][1][0] + wid * 1024);
        GLDS(W + (size_t)(n0 + r2) * K + k0 + c2 * 8, &lds[buf][1][0] + 4096 + wid * 1024);
    };

    stage(0, 0);
    for (int t = 0; t < nt; ++t) {
        int buf = t & 1;
        __syncthreads();
        if (t + 1 < nt) stage(t + 1, buf ^ 1);
        const char* Ab = &lds[buf][0][0];
        const char* Bb = &lds[buf][1][0];
        bf16x8 af[2][2], bfv[2][2];
        #pragma unroll
        for (int mf = 0; mf < 2; ++mf)
            #pragma unroll
            for (int kf = 0; kf < 2; ++kf) {
                int r = wm * 32 + mf * 16 + (lane & 15);
                int c = (lane >> 4) + kf * 4;
                af[mf][kf] = *(const bf16x8*)(Ab + r * 128 + ((c ^ (r & 7)) << 4));
            }
        #pragma unroll
        for (int nf = 0; nf < 2; ++nf)
            #pragma unroll
            for (int kf = 0; kf < 2; ++kf) {
                int r = wn * 32 + nf * 16 + (lane & 15);
                int c = (lane >> 4) + kf * 4;
                bfv[nf][kf] = *(const bf16x8*)(Bb + r * 128 + ((c ^ (r & 7)) << 4));
            }
        #pragma unroll
        for (int kf = 0; kf < 2; ++kf)
            #pragma unroll
            for (int mf = 0; mf < 2; ++mf)
                #pragma unroll
                for (int nf = 0; nf < 2; ++nf)
                    acc[mf][nf] = __builtin_amdgcn_mfma_f32_16x16x32_bf16(
                        af[mf][kf], bfv[nf][kf], acc[mf][nf], 0, 0, 0);
    }

    int cb0 = n0 + wn * 32 + (lane & 15);
    int rb0 = m0 + wm * 32 + ((lane >> 4) << 2);
    #pragma unroll
    for (int mf = 0; mf < 2; ++mf)
        #pragma unroll
        for (int nf = 0; nf < 2; ++nf) {
            int n = cb0 + nf * 16;
            #pragma unroll
            for (int r = 0; r < 4; ++r) {
                int m = rb0 + mf * 16 + r;
                float v = acc[mf][nf][r];
                if (EPI == EPI_IN) {
                    int dd = n >> 10, c = n & 1023;
                    unsigned short* dst = (c < 512)
                        ? (dd ? d1 : d0) + (size_t)m * 512 + c
                        : (dd ? e1 : e0) + (size_t)m * 512 + (c - 512);
                    *dst = f2bf(v);
                } else if (EPI == EPI_P2) {
                    if (n < 512) {
                        float sv = v + (dir ? aux1 : aux0)[n];
                        float sp = (sv > 20.f) ? sv : log1pf(__expf(sv));
                        (dir ? d1 : d0)[(size_t)m * 512 + n] = f2bf(sp);
                    } else if (n < 544) {
                        (dir ? e1 : e0)[(size_t)m * 32 + (n - 512)] = f2bf(v);
                    }
                } else {
                    outF[(size_t)m * 256 + n] = v + 2.f * Xres[(size_t)m * 256 + n];
                }
            }
        }
}

// ---------------- depthwise conv4 + silu (bf16, 8 ch/thread) --------------
__global__ __launch_bounds__(256) void conv_silu_kernel(
    const unsigned short* __restrict__ xh0, const unsigned short* __restrict__ xh1,
    const float* __restrict__ cw0, const float* __restrict__ cw1,
    const float* __restrict__ cb0, const float* __restrict__ cb1,
    unsigned short* __restrict__ o0, unsigned short* __restrict__ o1) {
    int dir = blockIdx.y;
    const unsigned short* xh = dir ? xh1 : xh0;
    const float* cw = dir ? cw1 : cw0;
    const float* cb = dir ? cb1 : cb0;
    unsigned short* xc = dir ? o1 : o0;
    int idx8 = blockIdx.x * 256 + threadIdx.x;
    int t = idx8 >> 6;
    int c8 = (idx8 & 63) << 3;
    int l = t & (LL - 1);
    float acc[8];
    #pragma unroll
    for (int j = 0; j < 8; ++j) acc[j] = cb[c8 + j];
    #pragma unroll
    for (int k = 0; k < 4; ++k) {
        int lo = dir ? (l + 3 - k) : (l - 3 + k);
        if (lo < 0 || lo >= LL) continue;
        uint4 u = *(const uint4*)(xh + (size_t)(t + lo - l) * DI + c8);
        unsigned wv[4] = {u.x, u.y, u.z, u.w};
        #pragma unroll
        for (int j = 0; j < 4; ++j) {
            float flo = __uint_as_float(wv[j] << 16);
            float fhi = __uint_as_float(wv[j] & 0xffff0000u);
            acc[2 * j]     = fmaf(flo, cw[(c8 + 2 * j) * 4 + k], acc[2 * j]);
            acc[2 * j + 1] = fmaf(fhi, cw[(c8 + 2 * j + 1) * 4 + k], acc[2 * j + 1]);
        }
    }
    unsigned out[4];
    #pragma unroll
    for (int j = 0; j < 4; ++j) {
        float a0 = acc[2 * j], a1 = acc[2 * j + 1];
        float s0 = a0 / (1.f + __expf(-a0));
        float s1 = a1 / (1.f + __expf(-a1));
        out[j] = (unsigned)f2bf(s0) | ((unsigned)f2bf(s1) << 16);
    }
    *(uint4*)(xc + (size_t)idx8 * 8) = make_uint4(out[0], out[1], out[2], out[3]);
}

// ---------------- scan part1: local chunk scan -> AC, HC, (y_loc,s) -------
// LDS exactly 20480B: sdxu[64][64] XOR-swizzled + sBC[64][16] packed B|C.
__global__ __launch_bounds__(256, 8) void scan_part1(
    const unsigned short* __restrict__ dlt0, const unsigned short* __restrict__ dlt1,
    const unsigned short* __restrict__ xc0, const unsigned short* __restrict__ xc1,
    const unsigned short* __restrict__ bc0, const unsigned short* __restrict__ bc1,
    const float* __restrict__ Al0, const float* __restrict__ Al1,
    const float* __restrict__ Dp0, const float* __restrict__ Dp1,
    float* __restrict__ AC, float* __restrict__ HC,
    unsigned* __restrict__ yls0, unsigned* __restrict__ yls1) {
    int dir = blockIdx.z;
    const unsigned short* delta = dir ? dlt1 : dlt0;
    const unsigned short* xc    = dir ? xc1 : xc0;
    const unsigned short* bc    = dir ? bc1 : bc0;
    const float* Alog           = dir ? Al1 : Al0;
    const float* Dp             = dir ? Dp1 : Dp0;
    unsigned* yls               = dir ? yls1 : yls0;
    int b = blockIdx.y >> 5, ch = blockIdx.y & 31;
    int d0 = blockIdx.x * 64;
    int tid = threadIdx.x;
    int dg = tid >> 2, nq = tid & 3;
    int d = d0 + dg;

    __shared__ unsigned sdxu[CL][64];    // [l][d] packed (delta|xc), col XOR row
    __shared__ unsigned sBC[CL][16];     // [l][n] packed (B|C)
    {
        int row = tid >> 2, q = tid & 3;
        int lr = ch * CL + row;
        int l = dir ? (LL - 1 - lr) : lr;
        size_t t = (size_t)b * LL + l;
        const uint4* dp = (const uint4*)(delta + t * DI + d0 + q * 16);
        const uint4* xp = (const uint4*)(xc + t * DI + d0 + q * 16);
        #pragma unroll
        for (int hh = 0; hh < 2; ++hh) {
            uint4 du = dp[hh], xu = xp[hh];
            unsigned dw[4] = {du.x, du.y, du.z, du.w};
            unsigned xw[4] = {xu.x, xu.y, xu.z, xu.w};
            #pragma unroll
            for (int j = 0; j < 4; ++j) {
                int col = q * 16 + hh * 8 + 2 * j;
                sdxu[row][col ^ row]       = (dw[j] & 0xffffu) | (xw[j] << 16);
                sdxu[row][(col + 1) ^ row] = (dw[j] >> 16) | (xw[j] & 0xffff0000u);
            }
        }
        uint2 Bu = *(const uint2*)(bc + t * 32 + q * 4);
        uint2 Cu = *(const uint2*)(bc + t * 32 + 16 + q * 4);
        sBC[row][q * 4 + 0] = (Bu.x & 0xffffu) | (Cu.x << 16);
        sBC[row][q * 4 + 1] = (Bu.x >> 16) | (Cu.x & 0xffff0000u);
        sBC[row][q * 4 + 2] = (Bu.y & 0xffffu) | (Cu.y << 16);
        sBC[row][q * 4 + 3] = (Bu.y >> 16) | (Cu.y & 0xffff0000u);
    }
    __syncthreads();

    float4 Al = *(const float4*)&Alog[d * DS2 + nq * 4];
    float Avl[4] = {-__expf(Al.x) * L2E, -__expf(Al.y) * L2E,
                    -__expf(Al.z) * L2E, -__expf(Al.w) * L2E};
    float Dv = Dp[d];
    float h[4] = {0.f, 0.f, 0.f, 0.f};
    float sdl = 0.f;

    #pragma unroll 2
    for (int r = 0; r < CL; ++r) {
        unsigned u = sdxu[r][dg ^ r];
        float dl = __uint_as_float(u << 16);
        float xcv = __uint_as_float(u & 0xffff0000u);
        uint4 bq = *(const uint4*)&sBC[r][nq * 4];
        unsigned bw[4] = {bq.x, bq.y, bq.z, bq.w};
        float u0 = dl * xcv;
        sdl += dl;
        float ts = 0.f;
        #pragma unroll
        for (int j = 0; j < 4; ++j) {
            float Bf = __uint_as_float(bw[j] << 16);
            float Cf = __uint_as_float(bw[j] & 0xffff0000u);
            float e = __builtin_amdgcn_exp2f(dl * Avl[j]);
            h[j] = fmaf(e, h[j], u0 * Bf);
            ts = fmaf(h[j], Cf, ts);
        }
        ts += __shfl_xor(ts, 1);
        ts += __shfl_xor(ts, 2);
        if (nq == 0) {
            int lr = ch * CL + r;
            float yv = fmaf(xcv, Dv, ts);
            yls[((size_t)b * LL + lr) * DI + d] =
                (unsigned)f2bf(yv) | ((unsigned)f2bf(sdl) << 16);
        }
    }
    size_t base = (size_t)ch * PLANE + (size_t)(((dir * 4 + b) * DI + d) * DS2 + nq * 4);
    *(float4*)&AC[base] = make_float4(
        __builtin_amdgcn_exp2f(Avl[0] * sdl), __builtin_amdgcn_exp2f(Avl[1] * sdl),
        __builtin_amdgcn_exp2f(Avl[2] * sdl), __builtin_amdgcn_exp2f(Avl[3] * sdl));
    *(float4*)&HC[base] = make_float4(h[0], h[1], h[2], h[3]);
}

// ---------------- scan part2: sequential chunk combine --------------------
__global__ __launch_bounds__(256) void scan_part2(
    const float* __restrict__ AC, const float* __restrict__ HC,
    float* __restrict__ HIN) {
    int idx = blockIdx.x * 256 + threadIdx.x;
    float hin = 0.f;
    #pragma unroll
    for (int ch = 0; ch < NCH; ++ch) {
        size_t o = (size_t)ch * PLANE + idx;
        HIN[o] = hin;
        hin = fmaf(AC[o], hin, HC[o]);
    }
}

// ---------------- scan lite: parallel correction + gate -> ycat -----------
// y = y_loc + sum_n C[l,n]*exp2(Avl[d,n]*s[l,d])*hin[ch,d,n]; y *= silu(z)
__global__ __launch_bounds__(256, 8) void scan_lite(
    const unsigned* __restrict__ yls0, const unsigned* __restrict__ yls1,
    const unsigned short* __restrict__ bc0, const unsigned short* __restrict__ bc1,
    const unsigned short* __restrict__ z0, const unsigned short* __restrict__ z1,
    const float* __restrict__ Al0, const float* __restrict__ Al1,
    const float* __restrict__ HIN, unsigned short* __restrict__ ycat) {
    int dir = blockIdx.z;
    const unsigned* yls         = dir ? yls1 : yls0;
    const unsigned short* bc    = dir ? bc1 : bc0;
    const unsigned short* zb    = dir ? z1 : z0;
    const float* Alog           = dir ? Al1 : Al0;
    int b = blockIdx.y >> 5, ch = blockIdx.y & 31;
    int d0 = blockIdx.x * 64;
    int tid = threadIdx.x;
    int dg = tid & 63, lg = tid >> 6;
    int d = d0 + dg;

    __shared__ unsigned sC[CL][8];       // [l][n-pair] C packed bf16 pairs
    {
        int row = tid >> 2, q = tid & 3;
        if (q < 2) {
            int lr = ch * CL + row;
            int l = dir ? (LL - 1 - lr) : lr;
            size_t t = (size_t)b * LL + l;
            uint4 cu = *(const uint4*)(bc + t * 32 + 16 + q * 8);
            *(uint4*)&sC[row][q * 4] = cu;
        }
    }
    __syncthreads();

    float Avl[16];
    #pragma unroll
    for (int qq = 0; qq < 4; ++qq) {
        float4 Al = *(const float4*)&Alog[d * DS2 + qq * 4];
        Avl[qq * 4 + 0] = -__expf(Al.x) * L2E;
        Avl[qq * 4 + 1] = -__expf(Al.y) * L2E;
        Avl[qq * 4 + 2] = -__expf(Al.z) * L2E;
        Avl[qq * 4 + 3] = -__expf(Al.w) * L2E;
    }
    float hin[16];
    size_t hbase = (size_t)ch * PLANE + (size_t)(((dir * 4 + b) * DI + d) * DS2);
    #pragma unroll
    for (int qq = 0; qq < 4; ++qq)
        *(float4*)&hin[qq * 4] = *(const float4*)&HIN[hbase + qq * 4];

    #pragma unroll 2
    for (int i = 0; i < 16; ++i) {
        int row = lg * 16 + i;
        int lr = ch * CL + row;
        int ll = dir ? (LL - 1 - lr) : lr;
        size_t tt = (size_t)b * LL + ll;
        unsigned u = yls[((size_t)b * LL + lr) * DI + d];
        float yv = __uint_as_float(u << 16);
        float s  = __uint_as_float(u & 0xffff0000u);
        float acc = 0.f;
        #pragma unroll
        for (int p = 0; p < 8; ++p) {
            unsigned cp = sC[row][p];
            float C0 = __uint_as_float(cp << 16);
            float C1 = __uint_as_float(cp & 0xffff0000u);
            float e0 = __builtin_amdgcn_exp2f(s * Avl[2 * p]);
            float e1 = __builtin_amdgcn_exp2f(s * Avl[2 * p + 1]);
            acc = fmaf(e0 * hin[2 * p], C0, acc);
            acc = fmaf(e1 * hin[2 * p + 1], C1, acc);
        }
        yv += acc;
        float zz = bf2f(zb[tt * DI + d]);
        yv *= zz / (1.f + __expf(-zz));
        ycat[tt * 1024 + (size_t)dir * 512 + d] = f2bf(yv);
    }
}

// -------------------------------------------------------------------------
extern "C" void kernel_launch(void* const* d_in, const int* in_sizes, int n_in,
                              void* d_out, int out_size, void* d_ws, size_t ws_size,
                              hipStream_t stream) {
    const float* x = (const float*)d_in[0];
    const float* p[2][10];
    for (int dir = 0; dir < 2; ++dir)
        for (int i = 0; i < 10; ++i)
            p[dir][i] = (const float*)d_in[1 + dir * 10 + i];
    // p[dir]: 0 norm, 1 in_proj, 2 conv_w, 3 conv_b, 4 x_proj,
    //         5 dt_w, 6 dt_b, 7 A_log, 8 D, 9 out_proj

    char* w = (char*)d_ws;
    auto alloc = [&](size_t bytes) { char* q = w; w += (bytes + 255) & ~(size_t)255; return q; };
    unsigned short* xn    = (unsigned short*)alloc((size_t)NTOK * DM * 2);
    unsigned short* w_in  = (unsigned short*)alloc((size_t)2048 * 256 * 2);
    unsigned short* w_p2  = (unsigned short*)alloc((size_t)1152 * 512 * 2);
    unsigned short* w_out = (unsigned short*)alloc((size_t)256 * 1024 * 2);
    unsigned short *xh[2], *zb[2], *xcb[2], *dlt[2], *bc[2];
    for (int dir = 0; dir < 2; ++dir) {
        xh[dir]  = (unsigned short*)alloc((size_t)NTOK * DI * 2 * 2); // xh, then (y_loc,s) packed u32
        zb[dir]  = (unsigned short*)alloc((size_t)NTOK * DI * 2);
        xcb[dir] = (unsigned short*)alloc((size_t)NTOK * DI * 2);
        dlt[dir] = (unsigned short*)alloc((size_t)NTOK * DI * 2);
        bc[dir]  = (unsigned short*)alloc((size_t)NTOK * 32 * 2);
    }
    unsigned short* ycat = (unsigned short*)alloc((size_t)NTOK * 1024 * 2);
    float* AC  = (float*)alloc((size_t)NCH * PLANE * 4);
    float* HC  = (float*)alloc((size_t)NCH * PLANE * 4);
    float* HIN = (float*)alloc((size_t)NCH * PLANE * 4);
    float* out = (float*)d_out;
    unsigned* yls[2] = {(unsigned*)xh[0], (unsigned*)xh[1]};  // reuse dead xh

    prep_kernel<<<3456, 256, 0, stream>>>(
        p[0][1], p[0][0], p[1][1], p[1][0],
        p[0][4], p[0][5], p[1][4], p[1][5],
        p[0][9], p[1][9], w_in, w_p2, w_out);

    rmsnorm_kernel<<<NTOK, 256, 0, stream>>>(x, xn);

    mfma_gemm<EPI_IN><<<dim3(32, 128, 1), 256, 0, stream>>>(
        xn, xn, w_in, 256, xh[0], xh[1], zb[0], zb[1],
        nullptr, nullptr, nullptr, nullptr);

    conv_silu_kernel<<<dim3(2048, 2), 256, 0, stream>>>(
        xh[0], xh[1], p[0][2], p[1][2], p[0][3], p[1][3], xcb[0], xcb[1]);

    mfma_gemm<EPI_P2><<<dim3(9, 128, 2), 256, 0, stream>>>(
        xcb[0], xcb[1], w_p2, 512, dlt[0], dlt[1], bc[0], bc[1],
        p[0][6], p[1][6], nullptr, nullptr);

    scan_part1<<<dim3(DI / 64, 4 * NCH, 2), 256, 0, stream>>>(
        dlt[0], dlt[1], xcb[0], xcb[1], bc[0], bc[1], p[0][7], p[1][7],
        p[0][8], p[1][8], AC, HC, yls[0], yls[1]);
    scan_part2<<<PLANE / 256, 256, 0, stream>>>(AC, HC, HIN);
    scan_lite<<<dim3(DI / 64, 4 * NCH, 2), 256, 0, stream>>>(
        yls[0], yls[1], bc[0], bc[1], zb[0], zb[1],
        p[0][7], p[1][7], HIN, ycat);

    mfma_gemm<EPI_OUT><<<dim3(4, 128, 1), 256, 0, stream>>>(
        ycat, ycat, w_out, 1024, nullptr, nullptr, nullptr, nullptr,
        nullptr, nullptr, x, out);
}

// Round 6
// 225.027 us; speedup vs baseline: 4.1226x; 1.1142x over previous
//
#include <hip/hip_runtime.h>
#include <hip/hip_bf16.h>
#include <math.h>

// Bidirectional Mamba block. Round 6: conv weight loads coalesced (reg-cached).
//   part1: local chunk scan -> AC, HC, packed (y_local, cumDelta)
//   part2: sequential chunk combine -> HIN
//   lite : parallel correction + silu(z) gate -> ycat

#define NTOK 8192
#define LL   2048
#define DM   256
#define DI   512
#define DS2  16
#define CL   64
#define NCH  32
#define PLANE 65536
#define KSTEP 64

typedef __bf16 bf16x8 __attribute__((ext_vector_type(8)));
typedef float f32x4 __attribute__((ext_vector_type(4)));

__device__ inline unsigned short f2bf(float f) {
    unsigned u = __float_as_uint(f);
    unsigned r = (u + 0x7fffu + ((u >> 16) & 1u)) >> 16;
    return (unsigned short)r;
}
__device__ inline float bf2f(unsigned short s) {
    return __uint_as_float((unsigned)s << 16);
}

#define GLDS(gp, lp) __builtin_amdgcn_global_load_lds( \
    (const __attribute__((address_space(1))) void*)(gp), \
    (__attribute__((address_space(3))) void*)(lp), 16, 0, 0)

#define L2E 1.4426950408889634f

// ---------------- prep: weight conversion / folding -----------------------
__global__ __launch_bounds__(256) void prep_kernel(
    const float* __restrict__ ip0, const float* __restrict__ nw0,
    const float* __restrict__ ip1, const float* __restrict__ nw1,
    const float* __restrict__ xp0, const float* __restrict__ dtw0,
    const float* __restrict__ xp1, const float* __restrict__ dtw1,
    const float* __restrict__ op0, const float* __restrict__ op1,
    unsigned short* __restrict__ w_in, unsigned short* __restrict__ w_p2,
    unsigned short* __restrict__ w_out) {
    int bid = blockIdx.x, tid = threadIdx.x;
    if (bid < 2048) {                       // in_proj rows, norm folded
        int dir = bid >> 10, n = bid & 1023;
        const float* ip = dir ? ip1 : ip0;
        const float* nw = dir ? nw1 : nw0;
        w_in[(size_t)bid * 256 + tid] = f2bf(ip[n * 256 + tid] * nw[tid]);
    } else if (bid < 3200) {                // w_p2 rows (576 per dir)
        int idx = bid - 2048;
        int dir = idx / 576, row = idx % 576;
        const float* xp = dir ? xp1 : xp0;
        const float* dtw = dir ? dtw1 : dtw0;
        unsigned short* dst = w_p2 + (size_t)idx * 512;
        for (int k = tid; k < 512; k += 256) {
            float v = 0.f;
            if (row < 512) {
                #pragma unroll
                for (int r = 0; r < 16; ++r) v = fmaf(dtw[row * 16 + r], xp[r * 512 + k], v);
            } else if (row < 544) {
                v = xp[(16 + row - 512) * 512 + k];
            }
            dst[k] = f2bf(v);
        }
    } else {                                // w_out rows (256), K=1024 concat
        int n = bid - 3200;
        for (int k = tid; k < 1024; k += 256) {
            float v = (k < 512) ? op0[n * 512 + k] : op1[n * 512 + (k - 512)];
            w_out[(size_t)n * 1024 + k] = f2bf(v);
        }
    }
}

// ---------------- rmsnorm -> bf16 -----------------------------------------
__global__ __launch_bounds__(256) void rmsnorm_kernel(const float* __restrict__ x,
                                                      unsigned short* __restrict__ xn) {
    int t = blockIdx.x;
    int tid = threadIdx.x;
    float v = x[(size_t)t * DM + tid];
    float ss = v * v;
    #pragma unroll
    for (int m = 1; m < 64; m <<= 1) ss += __shfl_xor(ss, m);
    __shared__ float ws[4];
    if ((tid & 63) == 0) ws[tid >> 6] = ss;
    __syncthreads();
    float tot = ws[0] + ws[1] + ws[2] + ws[3];
    float scale = rsqrtf(tot / (float)DM + 1e-5f);
    xn[(size_t)t * DM + tid] = f2bf(v * scale);
}

// ---------------- bf16 MFMA GEMM: C = A[M,K] @ W[N,K]^T -------------------
#define EPI_IN  0
#define EPI_P2  1
#define EPI_OUT 2

template <int EPI>
__global__ __launch_bounds__(256) void mfma_gemm(
    const unsigned short* __restrict__ A0, const unsigned short* __restrict__ A1,
    const unsigned short* __restrict__ Wb, int K,
    unsigned short* __restrict__ d0, unsigned short* __restrict__ d1,
    unsigned short* __restrict__ e0, unsigned short* __restrict__ e1,
    const float* __restrict__ aux0, const float* __restrict__ aux1,
    const float* __restrict__ Xres, float* __restrict__ outF) {
    __shared__ char lds[2][2][8192];     // [buf][A/B][64 rows * 128B]
    int tid = threadIdx.x;
    int lane = tid & 63, wid = tid >> 6;
    int wm = wid >> 1, wn = wid & 1;
    int m0 = blockIdx.y * 64;
    int n0 = blockIdx.x * 64;
    int dir = blockIdx.z;
    const unsigned short* A = dir ? A1 : A0;
    const unsigned short* W = Wb + ((EPI == EPI_P2) ? (size_t)dir * 576 * 512 : 0);

    const int s1 = tid, s2 = tid + 256;
    const int r1 = s1 >> 3, c1 = (s1 & 7) ^ (r1 & 7);
    const int r2 = s2 >> 3, c2 = (s2 & 7) ^ (r2 & 7);

    f32x4 acc[2][2] = {};
    int nt = K / KSTEP;

    auto stage = [&](int t, int buf) {
        int k0 = t * KSTEP;
        GLDS(A + (size_t)(m0 + r1) * K + k0 + c1 * 8, &lds[buf][0][0] + wid * 1024);
        GLDS(A + (size_t)(m0 + r2) * K + k0 + c2 * 8, &lds[buf][0][0] + 4096 + wid * 1024);
        GLDS(W + (size_t)(n0 + r1) * K + k0 + c1 * 8, &lds[buf][1][0] + wid * 1024);
        GLDS(W + (size_t)(n0 + r2) * K + k0 + c2 * 8, &lds[buf][1][0] + 4096 + wid * 1024);
    };

    stage(0, 0);
    for (int t = 0; t < nt; ++t) {
        int buf = t & 1;
        __syncthreads();
        if (t + 1 < nt) stage(t + 1, buf ^ 1);
        const char* Ab = &lds[buf][0][0];
        const char* Bb = &lds[buf][1][0];
        bf16x8 af[2][2], bfv[2][2];
        #pragma unroll
        for (int mf = 0; mf < 2; ++mf)
            #pragma unroll
            for (int kf = 0; kf < 2; ++kf) {
                int r = wm * 32 + mf * 16 + (lane & 15);
                int c = (lane >> 4) + kf * 4;
                af[mf][kf] = *(const bf16x8*)(Ab + r * 128 + ((c ^ (r & 7)) << 4));
            }
        #pragma unroll
        for (int nf = 0; nf < 2; ++nf)
            #pragma unroll
            for (int kf = 0; kf < 2; ++kf) {
                int r = wn * 32 + nf * 16 + (lane & 15);
                int c = (lane >> 4) + kf * 4;
                bfv[nf][kf] = *(const bf16x8*)(Bb + r * 128 + ((c ^ (r & 7)) << 4));
            }
        #pragma unroll
        for (int kf = 0; kf < 2; ++kf)
            #pragma unroll
            for (int mf = 0; mf < 2; ++mf)
                #pragma unroll
                for (int nf = 0; nf < 2; ++nf)
                    acc[mf][nf] = __builtin_amdgcn_mfma_f32_16x16x32_bf16(
                        af[mf][kf], bfv[nf][kf], acc[mf][nf], 0, 0, 0);
    }

    int cb0 = n0 + wn * 32 + (lane & 15);
    int rb0 = m0 + wm * 32 + ((lane >> 4) << 2);
    #pragma unroll
    for (int mf = 0; mf < 2; ++mf)
        #pragma unroll
        for (int nf = 0; nf < 2; ++nf) {
            int n = cb0 + nf * 16;
            #pragma unroll
            for (int r = 0; r < 4; ++r) {
                int m = rb0 + mf * 16 + r;
                float v = acc[mf][nf][r];
                if (EPI == EPI_IN) {
                    int dd = n >> 10, c = n & 1023;
                    unsigned short* dst = (c < 512)
                        ? (dd ? d1 : d0) + (size_t)m * 512 + c
                        : (dd ? e1 : e0) + (size_t)m * 512 + (c - 512);
                    *dst = f2bf(v);
                } else if (EPI == EPI_P2) {
                    if (n < 512) {
                        float sv = v + (dir ? aux1 : aux0)[n];
                        float sp = (sv > 20.f) ? sv : log1pf(__expf(sv));
                        (dir ? d1 : d0)[(size_t)m * 512 + n] = f2bf(sp);
                    } else if (n < 544) {
                        (dir ? e1 : e0)[(size_t)m * 32 + (n - 512)] = f2bf(v);
                    }
                } else {
                    outF[(size_t)m * 256 + n] = v + 2.f * Xres[(size_t)m * 256 + n];
                }
            }
        }
}

// ---------------- depthwise conv4 + silu (bf16, 8 ch/thread) --------------
// weights reg-cached via coalesced float4 loads (cw rows contiguous per thread)
__global__ __launch_bounds__(256) void conv_silu_kernel(
    const unsigned short* __restrict__ xh0, const unsigned short* __restrict__ xh1,
    const float* __restrict__ cw0, const float* __restrict__ cw1,
    const float* __restrict__ cb0, const float* __restrict__ cb1,
    unsigned short* __restrict__ o0, unsigned short* __restrict__ o1) {
    int dir = blockIdx.y;
    const unsigned short* xh = dir ? xh1 : xh0;
    const float* cw = dir ? cw1 : cw0;
    const float* cb = dir ? cb1 : cb0;
    unsigned short* xc = dir ? o1 : o0;
    int idx8 = blockIdx.x * 256 + threadIdx.x;
    int t = idx8 >> 6;
    int c8 = (idx8 & 63) << 3;
    int l = t & (LL - 1);

    float wreg[32];                      // wreg[j*4+k] = cw[(c8+j)*4 + k]
    #pragma unroll
    for (int q = 0; q < 8; ++q)
        *(float4*)&wreg[q * 4] = *(const float4*)&cw[c8 * 4 + q * 4];
    float acc[8];
    *(float4*)&acc[0] = *(const float4*)&cb[c8];
    *(float4*)&acc[4] = *(const float4*)&cb[c8 + 4];

    #pragma unroll
    for (int k = 0; k < 4; ++k) {
        int lo = dir ? (l + 3 - k) : (l - 3 + k);
        if (lo < 0 || lo >= LL) continue;
        uint4 u = *(const uint4*)(xh + (size_t)(t + lo - l) * DI + c8);
        unsigned wv[4] = {u.x, u.y, u.z, u.w};
        #pragma unroll
        for (int j = 0; j < 4; ++j) {
            float flo = __uint_as_float(wv[j] << 16);
            float fhi = __uint_as_float(wv[j] & 0xffff0000u);
            acc[2 * j]     = fmaf(flo, wreg[(2 * j) * 4 + k], acc[2 * j]);
            acc[2 * j + 1] = fmaf(fhi, wreg[(2 * j + 1) * 4 + k], acc[2 * j + 1]);
        }
    }
    unsigned out[4];
    #pragma unroll
    for (int j = 0; j < 4; ++j) {
        float a0 = acc[2 * j], a1 = acc[2 * j + 1];
        float s0 = a0 / (1.f + __expf(-a0));
        float s1 = a1 / (1.f + __expf(-a1));
        out[j] = (unsigned)f2bf(s0) | ((unsigned)f2bf(s1) << 16);
    }
    *(uint4*)(xc + (size_t)idx8 * 8) = make_uint4(out[0], out[1], out[2], out[3]);
}

// ---------------- scan part1: local chunk scan -> AC, HC, (y_loc,s) -------
__global__ __launch_bounds__(256, 8) void scan_part1(
    const unsigned short* __restrict__ dlt0, const unsigned short* __restrict__ dlt1,
    const unsigned short* __restrict__ xc0, const unsigned short* __restrict__ xc1,
    const unsigned short* __restrict__ bc0, const unsigned short* __restrict__ bc1,
    const float* __restrict__ Al0, const float* __restrict__ Al1,
    const float* __restrict__ Dp0, const float* __restrict__ Dp1,
    float* __restrict__ AC, float* __restrict__ HC,
    unsigned* __restrict__ yls0, unsigned* __restrict__ yls1) {
    int dir = blockIdx.z;
    const unsigned short* delta = dir ? dlt1 : dlt0;
    const unsigned short* xc    = dir ? xc1 : xc0;
    const unsigned short* bc    = dir ? bc1 : bc0;
    const float* Alog           = dir ? Al1 : Al0;
    const float* Dp             = dir ? Dp1 : Dp0;
    unsigned* yls               = dir ? yls1 : yls0;
    int b = blockIdx.y >> 5, ch = blockIdx.y & 31;
    int d0 = blockIdx.x * 64;
    int tid = threadIdx.x;
    int dg = tid >> 2, nq = tid & 3;
    int d = d0 + dg;

    __shared__ unsigned sdxu[CL][64];    // [l][d] packed (delta|xc), col XOR row
    __shared__ unsigned sBC[CL][16];     // [l][n] packed (B|C)
    {
        int row = tid >> 2, q = tid & 3;
        int lr = ch * CL + row;
        int l = dir ? (LL - 1 - lr) : lr;
        size_t t = (size_t)b * LL + l;
        const uint4* dp = (const uint4*)(delta + t * DI + d0 + q * 16);
        const uint4* xp = (const uint4*)(xc + t * DI + d0 + q * 16);
        #pragma unroll
        for (int hh = 0; hh < 2; ++hh) {
            uint4 du = dp[hh], xu = xp[hh];
            unsigned dw[4] = {du.x, du.y, du.z, du.w};
            unsigned xw[4] = {xu.x, xu.y, xu.z, xu.w};
            #pragma unroll
            for (int j = 0; j < 4; ++j) {
                int col = q * 16 + hh * 8 + 2 * j;
                sdxu[row][col ^ row]       = (dw[j] & 0xffffu) | (xw[j] << 16);
                sdxu[row][(col + 1) ^ row] = (dw[j] >> 16) | (xw[j] & 0xffff0000u);
            }
        }
        uint2 Bu = *(const uint2*)(bc + t * 32 + q * 4);
        uint2 Cu = *(const uint2*)(bc + t * 32 + 16 + q * 4);
        sBC[row][q * 4 + 0] = (Bu.x & 0xffffu) | (Cu.x << 16);
        sBC[row][q * 4 + 1] = (Bu.x >> 16) | (Cu.x & 0xffff0000u);
        sBC[row][q * 4 + 2] = (Bu.y & 0xffffu) | (Cu.y << 16);
        sBC[row][q * 4 + 3] = (Bu.y >> 16) | (Cu.y & 0xffff0000u);
    }
    __syncthreads();

    float4 Al = *(const float4*)&Alog[d * DS2 + nq * 4];
    float Avl[4] = {-__expf(Al.x) * L2E, -__expf(Al.y) * L2E,
                    -__expf(Al.z) * L2E, -__expf(Al.w) * L2E};
    float Dv = Dp[d];
    float h[4] = {0.f, 0.f, 0.f, 0.f};
    float sdl = 0.f;

    #pragma unroll 2
    for (int r = 0; r < CL; ++r) {
        unsigned u = sdxu[r][dg ^ r];
        float dl = __uint_as_float(u << 16);
        float xcv = __uint_as_float(u & 0xffff0000u);
        uint4 bq = *(const uint4*)&sBC[r][nq * 4];
        unsigned bw[4] = {bq.x, bq.y, bq.z, bq.w};
        float u0 = dl * xcv;
        sdl += dl;
        float ts = 0.f;
        #pragma unroll
        for (int j = 0; j < 4; ++j) {
            float Bf = __uint_as_float(bw[j] << 16);
            float Cf = __uint_as_float(bw[j] & 0xffff0000u);
            float e = __builtin_amdgcn_exp2f(dl * Avl[j]);
            h[j] = fmaf(e, h[j], u0 * Bf);
            ts = fmaf(h[j], Cf, ts);
        }
        ts += __shfl_xor(ts, 1);
        ts += __shfl_xor(ts, 2);
        if (nq == 0) {
            int lr = ch * CL + r;
            float yv = fmaf(xcv, Dv, ts);
            yls[((size_t)b * LL + lr) * DI + d] =
                (unsigned)f2bf(yv) | ((unsigned)f2bf(sdl) << 16);
        }
    }
    size_t base = (size_t)ch * PLANE + (size_t)(((dir * 4 + b) * DI + d) * DS2 + nq * 4);
    *(float4*)&AC[base] = make_float4(
        __builtin_amdgcn_exp2f(Avl[0] * sdl), __builtin_amdgcn_exp2f(Avl[1] * sdl),
        __builtin_amdgcn_exp2f(Avl[2] * sdl), __builtin_amdgcn_exp2f(Avl[3] * sdl));
    *(float4*)&HC[base] = make_float4(h[0], h[1], h[2], h[3]);
}

// ---------------- scan part2: sequential chunk combine --------------------
__global__ __launch_bounds__(256) void scan_part2(
    const float* __restrict__ AC, const float* __restrict__ HC,
    float* __restrict__ HIN) {
    int idx = blockIdx.x * 256 + threadIdx.x;
    float hin = 0.f;
    #pragma unroll
    for (int ch = 0; ch < NCH; ++ch) {
        size_t o = (size_t)ch * PLANE + idx;
        HIN[o] = hin;
        hin = fmaf(AC[o], hin, HC[o]);
    }
}

// ---------------- scan lite: parallel correction + gate -> ycat -----------
__global__ __launch_bounds__(256, 8) void scan_lite(
    const unsigned* __restrict__ yls0, const unsigned* __restrict__ yls1,
    const unsigned short* __restrict__ bc0, const unsigned short* __restrict__ bc1,
    const unsigned short* __restrict__ z0, const unsigned short* __restrict__ z1,
    const float* __restrict__ Al0, const float* __restrict__ Al1,
    const float* __restrict__ HIN, unsigned short* __restrict__ ycat) {
    int dir = blockIdx.z;
    const unsigned* yls         = dir ? yls1 : yls0;
    const unsigned short* bc    = dir ? bc1 : bc0;
    const unsigned short* zb    = dir ? z1 : z0;
    const float* Alog           = dir ? Al1 : Al0;
    int b = blockIdx.y >> 5, ch = blockIdx.y & 31;
    int d0 = blockIdx.x * 64;
    int tid = threadIdx.x;
    int dg = tid & 63, lg = tid >> 6;
    int d = d0 + dg;

    __shared__ unsigned sC[CL][8];       // [l][n-pair] C packed bf16 pairs
    {
        int row = tid >> 2, q = tid & 3;
        if (q < 2) {
            int lr = ch * CL + row;
            int l = dir ? (LL - 1 - lr) : lr;
            size_t t = (size_t)b * LL + l;
            uint4 cu = *(const uint4*)(bc + t * 32 + 16 + q * 8);
            *(uint4*)&sC[row][q * 4] = cu;
        }
    }
    __syncthreads();

    float Avl[16];
    #pragma unroll
    for (int qq = 0; qq < 4; ++qq) {
        float4 Al = *(const float4*)&Alog[d * DS2 + qq * 4];
        Avl[qq * 4 + 0] = -__expf(Al.x) * L2E;
        Avl[qq * 4 + 1] = -__expf(Al.y) * L2E;
        Avl[qq * 4 + 2] = -__expf(Al.z) * L2E;
        Avl[qq * 4 + 3] = -__expf(Al.w) * L2E;
    }
    float hin[16];
    size_t hbase = (size_t)ch * PLANE + (size_t)(((dir * 4 + b) * DI + d) * DS2);
    #pragma unroll
    for (int qq = 0; qq < 4; ++qq)
        *(float4*)&hin[qq * 4] = *(const float4*)&HIN[hbase + qq * 4];

    #pragma unroll 2
    for (int i = 0; i < 16; ++i) {
        int row = lg * 16 + i;
        int lr = ch * CL + row;
        int ll = dir ? (LL - 1 - lr) : lr;
        size_t tt = (size_t)b * LL + ll;
        unsigned u = yls[((size_t)b * LL + lr) * DI + d];
        float yv = __uint_as_float(u << 16);
        float s  = __uint_as_float(u & 0xffff0000u);
        float acc = 0.f;
        #pragma unroll
        for (int p = 0; p < 8; ++p) {
            unsigned cp = sC[row][p];
            float C0 = __uint_as_float(cp << 16);
            float C1 = __uint_as_float(cp & 0xffff0000u);
            float e0 = __builtin_amdgcn_exp2f(s * Avl[2 * p]);
            float e1 = __builtin_amdgcn_exp2f(s * Avl[2 * p + 1]);
            acc = fmaf(e0 * hin[2 * p], C0, acc);
            acc = fmaf(e1 * hin[2 * p + 1], C1, acc);
        }
        yv += acc;
        float zz = bf2f(zb[tt * DI + d]);
        yv *= zz / (1.f + __expf(-zz));
        ycat[tt * 1024 + (size_t)dir * 512 + d] = f2bf(yv);
    }
}

// -------------------------------------------------------------------------
extern "C" void kernel_launch(void* const* d_in, const int* in_sizes, int n_in,
                              void* d_out, int out_size, void* d_ws, size_t ws_size,
                              hipStream_t stream) {
    const float* x = (const float*)d_in[0];
    const float* p[2][10];
    for (int dir = 0; dir < 2; ++dir)
        for (int i = 0; i < 10; ++i)
            p[dir][i] = (const float*)d_in[1 + dir * 10 + i];
    // p[dir]: 0 norm, 1 in_proj, 2 conv_w, 3 conv_b, 4 x_proj,
    //         5 dt_w, 6 dt_b, 7 A_log, 8 D, 9 out_proj

    char* w = (char*)d_ws;
    auto alloc = [&](size_t bytes) { char* q = w; w += (bytes + 255) & ~(size_t)255; return q; };
    unsigned short* xn    = (unsigned short*)alloc((size_t)NTOK * DM * 2);
    unsigned short* w_in  = (unsigned short*)alloc((size_t)2048 * 256 * 2);
    unsigned short* w_p2  = (unsigned short*)alloc((size_t)1152 * 512 * 2);
    unsigned short* w_out = (unsigned short*)alloc((size_t)256 * 1024 * 2);
    unsigned short *xh[2], *zb[2], *xcb[2], *dlt[2], *bc[2];
    for (int dir = 0; dir < 2; ++dir) {
        xh[dir]  = (unsigned short*)alloc((size_t)NTOK * DI * 2 * 2); // xh, then (y_loc,s) packed u32
        zb[dir]  = (unsigned short*)alloc((size_t)NTOK * DI * 2);
        xcb[dir] = (unsigned short*)alloc((size_t)NTOK * DI * 2);
        dlt[dir] = (unsigned short*)alloc((size_t)NTOK * DI * 2);
        bc[dir]  = (unsigned short*)alloc((size_t)NTOK * 32 * 2);
    }
    unsigned short* ycat = (unsigned short*)alloc((size_t)NTOK * 1024 * 2);
    float* AC  = (float*)alloc((size_t)NCH * PLANE * 4);
    float* HC  = (float*)alloc((size_t)NCH * PLANE * 4);
    float* HIN = (float*)alloc((size_t)NCH * PLANE * 4);
    float* out = (float*)d_out;
    unsigned* yls[2] = {(unsigned*)xh[0], (unsigned*)xh[1]};  // reuse dead xh

    prep_kernel<<<3456, 256, 0, stream>>>(
        p[0][1], p[0][0], p[1][1], p[1][0],
        p[0][4], p[0][5], p[1][4], p[1][5],
        p[0][9], p[1][9], w_in, w_p2, w_out);

    rmsnorm_kernel<<<NTOK, 256, 0, stream>>>(x, xn);

    mfma_gemm<EPI_IN><<<dim3(32, 128, 1), 256, 0, stream>>>(
        xn, xn, w_in, 256, xh[0], xh[1], zb[0], zb[1],
        nullptr, nullptr, nullptr, nullptr);

    conv_silu_kernel<<<dim3(2048, 2), 256, 0, stream>>>(
        xh[0], xh[1], p[0][2], p[1][2], p[0][3], p[1][3], xcb[0], xcb[1]);

    mfma_gemm<EPI_P2><<<dim3(9, 128, 2), 256, 0, stream>>>(
        xcb[0], xcb[1], w_p2, 512, dlt[0], dlt[1], bc[0], bc[1],
        p[0][6], p[1][6], nullptr, nullptr);

    scan_part1<<<dim3(DI / 64, 4 * NCH, 2), 256, 0, stream>>>(
        dlt[0], dlt[1], xcb[0], xcb[1], bc[0], bc[1], p[0][7], p[1][7],
        p[0][8], p[1][8], AC, HC, yls[0], yls[1]);
    scan_part2<<<PLANE / 256, 256, 0, stream>>>(AC, HC, HIN);
    scan_lite<<<dim3(DI / 64, 4 * NCH, 2), 256, 0, stream>>>(
        yls[0], yls[1], bc[0], bc[1], zb[0], zb[1],
        p[0][7], p[1][7], HIN, ycat);

    mfma_gemm<EPI_OUT><<<dim3(4, 128, 1), 256, 0, stream>>>(
        ycat, ycat, w_out, 1024, nullptr, nullptr, nullptr, nullptr,
        nullptr, nullptr, x, out);
}

// Round 7
// 221.401 us; speedup vs baseline: 4.1901x; 1.0164x over previous
//
#include <hip/hip_runtime.h>
#include <hip/hip_bf16.h>
#include <math.h>

// Bidirectional Mamba block. Round 7: XCD-chunked swizzle on GEMMs (T1),
// merged xz layout (branch-free in_proj epilogue).

#define NTOK 8192
#define LL   2048
#define DM   256
#define DI   512
#define DS2  16
#define CL   64
#define NCH  32
#define PLANE 65536
#define KSTEP 64

typedef __bf16 bf16x8 __attribute__((ext_vector_type(8)));
typedef float f32x4 __attribute__((ext_vector_type(4)));

__device__ inline unsigned short f2bf(float f) {
    unsigned u = __float_as_uint(f);
    unsigned r = (u + 0x7fffu + ((u >> 16) & 1u)) >> 16;
    return (unsigned short)r;
}
__device__ inline float bf2f(unsigned short s) {
    return __uint_as_float((unsigned)s << 16);
}

// bijective XCD-chunk swizzle (m204): round-robin dispatch -> contiguous chunks
__device__ inline int xcd_swz(int bid, int nwg) {
    int q = nwg >> 3, r = nwg & 7;
    int xcd = bid & 7, lo = bid >> 3;
    return (xcd < r ? xcd * (q + 1) : r * (q + 1) + (xcd - r) * q) + lo;
}

#define GLDS(gp, lp) __builtin_amdgcn_global_load_lds( \
    (const __attribute__((address_space(1))) void*)(gp), \
    (__attribute__((address_space(3))) void*)(lp), 16, 0, 0)

#define L2E 1.4426950408889634f

// ---------------- prep: weight conversion / folding -----------------------
__global__ __launch_bounds__(256) void prep_kernel(
    const float* __restrict__ ip0, const float* __restrict__ nw0,
    const float* __restrict__ ip1, const float* __restrict__ nw1,
    const float* __restrict__ xp0, const float* __restrict__ dtw0,
    const float* __restrict__ xp1, const float* __restrict__ dtw1,
    const float* __restrict__ op0, const float* __restrict__ op1,
    unsigned short* __restrict__ w_in, unsigned short* __restrict__ w_p2,
    unsigned short* __restrict__ w_out) {
    int bid = blockIdx.x, tid = threadIdx.x;
    if (bid < 2048) {                       // in_proj rows, norm folded
        int dir = bid >> 10, n = bid & 1023;
        const float* ip = dir ? ip1 : ip0;
        const float* nw = dir ? nw1 : nw0;
        w_in[(size_t)bid * 256 + tid] = f2bf(ip[n * 256 + tid] * nw[tid]);
    } else if (bid < 3200) {                // w_p2 rows (576 per dir)
        int idx = bid - 2048;
        int dir = idx / 576, row = idx % 576;
        const float* xp = dir ? xp1 : xp0;
        const float* dtw = dir ? dtw1 : dtw0;
        unsigned short* dst = w_p2 + (size_t)idx * 512;
        for (int k = tid; k < 512; k += 256) {
            float v = 0.f;
            if (row < 512) {
                #pragma unroll
                for (int r = 0; r < 16; ++r) v = fmaf(dtw[row * 16 + r], xp[r * 512 + k], v);
            } else if (row < 544) {
                v = xp[(16 + row - 512) * 512 + k];
            }
            dst[k] = f2bf(v);
        }
    } else {                                // w_out rows (256), K=1024 concat
        int n = bid - 3200;
        for (int k = tid; k < 1024; k += 256) {
            float v = (k < 512) ? op0[n * 512 + k] : op1[n * 512 + (k - 512)];
            w_out[(size_t)n * 1024 + k] = f2bf(v);
        }
    }
}

// ---------------- rmsnorm -> bf16 -----------------------------------------
__global__ __launch_bounds__(256) void rmsnorm_kernel(const float* __restrict__ x,
                                                      unsigned short* __restrict__ xn) {
    int t = blockIdx.x;
    int tid = threadIdx.x;
    float v = x[(size_t)t * DM + tid];
    float ss = v * v;
    #pragma unroll
    for (int m = 1; m < 64; m <<= 1) ss += __shfl_xor(ss, m);
    __shared__ float ws[4];
    if ((tid & 63) == 0) ws[tid >> 6] = ss;
    __syncthreads();
    float tot = ws[0] + ws[1] + ws[2] + ws[3];
    float scale = rsqrtf(tot / (float)DM + 1e-5f);
    xn[(size_t)t * DM + tid] = f2bf(v * scale);
}

// ---------------- bf16 MFMA GEMM: C = A[M,K] @ W[N,K]^T -------------------
#define EPI_IN  0   // -> xzcat[m][n], n in [0,2048)
#define EPI_P2  1
#define EPI_OUT 2

template <int EPI>
__global__ __launch_bounds__(256) void mfma_gemm(
    const unsigned short* __restrict__ A0, const unsigned short* __restrict__ A1,
    const unsigned short* __restrict__ Wb, int K,
    unsigned short* __restrict__ d0, unsigned short* __restrict__ d1,
    unsigned short* __restrict__ e0, unsigned short* __restrict__ e1,
    const float* __restrict__ aux0, const float* __restrict__ aux1,
    const float* __restrict__ Xres, float* __restrict__ outF) {
    __shared__ char lds[2][2][8192];     // [buf][A/B][64 rows * 128B]
    int tid = threadIdx.x;
    int lane = tid & 63, wid = tid >> 6;
    int wm = wid >> 1, wn = wid & 1;
    // XCD-chunked swizzle over flattened (x,y), n fastest
    int nwg = gridDim.x * gridDim.y;
    int lid = xcd_swz(blockIdx.y * gridDim.x + blockIdx.x, nwg);
    int n0 = (lid % gridDim.x) * 64;
    int m0 = (lid / gridDim.x) * 64;
    int dir = blockIdx.z;
    const unsigned short* A = dir ? A1 : A0;
    const unsigned short* W = Wb + ((EPI == EPI_P2) ? (size_t)dir * 576 * 512 : 0);

    const int s1 = tid, s2 = tid + 256;
    const int r1 = s1 >> 3, c1 = (s1 & 7) ^ (r1 & 7);
    const int r2 = s2 >> 3, c2 = (s2 & 7) ^ (r2 & 7);

    f32x4 acc[2][2] = {};
    int nt = K / KSTEP;

    auto stage = [&](int t, int buf) {
        int k0 = t * KSTEP;
        GLDS(A + (size_t)(m0 + r1) * K + k0 + c1 * 8, &lds[buf][0][0] + wid * 1024);
        GLDS(A + (size_t)(m0 + r2) * K + k0 + c2 * 8, &lds[buf][0][0] + 4096 + wid * 1024);
        GLDS(W + (size_t)(n0 + r1) * K + k0 + c1 * 8, &lds[buf][1][0] + wid * 1024);
        GLDS(W + (size_t)(n0 + r2) * K + k0 + c2 * 8, &lds[buf][1][0] + 4096 + wid * 1024);
    };

    stage(0, 0);
    for (int t = 0; t < nt; ++t) {
        int buf = t & 1;
        __syncthreads();
        if (t + 1 < nt) stage(t + 1, buf ^ 1);
        const char* Ab = &lds[buf][0][0];
        const char* Bb = &lds[buf][1][0];
        bf16x8 af[2][2], bfv[2][2];
        #pragma unroll
        for (int mf = 0; mf < 2; ++mf)
            #pragma unroll
            for (int kf = 0; kf < 2; ++kf) {
                int r = wm * 32 + mf * 16 + (lane & 15);
                int c = (lane >> 4) + kf * 4;
                af[mf][kf] = *(const bf16x8*)(Ab + r * 128 + ((c ^ (r & 7)) << 4));
            }
        #pragma unroll
        for (int nf = 0; nf < 2; ++nf)
            #pragma unroll
            for (int kf = 0; kf < 2; ++kf) {
                int r = wn * 32 + nf * 16 + (lane & 15);
                int c = (lane >> 4) + kf * 4;
                bfv[nf][kf] = *(const bf16x8*)(Bb + r * 128 + ((c ^ (r & 7)) << 4));
            }
        #pragma unroll
        for (int kf = 0; kf < 2; ++kf)
            #pragma unroll
            for (int mf = 0; mf < 2; ++mf)
                #pragma unroll
                for (int nf = 0; nf < 2; ++nf)
                    acc[mf][nf] = __builtin_amdgcn_mfma_f32_16x16x32_bf16(
                        af[mf][kf], bfv[nf][kf], acc[mf][nf], 0, 0, 0);
    }

    int cb0 = n0 + wn * 32 + (lane & 15);
    int rb0 = m0 + wm * 32 + ((lane >> 4) << 2);
    #pragma unroll
    for (int mf = 0; mf < 2; ++mf)
        #pragma unroll
        for (int nf = 0; nf < 2; ++nf) {
            int n = cb0 + nf * 16;
            #pragma unroll
            for (int r = 0; r < 4; ++r) {
                int m = rb0 + mf * 16 + r;
                float v = acc[mf][nf][r];
                if (EPI == EPI_IN) {
                    d0[(size_t)m * 2048 + n] = f2bf(v);   // xzcat
                } else if (EPI == EPI_P2) {
                    if (n < 512) {
                        float sv = v + (dir ? aux1 : aux0)[n];
                        float sp = (sv > 20.f) ? sv : log1pf(__expf(sv));
                        (dir ? d1 : d0)[(size_t)m * 512 + n] = f2bf(sp);
                    } else if (n < 544) {
                        (dir ? e1 : e0)[(size_t)m * 32 + (n - 512)] = f2bf(v);
                    }
                } else {
                    outF[(size_t)m * 256 + n] = v + 2.f * Xres[(size_t)m * 256 + n];
                }
            }
        }
}

// ---------------- depthwise conv4 + silu (bf16, 8 ch/thread) --------------
// reads xh half of xzcat (stride 2048); weights reg-cached coalesced
__global__ __launch_bounds__(256) void conv_silu_kernel(
    const unsigned short* __restrict__ xz,
    const float* __restrict__ cw0, const float* __restrict__ cw1,
    const float* __restrict__ cb0, const float* __restrict__ cb1,
    unsigned short* __restrict__ o0, unsigned short* __restrict__ o1) {
    int dir = blockIdx.y;
    const float* cw = dir ? cw1 : cw0;
    const float* cb = dir ? cb1 : cb0;
    unsigned short* xc = dir ? o1 : o0;
    int idx8 = blockIdx.x * 256 + threadIdx.x;
    int t = idx8 >> 6;
    int c8 = (idx8 & 63) << 3;
    int l = t & (LL - 1);
    const unsigned short* xh = xz + (size_t)dir * 1024 + c8;

    float wreg[32];                      // wreg[j*4+k] = cw[(c8+j)*4 + k]
    #pragma unroll
    for (int q = 0; q < 8; ++q)
        *(float4*)&wreg[q * 4] = *(const float4*)&cw[c8 * 4 + q * 4];
    float acc[8];
    *(float4*)&acc[0] = *(const float4*)&cb[c8];
    *(float4*)&acc[4] = *(const float4*)&cb[c8 + 4];

    #pragma unroll
    for (int k = 0; k < 4; ++k) {
        int lo = dir ? (l + 3 - k) : (l - 3 + k);
        if (lo < 0 || lo >= LL) continue;
        uint4 u = *(const uint4*)(xh + (size_t)(t + lo - l) * 2048);
        unsigned wv[4] = {u.x, u.y, u.z, u.w};
        #pragma unroll
        for (int j = 0; j < 4; ++j) {
            float flo = __uint_as_float(wv[j] << 16);
            float fhi = __uint_as_float(wv[j] & 0xffff0000u);
            acc[2 * j]     = fmaf(flo, wreg[(2 * j) * 4 + k], acc[2 * j]);
            acc[2 * j + 1] = fmaf(fhi, wreg[(2 * j + 1) * 4 + k], acc[2 * j + 1]);
        }
    }
    unsigned out[4];
    #pragma unroll
    for (int j = 0; j < 4; ++j) {
        float a0 = acc[2 * j], a1 = acc[2 * j + 1];
        float s0 = a0 / (1.f + __expf(-a0));
        float s1 = a1 / (1.f + __expf(-a1));
        out[j] = (unsigned)f2bf(s0) | ((unsigned)f2bf(s1) << 16);
    }
    *(uint4*)(xc + (size_t)idx8 * 8) = make_uint4(out[0], out[1], out[2], out[3]);
}

// ---------------- scan part1: local chunk scan -> AC, HC, (y_loc,s) -------
__global__ __launch_bounds__(256, 8) void scan_part1(
    const unsigned short* __restrict__ dlt0, const unsigned short* __restrict__ dlt1,
    const unsigned short* __restrict__ xc0, const unsigned short* __restrict__ xc1,
    const unsigned short* __restrict__ bc0, const unsigned short* __restrict__ bc1,
    const float* __restrict__ Al0, const float* __restrict__ Al1,
    const float* __restrict__ Dp0, const float* __restrict__ Dp1,
    float* __restrict__ AC, float* __restrict__ HC,
    unsigned* __restrict__ yls0, unsigned* __restrict__ yls1) {
    int dir = blockIdx.z;
    const unsigned short* delta = dir ? dlt1 : dlt0;
    const unsigned short* xc    = dir ? xc1 : xc0;
    const unsigned short* bc    = dir ? bc1 : bc0;
    const float* Alog           = dir ? Al1 : Al0;
    const float* Dp             = dir ? Dp1 : Dp0;
    unsigned* yls               = dir ? yls1 : yls0;
    int b = blockIdx.y >> 5, ch = blockIdx.y & 31;
    int d0 = blockIdx.x * 64;
    int tid = threadIdx.x;
    int dg = tid >> 2, nq = tid & 3;
    int d = d0 + dg;

    __shared__ unsigned sdxu[CL][64];    // [l][d] packed (delta|xc), col XOR row
    __shared__ unsigned sBC[CL][16];     // [l][n] packed (B|C)
    {
        int row = tid >> 2, q = tid & 3;
        int lr = ch * CL + row;
        int l = dir ? (LL - 1 - lr) : lr;
        size_t t = (size_t)b * LL + l;
        const uint4* dp = (const uint4*)(delta + t * DI + d0 + q * 16);
        const uint4* xp = (const uint4*)(xc + t * DI + d0 + q * 16);
        #pragma unroll
        for (int hh = 0; hh < 2; ++hh) {
            uint4 du = dp[hh], xu = xp[hh];
            unsigned dw[4] = {du.x, du.y, du.z, du.w};
            unsigned xw[4] = {xu.x, xu.y, xu.z, xu.w};
            #pragma unroll
            for (int j = 0; j < 4; ++j) {
                int col = q * 16 + hh * 8 + 2 * j;
                sdxu[row][col ^ row]       = (dw[j] & 0xffffu) | (xw[j] << 16);
                sdxu[row][(col + 1) ^ row] = (dw[j] >> 16) | (xw[j] & 0xffff0000u);
            }
        }
        uint2 Bu = *(const uint2*)(bc + t * 32 + q * 4);
        uint2 Cu = *(const uint2*)(bc + t * 32 + 16 + q * 4);
        sBC[row][q * 4 + 0] = (Bu.x & 0xffffu) | (Cu.x << 16);
        sBC[row][q * 4 + 1] = (Bu.x >> 16) | (Cu.x & 0xffff0000u);
        sBC[row][q * 4 + 2] = (Bu.y & 0xffffu) | (Cu.y << 16);
        sBC[row][q * 4 + 3] = (Bu.y >> 16) | (Cu.y & 0xffff0000u);
    }
    __syncthreads();

    float4 Al = *(const float4*)&Alog[d * DS2 + nq * 4];
    float Avl[4] = {-__expf(Al.x) * L2E, -__expf(Al.y) * L2E,
                    -__expf(Al.z) * L2E, -__expf(Al.w) * L2E};
    float Dv = Dp[d];
    float h[4] = {0.f, 0.f, 0.f, 0.f};
    float sdl = 0.f;

    #pragma unroll 2
    for (int r = 0; r < CL; ++r) {
        unsigned u = sdxu[r][dg ^ r];
        float dl = __uint_as_float(u << 16);
        float xcv = __uint_as_float(u & 0xffff0000u);
        uint4 bq = *(const uint4*)&sBC[r][nq * 4];
        unsigned bw[4] = {bq.x, bq.y, bq.z, bq.w};
        float u0 = dl * xcv;
        sdl += dl;
        float ts = 0.f;
        #pragma unroll
        for (int j = 0; j < 4; ++j) {
            float Bf = __uint_as_float(bw[j] << 16);
            float Cf = __uint_as_float(bw[j] & 0xffff0000u);
            float e = __builtin_amdgcn_exp2f(dl * Avl[j]);
            h[j] = fmaf(e, h[j], u0 * Bf);
            ts = fmaf(h[j], Cf, ts);
        }
        ts += __shfl_xor(ts, 1);
        ts += __shfl_xor(ts, 2);
        if (nq == 0) {
            int lr = ch * CL + r;
            float yv = fmaf(xcv, Dv, ts);
            yls[((size_t)b * LL + lr) * DI + d] =
                (unsigned)f2bf(yv) | ((unsigned)f2bf(sdl) << 16);
        }
    }
    size_t base = (size_t)ch * PLANE + (size_t)(((dir * 4 + b) * DI + d) * DS2 + nq * 4);
    *(float4*)&AC[base] = make_float4(
        __builtin_amdgcn_exp2f(Avl[0] * sdl), __builtin_amdgcn_exp2f(Avl[1] * sdl),
        __builtin_amdgcn_exp2f(Avl[2] * sdl), __builtin_amdgcn_exp2f(Avl[3] * sdl));
    *(float4*)&HC[base] = make_float4(h[0], h[1], h[2], h[3]);
}

// ---------------- scan part2: sequential chunk combine --------------------
__global__ __launch_bounds__(256) void scan_part2(
    const float* __restrict__ AC, const float* __restrict__ HC,
    float* __restrict__ HIN) {
    int idx = blockIdx.x * 256 + threadIdx.x;
    float hin = 0.f;
    #pragma unroll
    for (int ch = 0; ch < NCH; ++ch) {
        size_t o = (size_t)ch * PLANE + idx;
        HIN[o] = hin;
        hin = fmaf(AC[o], hin, HC[o]);
    }
}

// ---------------- scan lite: parallel correction + gate -> ycat -----------
__global__ __launch_bounds__(256, 8) void scan_lite(
    const unsigned* __restrict__ yls0, const unsigned* __restrict__ yls1,
    const unsigned short* __restrict__ bc0, const unsigned short* __restrict__ bc1,
    const unsigned short* __restrict__ xz,
    const float* __restrict__ Al0, const float* __restrict__ Al1,
    const float* __restrict__ HIN, unsigned short* __restrict__ ycat) {
    int dir = blockIdx.z;
    const unsigned* yls         = dir ? yls1 : yls0;
    const unsigned short* bc    = dir ? bc1 : bc0;
    const float* Alog           = dir ? Al1 : Al0;
    int b = blockIdx.y >> 5, ch = blockIdx.y & 31;
    int d0 = blockIdx.x * 64;
    int tid = threadIdx.x;
    int dg = tid & 63, lg = tid >> 6;
    int d = d0 + dg;

    __shared__ unsigned sC[CL][8];       // [l][n-pair] C packed bf16 pairs
    {
        int row = tid >> 2, q = tid & 3;
        if (q < 2) {
            int lr = ch * CL + row;
            int l = dir ? (LL - 1 - lr) : lr;
            size_t t = (size_t)b * LL + l;
            uint4 cu = *(const uint4*)(bc + t * 32 + 16 + q * 8);
            *(uint4*)&sC[row][q * 4] = cu;
        }
    }
    __syncthreads();

    float Avl[16];
    #pragma unroll
    for (int qq = 0; qq < 4; ++qq) {
        float4 Al = *(const float4*)&Alog[d * DS2 + qq * 4];
        Avl[qq * 4 + 0] = -__expf(Al.x) * L2E;
        Avl[qq * 4 + 1] = -__expf(Al.y) * L2E;
        Avl[qq * 4 + 2] = -__expf(Al.z) * L2E;
        Avl[qq * 4 + 3] = -__expf(Al.w) * L2E;
    }
    float hin[16];
    size_t hbase = (size_t)ch * PLANE + (size_t)(((dir * 4 + b) * DI + d) * DS2);
    #pragma unroll
    for (int qq = 0; qq < 4; ++qq)
        *(float4*)&hin[qq * 4] = *(const float4*)&HIN[hbase + qq * 4];

    #pragma unroll 2
    for (int i = 0; i < 16; ++i) {
        int row = lg * 16 + i;
        int lr = ch * CL + row;
        int ll = dir ? (LL - 1 - lr) : lr;
        size_t tt = (size_t)b * LL + ll;
        unsigned u = yls[((size_t)b * LL + lr) * DI + d];
        float yv = __uint_as_float(u << 16);
        float s  = __uint_as_float(u & 0xffff0000u);
        float acc = 0.f;
        #pragma unroll
        for (int p = 0; p < 8; ++p) {
            unsigned cp = sC[row][p];
            float C0 = __uint_as_float(cp << 16);
            float C1 = __uint_as_float(cp & 0xffff0000u);
            float e0 = __builtin_amdgcn_exp2f(s * Avl[2 * p]);
            float e1 = __builtin_amdgcn_exp2f(s * Avl[2 * p + 1]);
            acc = fmaf(e0 * hin[2 * p], C0, acc);
            acc = fmaf(e1 * hin[2 * p + 1], C1, acc);
        }
        yv += acc;
        float zz = bf2f(xz[tt * 2048 + (size_t)dir * 1024 + 512 + d]);
        yv *= zz / (1.f + __expf(-zz));
        ycat[tt * 1024 + (size_t)dir * 512 + d] = f2bf(yv);
    }
}

// -------------------------------------------------------------------------
extern "C" void kernel_launch(void* const* d_in, const int* in_sizes, int n_in,
                              void* d_out, int out_size, void* d_ws, size_t ws_size,
                              hipStream_t stream) {
    const float* x = (const float*)d_in[0];
    const float* p[2][10];
    for (int dir = 0; dir < 2; ++dir)
        for (int i = 0; i < 10; ++i)
            p[dir][i] = (const float*)d_in[1 + dir * 10 + i];
    // p[dir]: 0 norm, 1 in_proj, 2 conv_w, 3 conv_b, 4 x_proj,
    //         5 dt_w, 6 dt_b, 7 A_log, 8 D, 9 out_proj

    char* w = (char*)d_ws;
    auto alloc = [&](size_t bytes) { char* q = w; w += (bytes + 255) & ~(size_t)255; return q; };
    unsigned short* xn    = (unsigned short*)alloc((size_t)NTOK * DM * 2);
    unsigned short* w_in  = (unsigned short*)alloc((size_t)2048 * 256 * 2);
    unsigned short* w_p2  = (unsigned short*)alloc((size_t)1152 * 512 * 2);
    unsigned short* w_out = (unsigned short*)alloc((size_t)256 * 1024 * 2);
    unsigned short* xzcat = (unsigned short*)alloc((size_t)NTOK * 2048 * 2);
    unsigned short *xcb[2], *dlt[2], *bc[2];
    unsigned* yls[2];
    for (int dir = 0; dir < 2; ++dir) {
        xcb[dir] = (unsigned short*)alloc((size_t)NTOK * DI * 2);
        dlt[dir] = (unsigned short*)alloc((size_t)NTOK * DI * 2);
        bc[dir]  = (unsigned short*)alloc((size_t)NTOK * 32 * 2);
        yls[dir] = (unsigned*)alloc((size_t)NTOK * DI * 4);
    }
    unsigned short* ycat = (unsigned short*)alloc((size_t)NTOK * 1024 * 2);
    float* AC  = (float*)alloc((size_t)NCH * PLANE * 4);
    float* HC  = (float*)alloc((size_t)NCH * PLANE * 4);
    float* HIN = (float*)alloc((size_t)NCH * PLANE * 4);
    float* out = (float*)d_out;

    prep_kernel<<<3456, 256, 0, stream>>>(
        p[0][1], p[0][0], p[1][1], p[1][0],
        p[0][4], p[0][5], p[1][4], p[1][5],
        p[0][9], p[1][9], w_in, w_p2, w_out);

    rmsnorm_kernel<<<NTOK, 256, 0, stream>>>(x, xn);

    // in_proj both dirs -> xzcat[m][2048]
    mfma_gemm<EPI_IN><<<dim3(32, 128, 1), 256, 0, stream>>>(
        xn, xn, w_in, 256, xzcat, nullptr, nullptr, nullptr,
        nullptr, nullptr, nullptr, nullptr);

    conv_silu_kernel<<<dim3(2048, 2), 256, 0, stream>>>(
        xzcat, p[0][2], p[1][2], p[0][3], p[1][3], xcb[0], xcb[1]);

    mfma_gemm<EPI_P2><<<dim3(9, 128, 2), 256, 0, stream>>>(
        xcb[0], xcb[1], w_p2, 512, dlt[0], dlt[1], bc[0], bc[1],
        p[0][6], p[1][6], nullptr, nullptr);

    scan_part1<<<dim3(DI / 64, 4 * NCH, 2), 256, 0, stream>>>(
        dlt[0], dlt[1], xcb[0], xcb[1], bc[0], bc[1], p[0][7], p[1][7],
        p[0][8], p[1][8], AC, HC, yls[0], yls[1]);
    scan_part2<<<PLANE / 256, 256, 0, stream>>>(AC, HC, HIN);
    scan_lite<<<dim3(DI / 64, 4 * NCH, 2), 256, 0, stream>>>(
        yls[0], yls[1], bc[0], bc[1], xzcat,
        p[0][7], p[1][7], HIN, ycat);

    mfma_gemm<EPI_OUT><<<dim3(4, 128, 1), 256, 0, stream>>>(
        ycat, ycat, w_out, 1024, nullptr, nullptr, nullptr, nullptr,
        nullptr, nullptr, x, out);
}

// Round 8
// 195.282 us; speedup vs baseline: 4.7506x; 1.1337x over previous
//
#include <hip/hip_runtime.h>
#include <hip/hip_bf16.h>
#include <math.h>

// Bidirectional Mamba block. Round 8: scan_lite correction as Horner polynomial
// in E=exp(-s) (A[d,n] = -(n+1) verified at runtime, general fallback kept),
// plus wave-uniform decay skip when E is negligible.

#define NTOK 8192
#define LL   2048
#define DM   256
#define DI   512
#define DS2  16
#define CL   64
#define NCH  32
#define PLANE 65536
#define KSTEP 64

typedef __bf16 bf16x8 __attribute__((ext_vector_type(8)));
typedef float f32x4 __attribute__((ext_vector_type(4)));

__device__ inline unsigned short f2bf(float f) {
    unsigned u = __float_as_uint(f);
    unsigned r = (u + 0x7fffu + ((u >> 16) & 1u)) >> 16;
    return (unsigned short)r;
}
__device__ inline float bf2f(unsigned short s) {
    return __uint_as_float((unsigned)s << 16);
}

// bijective XCD-chunk swizzle (m204): round-robin dispatch -> contiguous chunks
__device__ inline int xcd_swz(int bid, int nwg) {
    int q = nwg >> 3, r = nwg & 7;
    int xcd = bid & 7, lo = bid >> 3;
    return (xcd < r ? xcd * (q + 1) : r * (q + 1) + (xcd - r) * q) + lo;
}

#define GLDS(gp, lp) __builtin_amdgcn_global_load_lds( \
    (const __attribute__((address_space(1))) void*)(gp), \
    (__attribute__((address_space(3))) void*)(lp), 16, 0, 0)

#define L2E 1.4426950408889634f

// ---------------- prep: weight conversion / folding -----------------------
__global__ __launch_bounds__(256) void prep_kernel(
    const float* __restrict__ ip0, const float* __restrict__ nw0,
    const float* __restrict__ ip1, const float* __restrict__ nw1,
    const float* __restrict__ xp0, const float* __restrict__ dtw0,
    const float* __restrict__ xp1, const float* __restrict__ dtw1,
    const float* __restrict__ op0, const float* __restrict__ op1,
    unsigned short* __restrict__ w_in, unsigned short* __restrict__ w_p2,
    unsigned short* __restrict__ w_out) {
    int bid = blockIdx.x, tid = threadIdx.x;
    if (bid < 2048) {                       // in_proj rows, norm folded
        int dir = bid >> 10, n = bid & 1023;
        const float* ip = dir ? ip1 : ip0;
        const float* nw = dir ? nw1 : nw0;
        w_in[(size_t)bid * 256 + tid] = f2bf(ip[n * 256 + tid] * nw[tid]);
    } else if (bid < 3200) {                // w_p2 rows (576 per dir)
        int idx = bid - 2048;
        int dir = idx / 576, row = idx % 576;
        const float* xp = dir ? xp1 : xp0;
        const float* dtw = dir ? dtw1 : dtw0;
        unsigned short* dst = w_p2 + (size_t)idx * 512;
        for (int k = tid; k < 512; k += 256) {
            float v = 0.f;
            if (row < 512) {
                #pragma unroll
                for (int r = 0; r < 16; ++r) v = fmaf(dtw[row * 16 + r], xp[r * 512 + k], v);
            } else if (row < 544) {
                v = xp[(16 + row - 512) * 512 + k];
            }
            dst[k] = f2bf(v);
        }
    } else {                                // w_out rows (256), K=1024 concat
        int n = bid - 3200;
        for (int k = tid; k < 1024; k += 256) {
            float v = (k < 512) ? op0[n * 512 + k] : op1[n * 512 + (k - 512)];
            w_out[(size_t)n * 1024 + k] = f2bf(v);
        }
    }
}

// ---------------- rmsnorm -> bf16 -----------------------------------------
__global__ __launch_bounds__(256) void rmsnorm_kernel(const float* __restrict__ x,
                                                      unsigned short* __restrict__ xn) {
    int t = blockIdx.x;
    int tid = threadIdx.x;
    float v = x[(size_t)t * DM + tid];
    float ss = v * v;
    #pragma unroll
    for (int m = 1; m < 64; m <<= 1) ss += __shfl_xor(ss, m);
    __shared__ float ws[4];
    if ((tid & 63) == 0) ws[tid >> 6] = ss;
    __syncthreads();
    float tot = ws[0] + ws[1] + ws[2] + ws[3];
    float scale = rsqrtf(tot / (float)DM + 1e-5f);
    xn[(size_t)t * DM + tid] = f2bf(v * scale);
}

// ---------------- bf16 MFMA GEMM: C = A[M,K] @ W[N,K]^T -------------------
#define EPI_IN  0   // -> xzcat[m][n], n in [0,2048)
#define EPI_P2  1
#define EPI_OUT 2

template <int EPI>
__global__ __launch_bounds__(256) void mfma_gemm(
    const unsigned short* __restrict__ A0, const unsigned short* __restrict__ A1,
    const unsigned short* __restrict__ Wb, int K,
    unsigned short* __restrict__ d0, unsigned short* __restrict__ d1,
    unsigned short* __restrict__ e0, unsigned short* __restrict__ e1,
    const float* __restrict__ aux0, const float* __restrict__ aux1,
    const float* __restrict__ Xres, float* __restrict__ outF) {
    __shared__ char lds[2][2][8192];     // [buf][A/B][64 rows * 128B]
    int tid = threadIdx.x;
    int lane = tid & 63, wid = tid >> 6;
    int wm = wid >> 1, wn = wid & 1;
    // XCD-chunked swizzle over flattened (x,y), n fastest
    int nwg = gridDim.x * gridDim.y;
    int lid = xcd_swz(blockIdx.y * gridDim.x + blockIdx.x, nwg);
    int n0 = (lid % gridDim.x) * 64;
    int m0 = (lid / gridDim.x) * 64;
    int dir = blockIdx.z;
    const unsigned short* A = dir ? A1 : A0;
    const unsigned short* W = Wb + ((EPI == EPI_P2) ? (size_t)dir * 576 * 512 : 0);

    const int s1 = tid, s2 = tid + 256;
    const int r1 = s1 >> 3, c1 = (s1 & 7) ^ (r1 & 7);
    const int r2 = s2 >> 3, c2 = (s2 & 7) ^ (r2 & 7);

    f32x4 acc[2][2] = {};
    int nt = K / KSTEP;

    auto stage = [&](int t, int buf) {
        int k0 = t * KSTEP;
        GLDS(A + (size_t)(m0 + r1) * K + k0 + c1 * 8, &lds[buf][0][0] + wid * 1024);
        GLDS(A + (size_t)(m0 + r2) * K + k0 + c2 * 8, &lds[buf][0][0] + 4096 + wid * 1024);
        GLDS(W + (size_t)(n0 + r1) * K + k0 + c1 * 8, &lds[buf][1][0] + wid * 1024);
        GLDS(W + (size_t)(n0 + r2) * K + k0 + c2 * 8, &lds[buf][1][0] + 4096 + wid * 1024);
    };

    stage(0, 0);
    for (int t = 0; t < nt; ++t) {
        int buf = t & 1;
        __syncthreads();
        if (t + 1 < nt) stage(t + 1, buf ^ 1);
        const char* Ab = &lds[buf][0][0];
        const char* Bb = &lds[buf][1][0];
        bf16x8 af[2][2], bfv[2][2];
        #pragma unroll
        for (int mf = 0; mf < 2; ++mf)
            #pragma unroll
            for (int kf = 0; kf < 2; ++kf) {
                int r = wm * 32 + mf * 16 + (lane & 15);
                int c = (lane >> 4) + kf * 4;
                af[mf][kf] = *(const bf16x8*)(Ab + r * 128 + ((c ^ (r & 7)) << 4));
            }
        #pragma unroll
        for (int nf = 0; nf < 2; ++nf)
            #pragma unroll
            for (int kf = 0; kf < 2; ++kf) {
                int r = wn * 32 + nf * 16 + (lane & 15);
                int c = (lane >> 4) + kf * 4;
                bfv[nf][kf] = *(const bf16x8*)(Bb + r * 128 + ((c ^ (r & 7)) << 4));
            }
        #pragma unroll
        for (int kf = 0; kf < 2; ++kf)
            #pragma unroll
            for (int mf = 0; mf < 2; ++mf)
                #pragma unroll
                for (int nf = 0; nf < 2; ++nf)
                    acc[mf][nf] = __builtin_amdgcn_mfma_f32_16x16x32_bf16(
                        af[mf][kf], bfv[nf][kf], acc[mf][nf], 0, 0, 0);
    }

    int cb0 = n0 + wn * 32 + (lane & 15);
    int rb0 = m0 + wm * 32 + ((lane >> 4) << 2);
    #pragma unroll
    for (int mf = 0; mf < 2; ++mf)
        #pragma unroll
        for (int nf = 0; nf < 2; ++nf) {
            int n = cb0 + nf * 16;
            #pragma unroll
            for (int r = 0; r < 4; ++r) {
                int m = rb0 + mf * 16 + r;
                float v = acc[mf][nf][r];
                if (EPI == EPI_IN) {
                    d0[(size_t)m * 2048 + n] = f2bf(v);   // xzcat
                } else if (EPI == EPI_P2) {
                    if (n < 512) {
                        float sv = v + (dir ? aux1 : aux0)[n];
                        float sp = (sv > 20.f) ? sv : log1pf(__expf(sv));
                        (dir ? d1 : d0)[(size_t)m * 512 + n] = f2bf(sp);
                    } else if (n < 544) {
                        (dir ? e1 : e0)[(size_t)m * 32 + (n - 512)] = f2bf(v);
                    }
                } else {
                    outF[(size_t)m * 256 + n] = v + 2.f * Xres[(size_t)m * 256 + n];
                }
            }
        }
}

// ---------------- depthwise conv4 + silu (bf16, 8 ch/thread) --------------
__global__ __launch_bounds__(256) void conv_silu_kernel(
    const unsigned short* __restrict__ xz,
    const float* __restrict__ cw0, const float* __restrict__ cw1,
    const float* __restrict__ cb0, const float* __restrict__ cb1,
    unsigned short* __restrict__ o0, unsigned short* __restrict__ o1) {
    int dir = blockIdx.y;
    const float* cw = dir ? cw1 : cw0;
    const float* cb = dir ? cb1 : cb0;
    unsigned short* xc = dir ? o1 : o0;
    int idx8 = blockIdx.x * 256 + threadIdx.x;
    int t = idx8 >> 6;
    int c8 = (idx8 & 63) << 3;
    int l = t & (LL - 1);
    const unsigned short* xh = xz + (size_t)dir * 1024 + c8;

    float wreg[32];                      // wreg[j*4+k] = cw[(c8+j)*4 + k]
    #pragma unroll
    for (int q = 0; q < 8; ++q)
        *(float4*)&wreg[q * 4] = *(const float4*)&cw[c8 * 4 + q * 4];
    float acc[8];
    *(float4*)&acc[0] = *(const float4*)&cb[c8];
    *(float4*)&acc[4] = *(const float4*)&cb[c8 + 4];

    #pragma unroll
    for (int k = 0; k < 4; ++k) {
        int lo = dir ? (l + 3 - k) : (l - 3 + k);
        if (lo < 0 || lo >= LL) continue;
        uint4 u = *(const uint4*)(xh + (size_t)(t + lo - l) * 2048);
        unsigned wv[4] = {u.x, u.y, u.z, u.w};
        #pragma unroll
        for (int j = 0; j < 4; ++j) {
            float flo = __uint_as_float(wv[j] << 16);
            float fhi = __uint_as_float(wv[j] & 0xffff0000u);
            acc[2 * j]     = fmaf(flo, wreg[(2 * j) * 4 + k], acc[2 * j]);
            acc[2 * j + 1] = fmaf(fhi, wreg[(2 * j + 1) * 4 + k], acc[2 * j + 1]);
        }
    }
    unsigned out[4];
    #pragma unroll
    for (int j = 0; j < 4; ++j) {
        float a0 = acc[2 * j], a1 = acc[2 * j + 1];
        float s0 = a0 / (1.f + __expf(-a0));
        float s1 = a1 / (1.f + __expf(-a1));
        out[j] = (unsigned)f2bf(s0) | ((unsigned)f2bf(s1) << 16);
    }
    *(uint4*)(xc + (size_t)idx8 * 8) = make_uint4(out[0], out[1], out[2], out[3]);
}

// ---------------- scan part1: local chunk scan -> AC, HC, (y_loc,s) -------
__global__ __launch_bounds__(256, 8) void scan_part1(
    const unsigned short* __restrict__ dlt0, const unsigned short* __restrict__ dlt1,
    const unsigned short* __restrict__ xc0, const unsigned short* __restrict__ xc1,
    const unsigned short* __restrict__ bc0, const unsigned short* __restrict__ bc1,
    const float* __restrict__ Al0, const float* __restrict__ Al1,
    const float* __restrict__ Dp0, const float* __restrict__ Dp1,
    float* __restrict__ AC, float* __restrict__ HC,
    unsigned* __restrict__ yls0, unsigned* __restrict__ yls1) {
    int dir = blockIdx.z;
    const unsigned short* delta = dir ? dlt1 : dlt0;
    const unsigned short* xc    = dir ? xc1 : xc0;
    const unsigned short* bc    = dir ? bc1 : bc0;
    const float* Alog           = dir ? Al1 : Al0;
    const float* Dp             = dir ? Dp1 : Dp0;
    unsigned* yls               = dir ? yls1 : yls0;
    int b = blockIdx.y >> 5, ch = blockIdx.y & 31;
    int d0 = blockIdx.x * 64;
    int tid = threadIdx.x;
    int dg = tid >> 2, nq = tid & 3;
    int d = d0 + dg;

    __shared__ unsigned sdxu[CL][64];    // [l][d] packed (delta|xc), col XOR row
    __shared__ unsigned sBC[CL][16];     // [l][n] packed (B|C)
    {
        int row = tid >> 2, q = tid & 3;
        int lr = ch * CL + row;
        int l = dir ? (LL - 1 - lr) : lr;
        size_t t = (size_t)b * LL + l;
        const uint4* dp = (const uint4*)(delta + t * DI + d0 + q * 16);
        const uint4* xp = (const uint4*)(xc + t * DI + d0 + q * 16);
        #pragma unroll
        for (int hh = 0; hh < 2; ++hh) {
            uint4 du = dp[hh], xu = xp[hh];
            unsigned dw[4] = {du.x, du.y, du.z, du.w};
            unsigned xw[4] = {xu.x, xu.y, xu.z, xu.w};
            #pragma unroll
            for (int j = 0; j < 4; ++j) {
                int col = q * 16 + hh * 8 + 2 * j;
                sdxu[row][col ^ row]       = (dw[j] & 0xffffu) | (xw[j] << 16);
                sdxu[row][(col + 1) ^ row] = (dw[j] >> 16) | (xw[j] & 0xffff0000u);
            }
        }
        uint2 Bu = *(const uint2*)(bc + t * 32 + q * 4);
        uint2 Cu = *(const uint2*)(bc + t * 32 + 16 + q * 4);
        sBC[row][q * 4 + 0] = (Bu.x & 0xffffu) | (Cu.x << 16);
        sBC[row][q * 4 + 1] = (Bu.x >> 16) | (Cu.x & 0xffff0000u);
        sBC[row][q * 4 + 2] = (Bu.y & 0xffffu) | (Cu.y << 16);
        sBC[row][q * 4 + 3] = (Bu.y >> 16) | (Cu.y & 0xffff0000u);
    }
    __syncthreads();

    float4 Al = *(const float4*)&Alog[d * DS2 + nq * 4];
    float Avl[4] = {-__expf(Al.x) * L2E, -__expf(Al.y) * L2E,
                    -__expf(Al.z) * L2E, -__expf(Al.w) * L2E};
    float Dv = Dp[d];
    float h[4] = {0.f, 0.f, 0.f, 0.f};
    float sdl = 0.f;

    #pragma unroll 2
    for (int r = 0; r < CL; ++r) {
        unsigned u = sdxu[r][dg ^ r];
        float dl = __uint_as_float(u << 16);
        float xcv = __uint_as_float(u & 0xffff0000u);
        uint4 bq = *(const uint4*)&sBC[r][nq * 4];
        unsigned bw[4] = {bq.x, bq.y, bq.z, bq.w};
        float u0 = dl * xcv;
        sdl += dl;
        float ts = 0.f;
        #pragma unroll
        for (int j = 0; j < 4; ++j) {
            float Bf = __uint_as_float(bw[j] << 16);
            float Cf = __uint_as_float(bw[j] & 0xffff0000u);
            float e = __builtin_amdgcn_exp2f(dl * Avl[j]);
            h[j] = fmaf(e, h[j], u0 * Bf);
            ts = fmaf(h[j], Cf, ts);
        }
        ts += __shfl_xor(ts, 1);
        ts += __shfl_xor(ts, 2);
        if (nq == 0) {
            int lr = ch * CL + r;
            float yv = fmaf(xcv, Dv, ts);
            yls[((size_t)b * LL + lr) * DI + d] =
                (unsigned)f2bf(yv) | ((unsigned)f2bf(sdl) << 16);
        }
    }
    size_t base = (size_t)ch * PLANE + (size_t)(((dir * 4 + b) * DI + d) * DS2 + nq * 4);
    *(float4*)&AC[base] = make_float4(
        __builtin_amdgcn_exp2f(Avl[0] * sdl), __builtin_amdgcn_exp2f(Avl[1] * sdl),
        __builtin_amdgcn_exp2f(Avl[2] * sdl), __builtin_amdgcn_exp2f(Avl[3] * sdl));
    *(float4*)&HC[base] = make_float4(h[0], h[1], h[2], h[3]);
}

// ---------------- scan part2: sequential chunk combine --------------------
__global__ __launch_bounds__(256) void scan_part2(
    const float* __restrict__ AC, const float* __restrict__ HC,
    float* __restrict__ HIN) {
    int idx = blockIdx.x * 256 + threadIdx.x;
    float hin = 0.f;
    #pragma unroll
    for (int ch = 0; ch < NCH; ++ch) {
        size_t o = (size_t)ch * PLANE + idx;
        HIN[o] = hin;
        hin = fmaf(AC[o], hin, HC[o]);
    }
}

// ---------------- scan lite: parallel correction + gate -> ycat -----------
// Fast path (A[d,n] == -(n+1), runtime-verified): corr = Horner poly in
// E = exp(-s): 1 exp2 + 31 fma. Decay skip when E wave-uniformly tiny.
// Fallback: general 16-exp2 path.
__global__ __launch_bounds__(256, 8) void scan_lite(
    const unsigned* __restrict__ yls0, const unsigned* __restrict__ yls1,
    const unsigned short* __restrict__ bc0, const unsigned short* __restrict__ bc1,
    const unsigned short* __restrict__ xz,
    const float* __restrict__ Al0, const float* __restrict__ Al1,
    const float* __restrict__ HIN, unsigned short* __restrict__ ycat) {
    int dir = blockIdx.z;
    const unsigned* yls         = dir ? yls1 : yls0;
    const unsigned short* bc    = dir ? bc1 : bc0;
    const float* Alog           = dir ? Al1 : Al0;
    int b = blockIdx.y >> 5, ch = blockIdx.y & 31;
    int d0 = blockIdx.x * 64;
    int tid = threadIdx.x;
    int dg = tid & 63, lg = tid >> 6;
    int d = d0 + dg;

    __shared__ unsigned sC[CL][8];       // [l][n-pair] C packed bf16 pairs
    {
        int row = tid >> 2, q = tid & 3;
        if (q < 2) {
            int lr = ch * CL + row;
            int l = dir ? (LL - 1 - lr) : lr;
            size_t t = (size_t)b * LL + l;
            uint4 cu = *(const uint4*)(bc + t * 32 + 16 + q * 8);
            *(uint4*)&sC[row][q * 4] = cu;
        }
    }
    __syncthreads();

    float Av[16];
    bool fastA = true;
    #pragma unroll
    for (int qq = 0; qq < 4; ++qq) {
        float4 Al = *(const float4*)&Alog[d * DS2 + qq * 4];
        Av[qq * 4 + 0] = -__expf(Al.x);
        Av[qq * 4 + 1] = -__expf(Al.y);
        Av[qq * 4 + 2] = -__expf(Al.z);
        Av[qq * 4 + 3] = -__expf(Al.w);
    }
    #pragma unroll
    for (int n = 0; n < 16; ++n)
        fastA = fastA && (fabsf(Av[n] + (float)(n + 1)) < 1e-3f * (float)(n + 1));

    float hin[16];
    size_t hbase = (size_t)ch * PLANE + (size_t)(((dir * 4 + b) * DI + d) * DS2);
    #pragma unroll
    for (int qq = 0; qq < 4; ++qq)
        *(float4*)&hin[qq * 4] = *(const float4*)&HIN[hbase + qq * 4];

    #pragma unroll 2
    for (int i = 0; i < 16; ++i) {
        int row = lg * 16 + i;
        int lr = ch * CL + row;
        int ll = dir ? (LL - 1 - lr) : lr;
        size_t tt = (size_t)b * LL + ll;
        unsigned u = yls[((size_t)b * LL + lr) * DI + d];
        float yv = __uint_as_float(u << 16);
        float s  = __uint_as_float(u & 0xffff0000u);
        if (fastA) {
            float E = __builtin_amdgcn_exp2f(-s * L2E);
            if (__any(E > 3e-6f)) {
                // corr = sum_n C_n*hin_n*E^(n+1), Horner high->low
                float acc = 0.f;
                #pragma unroll
                for (int p = 7; p >= 0; --p) {
                    unsigned cp = sC[row][p];
                    float C0 = __uint_as_float(cp << 16);
                    float C1 = __uint_as_float(cp & 0xffff0000u);
                    acc = fmaf(acc, E, C1 * hin[2 * p + 1]);
                    acc = fmaf(acc, E, C0 * hin[2 * p]);
                }
                yv = fmaf(acc, E, yv);
            }
        } else {
            float acc = 0.f;
            #pragma unroll
            for (int p = 0; p < 8; ++p) {
                unsigned cp = sC[row][p];
                float C0 = __uint_as_float(cp << 16);
                float C1 = __uint_as_float(cp & 0xffff0000u);
                float e0 = __builtin_amdgcn_exp2f(s * Av[2 * p] * L2E);
                float e1 = __builtin_amdgcn_exp2f(s * Av[2 * p + 1] * L2E);
                acc = fmaf(e0 * hin[2 * p], C0, acc);
                acc = fmaf(e1 * hin[2 * p + 1], C1, acc);
            }
            yv += acc;
        }
        float zz = bf2f(xz[tt * 2048 + (size_t)dir * 1024 + 512 + d]);
        yv *= zz / (1.f + __expf(-zz));
        ycat[tt * 1024 + (size_t)dir * 512 + d] = f2bf(yv);
    }
}

// -------------------------------------------------------------------------
extern "C" void kernel_launch(void* const* d_in, const int* in_sizes, int n_in,
                              void* d_out, int out_size, void* d_ws, size_t ws_size,
                              hipStream_t stream) {
    const float* x = (const float*)d_in[0];
    const float* p[2][10];
    for (int dir = 0; dir < 2; ++dir)
        for (int i = 0; i < 10; ++i)
            p[dir][i] = (const float*)d_in[1 + dir * 10 + i];
    // p[dir]: 0 norm, 1 in_proj, 2 conv_w, 3 conv_b, 4 x_proj,
    //         5 dt_w, 6 dt_b, 7 A_log, 8 D, 9 out_proj

    char* w = (char*)d_ws;
    auto alloc = [&](size_t bytes) { char* q = w; w += (bytes + 255) & ~(size_t)255; return q; };
    unsigned short* xn    = (unsigned short*)alloc((size_t)NTOK * DM * 2);
    unsigned short* w_in  = (unsigned short*)alloc((size_t)2048 * 256 * 2);
    unsigned short* w_p2  = (unsigned short*)alloc((size_t)1152 * 512 * 2);
    unsigned short* w_out = (unsigned short*)alloc((size_t)256 * 1024 * 2);
    unsigned short* xzcat = (unsigned short*)alloc((size_t)NTOK * 2048 * 2);
    unsigned short *xcb[2], *dlt[2], *bc[2];
    unsigned* yls[2];
    for (int dir = 0; dir < 2; ++dir) {
        xcb[dir] = (unsigned short*)alloc((size_t)NTOK * DI * 2);
        dlt[dir] = (unsigned short*)alloc((size_t)NTOK * DI * 2);
        bc[dir]  = (unsigned short*)alloc((size_t)NTOK * 32 * 2);
        yls[dir] = (unsigned*)alloc((size_t)NTOK * DI * 4);
    }
    unsigned short* ycat = (unsigned short*)alloc((size_t)NTOK * 1024 * 2);
    float* AC  = (float*)alloc((size_t)NCH * PLANE * 4);
    float* HC  = (float*)alloc((size_t)NCH * PLANE * 4);
    float* HIN = (float*)alloc((size_t)NCH * PLANE * 4);
    float* out = (float*)d_out;

    prep_kernel<<<3456, 256, 0, stream>>>(
        p[0][1], p[0][0], p[1][1], p[1][0],
        p[0][4], p[0][5], p[1][4], p[1][5],
        p[0][9], p[1][9], w_in, w_p2, w_out);

    rmsnorm_kernel<<<NTOK, 256, 0, stream>>>(x, xn);

    // in_proj both dirs -> xzcat[m][2048]
    mfma_gemm<EPI_IN><<<dim3(32, 128, 1), 256, 0, stream>>>(
        xn, xn, w_in, 256, xzcat, nullptr, nullptr, nullptr,
        nullptr, nullptr, nullptr, nullptr);

    conv_silu_kernel<<<dim3(2048, 2), 256, 0, stream>>>(
        xzcat, p[0][2], p[1][2], p[0][3], p[1][3], xcb[0], xcb[1]);

    mfma_gemm<EPI_P2><<<dim3(9, 128, 2), 256, 0, stream>>>(
        xcb[0], xcb[1], w_p2, 512, dlt[0], dlt[1], bc[0], bc[1],
        p[0][6], p[1][6], nullptr, nullptr);

    scan_part1<<<dim3(DI / 64, 4 * NCH, 2), 256, 0, stream>>>(
        dlt[0], dlt[1], xcb[0], xcb[1], bc[0], bc[1], p[0][7], p[1][7],
        p[0][8], p[1][8], AC, HC, yls[0], yls[1]);
    scan_part2<<<PLANE / 256, 256, 0, stream>>>(AC, HC, HIN);
    scan_lite<<<dim3(DI / 64, 4 * NCH, 2), 256, 0, stream>>>(
        yls[0], yls[1], bc[0], bc[1], xzcat,
        p[0][7], p[1][7], HIN, ycat);

    mfma_gemm<EPI_OUT><<<dim3(4, 128, 1), 256, 0, stream>>>(
        ycat, ycat, w_out, 1024, nullptr, nullptr, nullptr, nullptr,
        nullptr, nullptr, x, out);
}

// Round 9
// 187.394 us; speedup vs baseline: 4.9505x; 1.0421x over previous
//
#include <hip/hip_runtime.h>
#include <hip/hip_bf16.h>
#include <math.h>

// Bidirectional Mamba block. Round 9: scan_part1 restructured to 8 n-states
// per thread (128d x 2nq block) + ratio-exp tower (2 exp2 + 7 mul per step,
// A-spacing runtime-verified with general fallback).

#define NTOK 8192
#define LL   2048
#define DM   256
#define DI   512
#define DS2  16
#define CL   64
#define NCH  32
#define PLANE 65536
#define KSTEP 64

typedef __bf16 bf16x8 __attribute__((ext_vector_type(8)));
typedef float f32x4 __attribute__((ext_vector_type(4)));

__device__ inline unsigned short f2bf(float f) {
    unsigned u = __float_as_uint(f);
    unsigned r = (u + 0x7fffu + ((u >> 16) & 1u)) >> 16;
    return (unsigned short)r;
}
__device__ inline float bf2f(unsigned short s) {
    return __uint_as_float((unsigned)s << 16);
}

// bijective XCD-chunk swizzle (m204)
__device__ inline int xcd_swz(int bid, int nwg) {
    int q = nwg >> 3, r = nwg & 7;
    int xcd = bid & 7, lo = bid >> 3;
    return (xcd < r ? xcd * (q + 1) : r * (q + 1) + (xcd - r) * q) + lo;
}

#define GLDS(gp, lp) __builtin_amdgcn_global_load_lds( \
    (const __attribute__((address_space(1))) void*)(gp), \
    (__attribute__((address_space(3))) void*)(lp), 16, 0, 0)

#define L2E 1.4426950408889634f

// ---------------- prep: weight conversion / folding -----------------------
__global__ __launch_bounds__(256) void prep_kernel(
    const float* __restrict__ ip0, const float* __restrict__ nw0,
    const float* __restrict__ ip1, const float* __restrict__ nw1,
    const float* __restrict__ xp0, const float* __restrict__ dtw0,
    const float* __restrict__ xp1, const float* __restrict__ dtw1,
    const float* __restrict__ op0, const float* __restrict__ op1,
    unsigned short* __restrict__ w_in, unsigned short* __restrict__ w_p2,
    unsigned short* __restrict__ w_out) {
    int bid = blockIdx.x, tid = threadIdx.x;
    if (bid < 2048) {                       // in_proj rows, norm folded
        int dir = bid >> 10, n = bid & 1023;
        const float* ip = dir ? ip1 : ip0;
        const float* nw = dir ? nw1 : nw0;
        w_in[(size_t)bid * 256 + tid] = f2bf(ip[n * 256 + tid] * nw[tid]);
    } else if (bid < 3200) {                // w_p2 rows (576 per dir)
        int idx = bid - 2048;
        int dir = idx / 576, row = idx % 576;
        const float* xp = dir ? xp1 : xp0;
        const float* dtw = dir ? dtw1 : dtw0;
        unsigned short* dst = w_p2 + (size_t)idx * 512;
        for (int k = tid; k < 512; k += 256) {
            float v = 0.f;
            if (row < 512) {
                #pragma unroll
                for (int r = 0; r < 16; ++r) v = fmaf(dtw[row * 16 + r], xp[r * 512 + k], v);
            } else if (row < 544) {
                v = xp[(16 + row - 512) * 512 + k];
            }
            dst[k] = f2bf(v);
        }
    } else {                                // w_out rows (256), K=1024 concat
        int n = bid - 3200;
        for (int k = tid; k < 1024; k += 256) {
            float v = (k < 512) ? op0[n * 512 + k] : op1[n * 512 + (k - 512)];
            w_out[(size_t)n * 1024 + k] = f2bf(v);
        }
    }
}

// ---------------- rmsnorm -> bf16 -----------------------------------------
__global__ __launch_bounds__(256) void rmsnorm_kernel(const float* __restrict__ x,
                                                      unsigned short* __restrict__ xn) {
    int t = blockIdx.x;
    int tid = threadIdx.x;
    float v = x[(size_t)t * DM + tid];
    float ss = v * v;
    #pragma unroll
    for (int m = 1; m < 64; m <<= 1) ss += __shfl_xor(ss, m);
    __shared__ float ws[4];
    if ((tid & 63) == 0) ws[tid >> 6] = ss;
    __syncthreads();
    float tot = ws[0] + ws[1] + ws[2] + ws[3];
    float scale = rsqrtf(tot / (float)DM + 1e-5f);
    xn[(size_t)t * DM + tid] = f2bf(v * scale);
}

// ---------------- bf16 MFMA GEMM: C = A[M,K] @ W[N,K]^T -------------------
#define EPI_IN  0   // -> xzcat[m][n], n in [0,2048)
#define EPI_P2  1
#define EPI_OUT 2

template <int EPI>
__global__ __launch_bounds__(256) void mfma_gemm(
    const unsigned short* __restrict__ A0, const unsigned short* __restrict__ A1,
    const unsigned short* __restrict__ Wb, int K,
    unsigned short* __restrict__ d0, unsigned short* __restrict__ d1,
    unsigned short* __restrict__ e0, unsigned short* __restrict__ e1,
    const float* __restrict__ aux0, const float* __restrict__ aux1,
    const float* __restrict__ Xres, float* __restrict__ outF) {
    __shared__ char lds[2][2][8192];     // [buf][A/B][64 rows * 128B]
    int tid = threadIdx.x;
    int lane = tid & 63, wid = tid >> 6;
    int wm = wid >> 1, wn = wid & 1;
    int nwg = gridDim.x * gridDim.y;
    int lid = xcd_swz(blockIdx.y * gridDim.x + blockIdx.x, nwg);
    int n0 = (lid % gridDim.x) * 64;
    int m0 = (lid / gridDim.x) * 64;
    int dir = blockIdx.z;
    const unsigned short* A = dir ? A1 : A0;
    const unsigned short* W = Wb + ((EPI == EPI_P2) ? (size_t)dir * 576 * 512 : 0);

    const int s1 = tid, s2 = tid + 256;
    const int r1 = s1 >> 3, c1 = (s1 & 7) ^ (r1 & 7);
    const int r2 = s2 >> 3, c2 = (s2 & 7) ^ (r2 & 7);

    f32x4 acc[2][2] = {};
    int nt = K / KSTEP;

    auto stage = [&](int t, int buf) {
        int k0 = t * KSTEP;
        GLDS(A + (size_t)(m0 + r1) * K + k0 + c1 * 8, &lds[buf][0][0] + wid * 1024);
        GLDS(A + (size_t)(m0 + r2) * K + k0 + c2 * 8, &lds[buf][0][0] + 4096 + wid * 1024);
        GLDS(W + (size_t)(n0 + r1) * K + k0 + c1 * 8, &lds[buf][1][0] + wid * 1024);
        GLDS(W + (size_t)(n0 + r2) * K + k0 + c2 * 8, &lds[buf][1][0] + 4096 + wid * 1024);
    };

    stage(0, 0);
    for (int t = 0; t < nt; ++t) {
        int buf = t & 1;
        __syncthreads();
        if (t + 1 < nt) stage(t + 1, buf ^ 1);
        const char* Ab = &lds[buf][0][0];
        const char* Bb = &lds[buf][1][0];
        bf16x8 af[2][2], bfv[2][2];
        #pragma unroll
        for (int mf = 0; mf < 2; ++mf)
            #pragma unroll
            for (int kf = 0; kf < 2; ++kf) {
                int r = wm * 32 + mf * 16 + (lane & 15);
                int c = (lane >> 4) + kf * 4;
                af[mf][kf] = *(const bf16x8*)(Ab + r * 128 + ((c ^ (r & 7)) << 4));
            }
        #pragma unroll
        for (int nf = 0; nf < 2; ++nf)
            #pragma unroll
            for (int kf = 0; kf < 2; ++kf) {
                int r = wn * 32 + nf * 16 + (lane & 15);
                int c = (lane >> 4) + kf * 4;
                bfv[nf][kf] = *(const bf16x8*)(Bb + r * 128 + ((c ^ (r & 7)) << 4));
            }
        #pragma unroll
        for (int kf = 0; kf < 2; ++kf)
            #pragma unroll
            for (int mf = 0; mf < 2; ++mf)
                #pragma unroll
                for (int nf = 0; nf < 2; ++nf)
                    acc[mf][nf] = __builtin_amdgcn_mfma_f32_16x16x32_bf16(
                        af[mf][kf], bfv[nf][kf], acc[mf][nf], 0, 0, 0);
    }

    int cb0 = n0 + wn * 32 + (lane & 15);
    int rb0 = m0 + wm * 32 + ((lane >> 4) << 2);
    #pragma unroll
    for (int mf = 0; mf < 2; ++mf)
        #pragma unroll
        for (int nf = 0; nf < 2; ++nf) {
            int n = cb0 + nf * 16;
            #pragma unroll
            for (int r = 0; r < 4; ++r) {
                int m = rb0 + mf * 16 + r;
                float v = acc[mf][nf][r];
                if (EPI == EPI_IN) {
                    d0[(size_t)m * 2048 + n] = f2bf(v);   // xzcat
                } else if (EPI == EPI_P2) {
                    if (n < 512) {
                        float sv = v + (dir ? aux1 : aux0)[n];
                        float sp = (sv > 20.f) ? sv : log1pf(__expf(sv));
                        (dir ? d1 : d0)[(size_t)m * 512 + n] = f2bf(sp);
                    } else if (n < 544) {
                        (dir ? e1 : e0)[(size_t)m * 32 + (n - 512)] = f2bf(v);
                    }
                } else {
                    outF[(size_t)m * 256 + n] = v + 2.f * Xres[(size_t)m * 256 + n];
                }
            }
        }
}

// ---------------- depthwise conv4 + silu (bf16, 8 ch/thread) --------------
__global__ __launch_bounds__(256) void conv_silu_kernel(
    const unsigned short* __restrict__ xz,
    const float* __restrict__ cw0, const float* __restrict__ cw1,
    const float* __restrict__ cb0, const float* __restrict__ cb1,
    unsigned short* __restrict__ o0, unsigned short* __restrict__ o1) {
    int dir = blockIdx.y;
    const float* cw = dir ? cw1 : cw0;
    const float* cb = dir ? cb1 : cb0;
    unsigned short* xc = dir ? o1 : o0;
    int idx8 = blockIdx.x * 256 + threadIdx.x;
    int t = idx8 >> 6;
    int c8 = (idx8 & 63) << 3;
    int l = t & (LL - 1);
    const unsigned short* xh = xz + (size_t)dir * 1024 + c8;

    float wreg[32];
    #pragma unroll
    for (int q = 0; q < 8; ++q)
        *(float4*)&wreg[q * 4] = *(const float4*)&cw[c8 * 4 + q * 4];
    float acc[8];
    *(float4*)&acc[0] = *(const float4*)&cb[c8];
    *(float4*)&acc[4] = *(const float4*)&cb[c8 + 4];

    #pragma unroll
    for (int k = 0; k < 4; ++k) {
        int lo = dir ? (l + 3 - k) : (l - 3 + k);
        if (lo < 0 || lo >= LL) continue;
        uint4 u = *(const uint4*)(xh + (size_t)(t + lo - l) * 2048);
        unsigned wv[4] = {u.x, u.y, u.z, u.w};
        #pragma unroll
        for (int j = 0; j < 4; ++j) {
            float flo = __uint_as_float(wv[j] << 16);
            float fhi = __uint_as_float(wv[j] & 0xffff0000u);
            acc[2 * j]     = fmaf(flo, wreg[(2 * j) * 4 + k], acc[2 * j]);
            acc[2 * j + 1] = fmaf(fhi, wreg[(2 * j + 1) * 4 + k], acc[2 * j + 1]);
        }
    }
    unsigned out[4];
    #pragma unroll
    for (int j = 0; j < 4; ++j) {
        float a0 = acc[2 * j], a1 = acc[2 * j + 1];
        float s0 = a0 / (1.f + __expf(-a0));
        float s1 = a1 / (1.f + __expf(-a1));
        out[j] = (unsigned)f2bf(s0) | ((unsigned)f2bf(s1) << 16);
    }
    *(uint4*)(xc + (size_t)idx8 * 8) = make_uint4(out[0], out[1], out[2], out[3]);
}

// ---------------- scan part1: local chunk scan -> AC, HC, (y_loc,s) -------
// block 256 = 128 d x 2 nq (8 n-states/thread); grid (DI/128, 4*NCH, 2)
__global__ __launch_bounds__(256, 4) void scan_part1(
    const unsigned short* __restrict__ dlt0, const unsigned short* __restrict__ dlt1,
    const unsigned short* __restrict__ xc0, const unsigned short* __restrict__ xc1,
    const unsigned short* __restrict__ bc0, const unsigned short* __restrict__ bc1,
    const float* __restrict__ Al0, const float* __restrict__ Al1,
    const float* __restrict__ Dp0, const float* __restrict__ Dp1,
    float* __restrict__ AC, float* __restrict__ HC,
    unsigned* __restrict__ yls0, unsigned* __restrict__ yls1) {
    int dir = blockIdx.z;
    const unsigned short* delta = dir ? dlt1 : dlt0;
    const unsigned short* xc    = dir ? xc1 : xc0;
    const unsigned short* bc    = dir ? bc1 : bc0;
    const float* Alog           = dir ? Al1 : Al0;
    const float* Dp             = dir ? Dp1 : Dp0;
    unsigned* yls               = dir ? yls1 : yls0;
    int b = blockIdx.y >> 5, ch = blockIdx.y & 31;
    int d0 = blockIdx.x * 128;
    int tid = threadIdx.x;
    int dg = tid >> 1, nq = tid & 1;
    int d = d0 + dg;

    __shared__ unsigned sdxu[CL][128];   // [l][d] packed (delta|xc), col XOR row
    __shared__ unsigned sBC[CL][16];     // [l][n] packed (B|C)
    {
        int row = tid >> 2, q = tid & 3;
        int lr = ch * CL + row;
        int l = dir ? (LL - 1 - lr) : lr;
        size_t t = (size_t)b * LL + l;
        const uint4* dp = (const uint4*)(delta + t * DI + d0 + q * 32);
        const uint4* xp = (const uint4*)(xc + t * DI + d0 + q * 32);
        #pragma unroll
        for (int hh = 0; hh < 4; ++hh) {
            uint4 du = dp[hh], xu = xp[hh];
            unsigned dw[4] = {du.x, du.y, du.z, du.w};
            unsigned xw[4] = {xu.x, xu.y, xu.z, xu.w};
            #pragma unroll
            for (int j = 0; j < 4; ++j) {
                int col = q * 32 + hh * 8 + 2 * j;
                sdxu[row][col ^ row]       = (dw[j] & 0xffffu) | (xw[j] << 16);
                sdxu[row][(col + 1) ^ row] = (dw[j] >> 16) | (xw[j] & 0xffff0000u);
            }
        }
        uint2 Bu = *(const uint2*)(bc + t * 32 + q * 4);
        uint2 Cu = *(const uint2*)(bc + t * 32 + 16 + q * 4);
        sBC[row][q * 4 + 0] = (Bu.x & 0xffffu) | (Cu.x << 16);
        sBC[row][q * 4 + 1] = (Bu.x >> 16) | (Cu.x & 0xffff0000u);
        sBC[row][q * 4 + 2] = (Bu.y & 0xffffu) | (Cu.y << 16);
        sBC[row][q * 4 + 3] = (Bu.y >> 16) | (Cu.y & 0xffff0000u);
    }
    __syncthreads();

    // per-thread 8 A values (n = nq*8 + j)
    float Av[8], Avl[8];
    {
        float4 Ala = *(const float4*)&Alog[d * DS2 + nq * 8];
        float4 Alb = *(const float4*)&Alog[d * DS2 + nq * 8 + 4];
        Av[0] = -__expf(Ala.x); Av[1] = -__expf(Ala.y);
        Av[2] = -__expf(Ala.z); Av[3] = -__expf(Ala.w);
        Av[4] = -__expf(Alb.x); Av[5] = -__expf(Alb.y);
        Av[6] = -__expf(Alb.z); Av[7] = -__expf(Alb.w);
    }
    #pragma unroll
    for (int j = 0; j < 8; ++j) Avl[j] = Av[j] * L2E;
    bool fast = true;
    #pragma unroll
    for (int j = 0; j < 7; ++j)
        fast = fast && (fabsf(Av[j + 1] - Av[j] + 1.f) < 1e-2f);

    float Dv = Dp[d];
    float h[8] = {0.f, 0.f, 0.f, 0.f, 0.f, 0.f, 0.f, 0.f};
    float sdl = 0.f;
    const float nL2E = -L2E;

    if (fast) {
        #pragma unroll 2
        for (int r = 0; r < CL; ++r) {
            unsigned u = sdxu[r][dg ^ r];
            float dl = __uint_as_float(u << 16);
            float xcv = __uint_as_float(u & 0xffff0000u);
            uint4 q0 = *(const uint4*)&sBC[r][nq * 8];
            uint4 q1 = *(const uint4*)&sBC[r][nq * 8 + 4];
            unsigned bw[8] = {q0.x, q0.y, q0.z, q0.w, q1.x, q1.y, q1.z, q1.w};
            float u0 = dl * xcv;
            sdl += dl;
            float e  = __builtin_amdgcn_exp2f(dl * Avl[0]);
            float rr = __builtin_amdgcn_exp2f(dl * nL2E);
            float ts = 0.f;
            #pragma unroll
            for (int j = 0; j < 8; ++j) {
                float Bf = __uint_as_float(bw[j] << 16);
                float Cf = __uint_as_float(bw[j] & 0xffff0000u);
                h[j] = fmaf(e, h[j], u0 * Bf);
                ts = fmaf(h[j], Cf, ts);
                if (j < 7) e *= rr;
            }
            ts += __shfl_xor(ts, 1);
            if (nq == 0) {
                int lr = ch * CL + r;
                float yv = fmaf(xcv, Dv, ts);
                yls[((size_t)b * LL + lr) * DI + d] =
                    (unsigned)f2bf(yv) | ((unsigned)f2bf(sdl) << 16);
            }
        }
    } else {
        #pragma unroll 2
        for (int r = 0; r < CL; ++r) {
            unsigned u = sdxu[r][dg ^ r];
            float dl = __uint_as_float(u << 16);
            float xcv = __uint_as_float(u & 0xffff0000u);
            uint4 q0 = *(const uint4*)&sBC[r][nq * 8];
            uint4 q1 = *(const uint4*)&sBC[r][nq * 8 + 4];
            unsigned bw[8] = {q0.x, q0.y, q0.z, q0.w, q1.x, q1.y, q1.z, q1.w};
            float u0 = dl * xcv;
            sdl += dl;
            float ts = 0.f;
            #pragma unroll
            for (int j = 0; j < 8; ++j) {
                float Bf = __uint_as_float(bw[j] << 16);
                float Cf = __uint_as_float(bw[j] & 0xffff0000u);
                float e = __builtin_amdgcn_exp2f(dl * Avl[j]);
                h[j] = fmaf(e, h[j], u0 * Bf);
                ts = fmaf(h[j], Cf, ts);
            }
            ts += __shfl_xor(ts, 1);
            if (nq == 0) {
                int lr = ch * CL + r;
                float yv = fmaf(xcv, Dv, ts);
                yls[((size_t)b * LL + lr) * DI + d] =
                    (unsigned)f2bf(yv) | ((unsigned)f2bf(sdl) << 16);
            }
        }
    }

    size_t base = (size_t)ch * PLANE + (size_t)(((dir * 4 + b) * DI + d) * DS2 + nq * 8);
    float ac[8];
    #pragma unroll
    for (int j = 0; j < 8; ++j) ac[j] = __builtin_amdgcn_exp2f(Avl[j] * sdl);
    *(float4*)&AC[base]     = make_float4(ac[0], ac[1], ac[2], ac[3]);
    *(float4*)&AC[base + 4] = make_float4(ac[4], ac[5], ac[6], ac[7]);
    *(float4*)&HC[base]     = make_float4(h[0], h[1], h[2], h[3]);
    *(float4*)&HC[base + 4] = make_float4(h[4], h[5], h[6], h[7]);
}

// ---------------- scan part2: sequential chunk combine --------------------
__global__ __launch_bounds__(256) void scan_part2(
    const float* __restrict__ AC, const float* __restrict__ HC,
    float* __restrict__ HIN) {
    int idx = blockIdx.x * 256 + threadIdx.x;
    float hin = 0.f;
    #pragma unroll
    for (int ch = 0; ch < NCH; ++ch) {
        size_t o = (size_t)ch * PLANE + idx;
        HIN[o] = hin;
        hin = fmaf(AC[o], hin, HC[o]);
    }
}

// ---------------- scan lite: parallel correction + gate -> ycat -----------
__global__ __launch_bounds__(256, 8) void scan_lite(
    const unsigned* __restrict__ yls0, const unsigned* __restrict__ yls1,
    const unsigned short* __restrict__ bc0, const unsigned short* __restrict__ bc1,
    const unsigned short* __restrict__ xz,
    const float* __restrict__ Al0, const float* __restrict__ Al1,
    const float* __restrict__ HIN, unsigned short* __restrict__ ycat) {
    int dir = blockIdx.z;
    const unsigned* yls         = dir ? yls1 : yls0;
    const unsigned short* bc    = dir ? bc1 : bc0;
    const float* Alog           = dir ? Al1 : Al0;
    int b = blockIdx.y >> 5, ch = blockIdx.y & 31;
    int d0 = blockIdx.x * 64;
    int tid = threadIdx.x;
    int dg = tid & 63, lg = tid >> 6;
    int d = d0 + dg;

    __shared__ unsigned sC[CL][8];
    {
        int row = tid >> 2, q = tid & 3;
        if (q < 2) {
            int lr = ch * CL + row;
            int l = dir ? (LL - 1 - lr) : lr;
            size_t t = (size_t)b * LL + l;
            uint4 cu = *(const uint4*)(bc + t * 32 + 16 + q * 8);
            *(uint4*)&sC[row][q * 4] = cu;
        }
    }
    __syncthreads();

    float Av[16];
    bool fastA = true;
    #pragma unroll
    for (int qq = 0; qq < 4; ++qq) {
        float4 Al = *(const float4*)&Alog[d * DS2 + qq * 4];
        Av[qq * 4 + 0] = -__expf(Al.x);
        Av[qq * 4 + 1] = -__expf(Al.y);
        Av[qq * 4 + 2] = -__expf(Al.z);
        Av[qq * 4 + 3] = -__expf(Al.w);
    }
    #pragma unroll
    for (int n = 0; n < 16; ++n)
        fastA = fastA && (fabsf(Av[n] + (float)(n + 1)) < 1e-3f * (float)(n + 1));

    float hin[16];
    size_t hbase = (size_t)ch * PLANE + (size_t)(((dir * 4 + b) * DI + d) * DS2);
    #pragma unroll
    for (int qq = 0; qq < 4; ++qq)
        *(float4*)&hin[qq * 4] = *(const float4*)&HIN[hbase + qq * 4];

    #pragma unroll 2
    for (int i = 0; i < 16; ++i) {
        int row = lg * 16 + i;
        int lr = ch * CL + row;
        int ll = dir ? (LL - 1 - lr) : lr;
        size_t tt = (size_t)b * LL + ll;
        unsigned u = yls[((size_t)b * LL + lr) * DI + d];
        float yv = __uint_as_float(u << 16);
        float s  = __uint_as_float(u & 0xffff0000u);
        if (fastA) {
            float E = __builtin_amdgcn_exp2f(-s * L2E);
            if (__any(E > 3e-6f)) {
                float acc = 0.f;
                #pragma unroll
                for (int p = 7; p >= 0; --p) {
                    unsigned cp = sC[row][p];
                    float C0 = __uint_as_float(cp << 16);
                    float C1 = __uint_as_float(cp & 0xffff0000u);
                    acc = fmaf(acc, E, C1 * hin[2 * p + 1]);
                    acc = fmaf(acc, E, C0 * hin[2 * p]);
                }
                yv = fmaf(acc, E, yv);
            }
        } else {
            float acc = 0.f;
            #pragma unroll
            for (int p = 0; p < 8; ++p) {
                unsigned cp = sC[row][p];
                float C0 = __uint_as_float(cp << 16);
                float C1 = __uint_as_float(cp & 0xffff0000u);
                float e0 = __builtin_amdgcn_exp2f(s * Av[2 * p] * L2E);
                float e1 = __builtin_amdgcn_exp2f(s * Av[2 * p + 1] * L2E);
                acc = fmaf(e0 * hin[2 * p], C0, acc);
                acc = fmaf(e1 * hin[2 * p + 1], C1, acc);
            }
            yv += acc;
        }
        float zz = bf2f(xz[tt * 2048 + (size_t)dir * 1024 + 512 + d]);
        yv *= zz / (1.f + __expf(-zz));
        ycat[tt * 1024 + (size_t)dir * 512 + d] = f2bf(yv);
    }
}

// -------------------------------------------------------------------------
extern "C" void kernel_launch(void* const* d_in, const int* in_sizes, int n_in,
                              void* d_out, int out_size, void* d_ws, size_t ws_size,
                              hipStream_t stream) {
    const float* x = (const float*)d_in[0];
    const float* p[2][10];
    for (int dir = 0; dir < 2; ++dir)
        for (int i = 0; i < 10; ++i)
            p[dir][i] = (const float*)d_in[1 + dir * 10 + i];
    // p[dir]: 0 norm, 1 in_proj, 2 conv_w, 3 conv_b, 4 x_proj,
    //         5 dt_w, 6 dt_b, 7 A_log, 8 D, 9 out_proj

    char* w = (char*)d_ws;
    auto alloc = [&](size_t bytes) { char* q = w; w += (bytes + 255) & ~(size_t)255; return q; };
    unsigned short* xn    = (unsigned short*)alloc((size_t)NTOK * DM * 2);
    unsigned short* w_in  = (unsigned short*)alloc((size_t)2048 * 256 * 2);
    unsigned short* w_p2  = (unsigned short*)alloc((size_t)1152 * 512 * 2);
    unsigned short* w_out = (unsigned short*)alloc((size_t)256 * 1024 * 2);
    unsigned short* xzcat = (unsigned short*)alloc((size_t)NTOK * 2048 * 2);
    unsigned short *xcb[2], *dlt[2], *bc[2];
    unsigned* yls[2];
    for (int dir = 0; dir < 2; ++dir) {
        xcb[dir] = (unsigned short*)alloc((size_t)NTOK * DI * 2);
        dlt[dir] = (unsigned short*)alloc((size_t)NTOK * DI * 2);
        bc[dir]  = (unsigned short*)alloc((size_t)NTOK * 32 * 2);
        yls[dir] = (unsigned*)alloc((size_t)NTOK * DI * 4);
    }
    unsigned short* ycat = (unsigned short*)alloc((size_t)NTOK * 1024 * 2);
    float* AC  = (float*)alloc((size_t)NCH * PLANE * 4);
    float* HC  = (float*)alloc((size_t)NCH * PLANE * 4);
    float* HIN = (float*)alloc((size_t)NCH * PLANE * 4);
    float* out = (float*)d_out;

    prep_kernel<<<3456, 256, 0, stream>>>(
        p[0][1], p[0][0], p[1][1], p[1][0],
        p[0][4], p[0][5], p[1][4], p[1][5],
        p[0][9], p[1][9], w_in, w_p2, w_out);

    rmsnorm_kernel<<<NTOK, 256, 0, stream>>>(x, xn);

    mfma_gemm<EPI_IN><<<dim3(32, 128, 1), 256, 0, stream>>>(
        xn, xn, w_in, 256, xzcat, nullptr, nullptr, nullptr,
        nullptr, nullptr, nullptr, nullptr);

    conv_silu_kernel<<<dim3(2048, 2), 256, 0, stream>>>(
        xzcat, p[0][2], p[1][2], p[0][3], p[1][3], xcb[0], xcb[1]);

    mfma_gemm<EPI_P2><<<dim3(9, 128, 2), 256, 0, stream>>>(
        xcb[0], xcb[1], w_p2, 512, dlt[0], dlt[1], bc[0], bc[1],
        p[0][6], p[1][6], nullptr, nullptr);

    scan_part1<<<dim3(DI / 128, 4 * NCH, 2), 256, 0, stream>>>(
        dlt[0], dlt[1], xcb[0], xcb[1], bc[0], bc[1], p[0][7], p[1][7],
        p[0][8], p[1][8], AC, HC, yls[0], yls[1]);
    scan_part2<<<PLANE / 256, 256, 0, stream>>>(AC, HC, HIN);
    scan_lite<<<dim3(DI / 64, 4 * NCH, 2), 256, 0, stream>>>(
        yls[0], yls[1], bc[0], bc[1], xzcat,
        p[0][7], p[1][7], HIN, ycat);

    mfma_gemm<EPI_OUT><<<dim3(4, 128, 1), 256, 0, stream>>>(
        ycat, ycat, w_out, 1024, nullptr, nullptr, nullptr, nullptr,
        nullptr, nullptr, x, out);
}

// Round 10
// 169.906 us; speedup vs baseline: 5.4601x; 1.1029x over previous
//
#include <hip/hip_runtime.h>
#include <hip/hip_bf16.h>
#include <math.h>

// Bidirectional Mamba block. Round 10: branchless HW softplus in P2 epilogue
// (log1pf was ~40 instr x 16 outputs = epilogue cost ~ main loop);
// rmsnorm merged into prep (one fewer serialized launch).

#define NTOK 8192
#define LL   2048
#define DM   256
#define DI   512
#define DS2  16
#define CL   64
#define NCH  32
#define PLANE 65536
#define KSTEP 64

typedef __bf16 bf16x8 __attribute__((ext_vector_type(8)));
typedef float f32x4 __attribute__((ext_vector_type(4)));

__device__ inline unsigned short f2bf(float f) {
    unsigned u = __float_as_uint(f);
    unsigned r = (u + 0x7fffu + ((u >> 16) & 1u)) >> 16;
    return (unsigned short)r;
}
__device__ inline float bf2f(unsigned short s) {
    return __uint_as_float((unsigned)s << 16);
}

#define L2E 1.4426950408889634f
#define LN2 0.6931471805599453f

// branchless softplus via hw exp2/log2: log(1+e^x) = max(x,0)+ln2*log2(1+2^(-|x|*l2e))
__device__ inline float softplus_fast(float x) {
    float e = __builtin_amdgcn_exp2f(-fabsf(x) * L2E);
    float l = __builtin_amdgcn_logf(1.f + e);
    return fmaxf(x, 0.f) + l * LN2;
}

// bijective XCD-chunk swizzle (m204)
__device__ inline int xcd_swz(int bid, int nwg) {
    int q = nwg >> 3, r = nwg & 7;
    int xcd = bid & 7, lo = bid >> 3;
    return (xcd < r ? xcd * (q + 1) : r * (q + 1) + (xcd - r) * q) + lo;
}

#define GLDS(gp, lp) __builtin_amdgcn_global_load_lds( \
    (const __attribute__((address_space(1))) void*)(gp), \
    (__attribute__((address_space(3))) void*)(lp), 16, 0, 0)

// ---------------- prep: weight conversion / folding + rmsnorm -------------
__global__ __launch_bounds__(256) void prep_kernel(
    const float* __restrict__ ip0, const float* __restrict__ nw0,
    const float* __restrict__ ip1, const float* __restrict__ nw1,
    const float* __restrict__ xp0, const float* __restrict__ dtw0,
    const float* __restrict__ xp1, const float* __restrict__ dtw1,
    const float* __restrict__ op0, const float* __restrict__ op1,
    unsigned short* __restrict__ w_in, unsigned short* __restrict__ w_p2,
    unsigned short* __restrict__ w_out,
    const float* __restrict__ x, unsigned short* __restrict__ xn) {
    int bid = blockIdx.x, tid = threadIdx.x;
    if (bid < 2048) {                       // in_proj rows, norm folded
        int dir = bid >> 10, n = bid & 1023;
        const float* ip = dir ? ip1 : ip0;
        const float* nw = dir ? nw1 : nw0;
        w_in[(size_t)bid * 256 + tid] = f2bf(ip[n * 256 + tid] * nw[tid]);
    } else if (bid < 3200) {                // w_p2 rows (576 per dir)
        int idx = bid - 2048;
        int dir = idx / 576, row = idx % 576;
        const float* xp = dir ? xp1 : xp0;
        const float* dtw = dir ? dtw1 : dtw0;
        unsigned short* dst = w_p2 + (size_t)idx * 512;
        for (int k = tid; k < 512; k += 256) {
            float v = 0.f;
            if (row < 512) {
                #pragma unroll
                for (int r = 0; r < 16; ++r) v = fmaf(dtw[row * 16 + r], xp[r * 512 + k], v);
            } else if (row < 544) {
                v = xp[(16 + row - 512) * 512 + k];
            }
            dst[k] = f2bf(v);
        }
    } else if (bid < 3456) {                // w_out rows (256), K=1024 concat
        int n = bid - 3200;
        for (int k = tid; k < 1024; k += 256) {
            float v = (k < 512) ? op0[n * 512 + k] : op1[n * 512 + (k - 512)];
            w_out[(size_t)n * 1024 + k] = f2bf(v);
        }
    } else {                                // rmsnorm token
        int t = bid - 3456;
        float v = x[(size_t)t * DM + tid];
        float ss = v * v;
        #pragma unroll
        for (int m = 1; m < 64; m <<= 1) ss += __shfl_xor(ss, m);
        __shared__ float ws[4];
        if ((tid & 63) == 0) ws[tid >> 6] = ss;
        __syncthreads();
        float tot = ws[0] + ws[1] + ws[2] + ws[3];
        float scale = rsqrtf(tot / (float)DM + 1e-5f);
        xn[(size_t)t * DM + tid] = f2bf(v * scale);
    }
}

// ---------------- bf16 MFMA GEMM: C = A[M,K] @ W[N,K]^T -------------------
#define EPI_IN  0   // -> xzcat[m][n], n in [0,2048)
#define EPI_P2  1
#define EPI_OUT 2

template <int EPI>
__global__ __launch_bounds__(256) void mfma_gemm(
    const unsigned short* __restrict__ A0, const unsigned short* __restrict__ A1,
    const unsigned short* __restrict__ Wb, int K,
    unsigned short* __restrict__ d0, unsigned short* __restrict__ d1,
    unsigned short* __restrict__ e0, unsigned short* __restrict__ e1,
    const float* __restrict__ aux0, const float* __restrict__ aux1,
    const float* __restrict__ Xres, float* __restrict__ outF) {
    __shared__ char lds[2][2][8192];     // [buf][A/B][64 rows * 128B]
    int tid = threadIdx.x;
    int lane = tid & 63, wid = tid >> 6;
    int wm = wid >> 1, wn = wid & 1;
    int nwg = gridDim.x * gridDim.y;
    int lid = xcd_swz(blockIdx.y * gridDim.x + blockIdx.x, nwg);
    int n0 = (lid % gridDim.x) * 64;
    int m0 = (lid / gridDim.x) * 64;
    int dir = blockIdx.z;
    const unsigned short* A = dir ? A1 : A0;
    const unsigned short* W = Wb + ((EPI == EPI_P2) ? (size_t)dir * 576 * 512 : 0);

    const int s1 = tid, s2 = tid + 256;
    const int r1 = s1 >> 3, c1 = (s1 & 7) ^ (r1 & 7);
    const int r2 = s2 >> 3, c2 = (s2 & 7) ^ (r2 & 7);

    f32x4 acc[2][2] = {};
    int nt = K / KSTEP;

    auto stage = [&](int t, int buf) {
        int k0 = t * KSTEP;
        GLDS(A + (size_t)(m0 + r1) * K + k0 + c1 * 8, &lds[buf][0][0] + wid * 1024);
        GLDS(A + (size_t)(m0 + r2) * K + k0 + c2 * 8, &lds[buf][0][0] + 4096 + wid * 1024);
        GLDS(W + (size_t)(n0 + r1) * K + k0 + c1 * 8, &lds[buf][1][0] + wid * 1024);
        GLDS(W + (size_t)(n0 + r2) * K + k0 + c2 * 8, &lds[buf][1][0] + 4096 + wid * 1024);
    };

    stage(0, 0);
    for (int t = 0; t < nt; ++t) {
        int buf = t & 1;
        __syncthreads();
        if (t + 1 < nt) stage(t + 1, buf ^ 1);
        const char* Ab = &lds[buf][0][0];
        const char* Bb = &lds[buf][1][0];
        bf16x8 af[2][2], bfv[2][2];
        #pragma unroll
        for (int mf = 0; mf < 2; ++mf)
            #pragma unroll
            for (int kf = 0; kf < 2; ++kf) {
                int r = wm * 32 + mf * 16 + (lane & 15);
                int c = (lane >> 4) + kf * 4;
                af[mf][kf] = *(const bf16x8*)(Ab + r * 128 + ((c ^ (r & 7)) << 4));
            }
        #pragma unroll
        for (int nf = 0; nf < 2; ++nf)
            #pragma unroll
            for (int kf = 0; kf < 2; ++kf) {
                int r = wn * 32 + nf * 16 + (lane & 15);
                int c = (lane >> 4) + kf * 4;
                bfv[nf][kf] = *(const bf16x8*)(Bb + r * 128 + ((c ^ (r & 7)) << 4));
            }
        #pragma unroll
        for (int kf = 0; kf < 2; ++kf)
            #pragma unroll
            for (int mf = 0; mf < 2; ++mf)
                #pragma unroll
                for (int nf = 0; nf < 2; ++nf)
                    acc[mf][nf] = __builtin_amdgcn_mfma_f32_16x16x32_bf16(
                        af[mf][kf], bfv[nf][kf], acc[mf][nf], 0, 0, 0);
    }

    int cb0 = n0 + wn * 32 + (lane & 15);
    int rb0 = m0 + wm * 32 + ((lane >> 4) << 2);
    #pragma unroll
    for (int mf = 0; mf < 2; ++mf)
        #pragma unroll
        for (int nf = 0; nf < 2; ++nf) {
            int n = cb0 + nf * 16;
            #pragma unroll
            for (int r = 0; r < 4; ++r) {
                int m = rb0 + mf * 16 + r;
                float v = acc[mf][nf][r];
                if (EPI == EPI_IN) {
                    d0[(size_t)m * 2048 + n] = f2bf(v);   // xzcat
                } else if (EPI == EPI_P2) {
                    if (n < 512) {
                        float sv = v + (dir ? aux1 : aux0)[n];
                        (dir ? d1 : d0)[(size_t)m * 512 + n] = f2bf(softplus_fast(sv));
                    } else if (n < 544) {
                        (dir ? e1 : e0)[(size_t)m * 32 + (n - 512)] = f2bf(v);
                    }
                } else {
                    outF[(size_t)m * 256 + n] = v + 2.f * Xres[(size_t)m * 256 + n];
                }
            }
        }
}

// ---------------- depthwise conv4 + silu (bf16, 8 ch/thread) --------------
__global__ __launch_bounds__(256) void conv_silu_kernel(
    const unsigned short* __restrict__ xz,
    const float* __restrict__ cw0, const float* __restrict__ cw1,
    const float* __restrict__ cb0, const float* __restrict__ cb1,
    unsigned short* __restrict__ o0, unsigned short* __restrict__ o1) {
    int dir = blockIdx.y;
    const float* cw = dir ? cw1 : cw0;
    const float* cb = dir ? cb1 : cb0;
    unsigned short* xc = dir ? o1 : o0;
    int idx8 = blockIdx.x * 256 + threadIdx.x;
    int t = idx8 >> 6;
    int c8 = (idx8 & 63) << 3;
    int l = t & (LL - 1);
    const unsigned short* xh = xz + (size_t)dir * 1024 + c8;

    float wreg[32];
    #pragma unroll
    for (int q = 0; q < 8; ++q)
        *(float4*)&wreg[q * 4] = *(const float4*)&cw[c8 * 4 + q * 4];
    float acc[8];
    *(float4*)&acc[0] = *(const float4*)&cb[c8];
    *(float4*)&acc[4] = *(const float4*)&cb[c8 + 4];

    #pragma unroll
    for (int k = 0; k < 4; ++k) {
        int lo = dir ? (l + 3 - k) : (l - 3 + k);
        if (lo < 0 || lo >= LL) continue;
        uint4 u = *(const uint4*)(xh + (size_t)(t + lo - l) * 2048);
        unsigned wv[4] = {u.x, u.y, u.z, u.w};
        #pragma unroll
        for (int j = 0; j < 4; ++j) {
            float flo = __uint_as_float(wv[j] << 16);
            float fhi = __uint_as_float(wv[j] & 0xffff0000u);
            acc[2 * j]     = fmaf(flo, wreg[(2 * j) * 4 + k], acc[2 * j]);
            acc[2 * j + 1] = fmaf(fhi, wreg[(2 * j + 1) * 4 + k], acc[2 * j + 1]);
        }
    }
    unsigned out[4];
    #pragma unroll
    for (int j = 0; j < 4; ++j) {
        float a0 = acc[2 * j], a1 = acc[2 * j + 1];
        float s0 = a0 / (1.f + __expf(-a0));
        float s1 = a1 / (1.f + __expf(-a1));
        out[j] = (unsigned)f2bf(s0) | ((unsigned)f2bf(s1) << 16);
    }
    *(uint4*)(xc + (size_t)idx8 * 8) = make_uint4(out[0], out[1], out[2], out[3]);
}

// ---------------- scan part1: local chunk scan -> AC, HC, (y_loc,s) -------
// block 256 = 128 d x 2 nq (8 n-states/thread); grid (DI/128, 4*NCH, 2)
__global__ __launch_bounds__(256, 4) void scan_part1(
    const unsigned short* __restrict__ dlt0, const unsigned short* __restrict__ dlt1,
    const unsigned short* __restrict__ xc0, const unsigned short* __restrict__ xc1,
    const unsigned short* __restrict__ bc0, const unsigned short* __restrict__ bc1,
    const float* __restrict__ Al0, const float* __restrict__ Al1,
    const float* __restrict__ Dp0, const float* __restrict__ Dp1,
    float* __restrict__ AC, float* __restrict__ HC,
    unsigned* __restrict__ yls0, unsigned* __restrict__ yls1) {
    int dir = blockIdx.z;
    const unsigned short* delta = dir ? dlt1 : dlt0;
    const unsigned short* xc    = dir ? xc1 : xc0;
    const unsigned short* bc    = dir ? bc1 : bc0;
    const float* Alog           = dir ? Al1 : Al0;
    const float* Dp             = dir ? Dp1 : Dp0;
    unsigned* yls               = dir ? yls1 : yls0;
    int b = blockIdx.y >> 5, ch = blockIdx.y & 31;
    int d0 = blockIdx.x * 128;
    int tid = threadIdx.x;
    int dg = tid >> 1, nq = tid & 1;
    int d = d0 + dg;

    __shared__ unsigned sdxu[CL][128];   // [l][d] packed (delta|xc), col XOR row
    __shared__ unsigned sBC[CL][16];     // [l][n] packed (B|C)
    {
        int row = tid >> 2, q = tid & 3;
        int lr = ch * CL + row;
        int l = dir ? (LL - 1 - lr) : lr;
        size_t t = (size_t)b * LL + l;
        const uint4* dp = (const uint4*)(delta + t * DI + d0 + q * 32);
        const uint4* xp = (const uint4*)(xc + t * DI + d0 + q * 32);
        #pragma unroll
        for (int hh = 0; hh < 4; ++hh) {
            uint4 du = dp[hh], xu = xp[hh];
            unsigned dw[4] = {du.x, du.y, du.z, du.w};
            unsigned xw[4] = {xu.x, xu.y, xu.z, xu.w};
            #pragma unroll
            for (int j = 0; j < 4; ++j) {
                int col = q * 32 + hh * 8 + 2 * j;
                sdxu[row][col ^ row]       = (dw[j] & 0xffffu) | (xw[j] << 16);
                sdxu[row][(col + 1) ^ row] = (dw[j] >> 16) | (xw[j] & 0xffff0000u);
            }
        }
        uint2 Bu = *(const uint2*)(bc + t * 32 + q * 4);
        uint2 Cu = *(const uint2*)(bc + t * 32 + 16 + q * 4);
        sBC[row][q * 4 + 0] = (Bu.x & 0xffffu) | (Cu.x << 16);
        sBC[row][q * 4 + 1] = (Bu.x >> 16) | (Cu.x & 0xffff0000u);
        sBC[row][q * 4 + 2] = (Bu.y & 0xffffu) | (Cu.y << 16);
        sBC[row][q * 4 + 3] = (Bu.y >> 16) | (Cu.y & 0xffff0000u);
    }
    __syncthreads();

    float Av[8], Avl[8];
    {
        float4 Ala = *(const float4*)&Alog[d * DS2 + nq * 8];
        float4 Alb = *(const float4*)&Alog[d * DS2 + nq * 8 + 4];
        Av[0] = -__expf(Ala.x); Av[1] = -__expf(Ala.y);
        Av[2] = -__expf(Ala.z); Av[3] = -__expf(Ala.w);
        Av[4] = -__expf(Alb.x); Av[5] = -__expf(Alb.y);
        Av[6] = -__expf(Alb.z); Av[7] = -__expf(Alb.w);
    }
    #pragma unroll
    for (int j = 0; j < 8; ++j) Avl[j] = Av[j] * L2E;
    bool fast = true;
    #pragma unroll
    for (int j = 0; j < 7; ++j)
        fast = fast && (fabsf(Av[j + 1] - Av[j] + 1.f) < 1e-2f);

    float Dv = Dp[d];
    float h[8] = {0.f, 0.f, 0.f, 0.f, 0.f, 0.f, 0.f, 0.f};
    float sdl = 0.f;
    const float nL2E = -L2E;

    if (fast) {
        #pragma unroll 2
        for (int r = 0; r < CL; ++r) {
            unsigned u = sdxu[r][dg ^ r];
            float dl = __uint_as_float(u << 16);
            float xcv = __uint_as_float(u & 0xffff0000u);
            uint4 q0 = *(const uint4*)&sBC[r][nq * 8];
            uint4 q1 = *(const uint4*)&sBC[r][nq * 8 + 4];
            unsigned bw[8] = {q0.x, q0.y, q0.z, q0.w, q1.x, q1.y, q1.z, q1.w};
            float u0 = dl * xcv;
            sdl += dl;
            float e  = __builtin_amdgcn_exp2f(dl * Avl[0]);
            float rr = __builtin_amdgcn_exp2f(dl * nL2E);
            float ts = 0.f;
            #pragma unroll
            for (int j = 0; j < 8; ++j) {
                float Bf = __uint_as_float(bw[j] << 16);
                float Cf = __uint_as_float(bw[j] & 0xffff0000u);
                h[j] = fmaf(e, h[j], u0 * Bf);
                ts = fmaf(h[j], Cf, ts);
                if (j < 7) e *= rr;
            }
            ts += __shfl_xor(ts, 1);
            if (nq == 0) {
                int lr = ch * CL + r;
                float yv = fmaf(xcv, Dv, ts);
                yls[((size_t)b * LL + lr) * DI + d] =
                    (unsigned)f2bf(yv) | ((unsigned)f2bf(sdl) << 16);
            }
        }
    } else {
        #pragma unroll 2
        for (int r = 0; r < CL; ++r) {
            unsigned u = sdxu[r][dg ^ r];
            float dl = __uint_as_float(u << 16);
            float xcv = __uint_as_float(u & 0xffff0000u);
            uint4 q0 = *(const uint4*)&sBC[r][nq * 8];
            uint4 q1 = *(const uint4*)&sBC[r][nq * 8 + 4];
            unsigned bw[8] = {q0.x, q0.y, q0.z, q0.w, q1.x, q1.y, q1.z, q1.w};
            float u0 = dl * xcv;
            sdl += dl;
            float ts = 0.f;
            #pragma unroll
            for (int j = 0; j < 8; ++j) {
                float Bf = __uint_as_float(bw[j] << 16);
                float Cf = __uint_as_float(bw[j] & 0xffff0000u);
                float e = __builtin_amdgcn_exp2f(dl * Avl[j]);
                h[j] = fmaf(e, h[j], u0 * Bf);
                ts = fmaf(h[j], Cf, ts);
            }
            ts += __shfl_xor(ts, 1);
            if (nq == 0) {
                int lr = ch * CL + r;
                float yv = fmaf(xcv, Dv, ts);
                yls[((size_t)b * LL + lr) * DI + d] =
                    (unsigned)f2bf(yv) | ((unsigned)f2bf(sdl) << 16);
            }
        }
    }

    size_t base = (size_t)ch * PLANE + (size_t)(((dir * 4 + b) * DI + d) * DS2 + nq * 8);
    float ac[8];
    #pragma unroll
    for (int j = 0; j < 8; ++j) ac[j] = __builtin_amdgcn_exp2f(Avl[j] * sdl);
    *(float4*)&AC[base]     = make_float4(ac[0], ac[1], ac[2], ac[3]);
    *(float4*)&AC[base + 4] = make_float4(ac[4], ac[5], ac[6], ac[7]);
    *(float4*)&HC[base]     = make_float4(h[0], h[1], h[2], h[3]);
    *(float4*)&HC[base + 4] = make_float4(h[4], h[5], h[6], h[7]);
}

// ---------------- scan part2: sequential chunk combine --------------------
__global__ __launch_bounds__(256) void scan_part2(
    const float* __restrict__ AC, const float* __restrict__ HC,
    float* __restrict__ HIN) {
    int idx = blockIdx.x * 256 + threadIdx.x;
    float hin = 0.f;
    #pragma unroll
    for (int ch = 0; ch < NCH; ++ch) {
        size_t o = (size_t)ch * PLANE + idx;
        HIN[o] = hin;
        hin = fmaf(AC[o], hin, HC[o]);
    }
}

// ---------------- scan lite: parallel correction + gate -> ycat -----------
__global__ __launch_bounds__(256, 8) void scan_lite(
    const unsigned* __restrict__ yls0, const unsigned* __restrict__ yls1,
    const unsigned short* __restrict__ bc0, const unsigned short* __restrict__ bc1,
    const unsigned short* __restrict__ xz,
    const float* __restrict__ Al0, const float* __restrict__ Al1,
    const float* __restrict__ HIN, unsigned short* __restrict__ ycat) {
    int dir = blockIdx.z;
    const unsigned* yls         = dir ? yls1 : yls0;
    const unsigned short* bc    = dir ? bc1 : bc0;
    const float* Alog           = dir ? Al1 : Al0;
    int b = blockIdx.y >> 5, ch = blockIdx.y & 31;
    int d0 = blockIdx.x * 64;
    int tid = threadIdx.x;
    int dg = tid & 63, lg = tid >> 6;
    int d = d0 + dg;

    __shared__ unsigned sC[CL][8];
    {
        int row = tid >> 2, q = tid & 3;
        if (q < 2) {
            int lr = ch * CL + row;
            int l = dir ? (LL - 1 - lr) : lr;
            size_t t = (size_t)b * LL + l;
            uint4 cu = *(const uint4*)(bc + t * 32 + 16 + q * 8);
            *(uint4*)&sC[row][q * 4] = cu;
        }
    }
    __syncthreads();

    float Av[16];
    bool fastA = true;
    #pragma unroll
    for (int qq = 0; qq < 4; ++qq) {
        float4 Al = *(const float4*)&Alog[d * DS2 + qq * 4];
        Av[qq * 4 + 0] = -__expf(Al.x);
        Av[qq * 4 + 1] = -__expf(Al.y);
        Av[qq * 4 + 2] = -__expf(Al.z);
        Av[qq * 4 + 3] = -__expf(Al.w);
    }
    #pragma unroll
    for (int n = 0; n < 16; ++n)
        fastA = fastA && (fabsf(Av[n] + (float)(n + 1)) < 1e-3f * (float)(n + 1));

    float hin[16];
    size_t hbase = (size_t)ch * PLANE + (size_t)(((dir * 4 + b) * DI + d) * DS2);
    #pragma unroll
    for (int qq = 0; qq < 4; ++qq)
        *(float4*)&hin[qq * 4] = *(const float4*)&HIN[hbase + qq * 4];

    #pragma unroll 2
    for (int i = 0; i < 16; ++i) {
        int row = lg * 16 + i;
        int lr = ch * CL + row;
        int ll = dir ? (LL - 1 - lr) : lr;
        size_t tt = (size_t)b * LL + ll;
        unsigned u = yls[((size_t)b * LL + lr) * DI + d];
        float yv = __uint_as_float(u << 16);
        float s  = __uint_as_float(u & 0xffff0000u);
        if (fastA) {
            float E = __builtin_amdgcn_exp2f(-s * L2E);
            if (__any(E > 3e-6f)) {
                float acc = 0.f;
                #pragma unroll
                for (int p = 7; p >= 0; --p) {
                    unsigned cp = sC[row][p];
                    float C0 = __uint_as_float(cp << 16);
                    float C1 = __uint_as_float(cp & 0xffff0000u);
                    acc = fmaf(acc, E, C1 * hin[2 * p + 1]);
                    acc = fmaf(acc, E, C0 * hin[2 * p]);
                }
                yv = fmaf(acc, E, yv);
            }
        } else {
            float acc = 0.f;
            #pragma unroll
            for (int p = 0; p < 8; ++p) {
                unsigned cp = sC[row][p];
                float C0 = __uint_as_float(cp << 16);
                float C1 = __uint_as_float(cp & 0xffff0000u);
                float e0 = __builtin_amdgcn_exp2f(s * Av[2 * p] * L2E);
                float e1 = __builtin_amdgcn_exp2f(s * Av[2 * p + 1] * L2E);
                acc = fmaf(e0 * hin[2 * p], C0, acc);
                acc = fmaf(e1 * hin[2 * p + 1], C1, acc);
            }
            yv += acc;
        }
        float zz = bf2f(xz[tt * 2048 + (size_t)dir * 1024 + 512 + d]);
        yv *= zz / (1.f + __expf(-zz));
        ycat[tt * 1024 + (size_t)dir * 512 + d] = f2bf(yv);
    }
}

// -------------------------------------------------------------------------
extern "C" void kernel_launch(void* const* d_in, const int* in_sizes, int n_in,
                              void* d_out, int out_size, void* d_ws, size_t ws_size,
                              hipStream_t stream) {
    const float* x = (const float*)d_in[0];
    const float* p[2][10];
    for (int dir = 0; dir < 2; ++dir)
        for (int i = 0; i < 10; ++i)
            p[dir][i] = (const float*)d_in[1 + dir * 10 + i];
    // p[dir]: 0 norm, 1 in_proj, 2 conv_w, 3 conv_b, 4 x_proj,
    //         5 dt_w, 6 dt_b, 7 A_log, 8 D, 9 out_proj

    char* w = (char*)d_ws;
    auto alloc = [&](size_t bytes) { char* q = w; w += (bytes + 255) & ~(size_t)255; return q; };
    unsigned short* xn    = (unsigned short*)alloc((size_t)NTOK * DM * 2);
    unsigned short* w_in  = (unsigned short*)alloc((size_t)2048 * 256 * 2);
    unsigned short* w_p2  = (unsigned short*)alloc((size_t)1152 * 512 * 2);
    unsigned short* w_out = (unsigned short*)alloc((size_t)256 * 1024 * 2);
    unsigned short* xzcat = (unsigned short*)alloc((size_t)NTOK * 2048 * 2);
    unsigned short *xcb[2], *dlt[2], *bc[2];
    unsigned* yls[2];
    for (int dir = 0; dir < 2; ++dir) {
        xcb[dir] = (unsigned short*)alloc((size_t)NTOK * DI * 2);
        dlt[dir] = (unsigned short*)alloc((size_t)NTOK * DI * 2);
        bc[dir]  = (unsigned short*)alloc((size_t)NTOK * 32 * 2);
        yls[dir] = (unsigned*)alloc((size_t)NTOK * DI * 4);
    }
    unsigned short* ycat = (unsigned short*)alloc((size_t)NTOK * 1024 * 2);
    float* AC  = (float*)alloc((size_t)NCH * PLANE * 4);
    float* HC  = (float*)alloc((size_t)NCH * PLANE * 4);
    float* HIN = (float*)alloc((size_t)NCH * PLANE * 4);
    float* out = (float*)d_out;

    prep_kernel<<<3456 + NTOK, 256, 0, stream>>>(
        p[0][1], p[0][0], p[1][1], p[1][0],
        p[0][4], p[0][5], p[1][4], p[1][5],
        p[0][9], p[1][9], w_in, w_p2, w_out, x, xn);

    mfma_gemm<EPI_IN><<<dim3(32, 128, 1), 256, 0, stream>>>(
        xn, xn, w_in, 256, xzcat, nullptr, nullptr, nullptr,
        nullptr, nullptr, nullptr, nullptr);

    conv_silu_kernel<<<dim3(2048, 2), 256, 0, stream>>>(
        xzcat, p[0][2], p[1][2], p[0][3], p[1][3], xcb[0], xcb[1]);

    mfma_gemm<EPI_P2><<<dim3(9, 128, 2), 256, 0, stream>>>(
        xcb[0], xcb[1], w_p2, 512, dlt[0], dlt[1], bc[0], bc[1],
        p[0][6], p[1][6], nullptr, nullptr);

    scan_part1<<<dim3(DI / 128, 4 * NCH, 2), 256, 0, stream>>>(
        dlt[0], dlt[1], xcb[0], xcb[1], bc[0], bc[1], p[0][7], p[1][7],
        p[0][8], p[1][8], AC, HC, yls[0], yls[1]);
    scan_part2<<<PLANE / 256, 256, 0, stream>>>(AC, HC, HIN);
    scan_lite<<<dim3(DI / 64, 4 * NCH, 2), 256, 0, stream>>>(
        yls[0], yls[1], bc[0], bc[1], xzcat,
        p[0][7], p[1][7], HIN, ycat);

    mfma_gemm<EPI_OUT><<<dim3(4, 128, 1), 256, 0, stream>>>(
        ycat, ycat, w_out, 1024, nullptr, nullptr, nullptr, nullptr,
        nullptr, nullptr, x, out);
}